// Round 3
// baseline (1184.801 us; speedup 1.0000x reference)
//
#include <hip/hip_runtime.h>

// ---------------------------------------------------------------------------
// KAN-FNO block, fp32, MI355X.
// Pipeline:
//   1. fwd_dft:   truncated separable rfft2 -> Xf[b,c,32,16] (complex planes)
//   2. mode_mix:  per-mode 16x64x64 complex GEMM (in-place on Xf)
//   3. inv_h:     inverse DFT along h -> Y1[b,o,128,16]
//   4. invw_conv: inverse c2r along w (pocketfft conv: imag of kx=0 ignored)
//                 + 1x1 conv + bias  -> y (stored in d_out as scratch)
//   5. kan<false>: KAN layer 1, in-place on d_out
//   6. kan<true>:  KAN layer 2 + exact GELU, in-place on d_out
// Weight prep: Wq[144][64] float4 = transposed+scaled [576 feat][64 out].
//
// R2 fix: B-spline degree-0 indicator used inconsistent interval edges
// (gl+0.4f vs next gl) -> ~1e-7-wide gaps/overlaps at knots; ~80 of 1e9
// evaluations landed in a gap, dropping a channel's spline contribution
// (~0.04 error). Now a single consistent knot array K[12] (bitwise = ref's
// arange*h-1 fp32 arithmetic) is used for indicators AND recursion.
// ---------------------------------------------------------------------------

// ---------------- forward truncated rfft2 ----------------
__global__ __launch_bounds__(256) void fwd_dft_kernel(
    const float* __restrict__ x, float* __restrict__ XfRe, float* __restrict__ XfIm) {
  __shared__ __align__(16) float img[64 * 132];   // half image, padded rows
  __shared__ float XwRe[128 * 16];
  __shared__ float XwIm[128 * 16];
  __shared__ float ctab[128];
  __shared__ float stab[128];
  const int tid = threadIdx.x;
  const int bc = blockIdx.x;  // b*64+c
  const float4* src4 = (const float4*)(x + (size_t)bc * 16384);
  if (tid < 128) {
    float s, c;
    sincosf((float)((double)tid * (6.283185307179586476925287 / 128.0)), &s, &c);
    ctab[tid] = c;
    stab[tid] = s;
  }
  for (int h0 = 0; h0 < 128; h0 += 64) {
    __syncthreads();
    for (int e = tid; e < 2048; e += 256) {
      int r = e >> 5, w4 = e & 31;
      float4 v = src4[(h0 + r) * 32 + w4];
      *((float4*)&img[r * 132 + w4 * 4]) = v;
    }
    __syncthreads();
    // stage 1: DFT along w for kx=0..15
    for (int e = tid; e < 1024; e += 256) {
      int hr = e >> 4, kx = e & 15;
      const float* row = img + hr * 132;
      float re = 0.f, im = 0.f;
      int t = 0;
#pragma unroll 8
      for (int w = 0; w < 128; ++w) {
        float v = row[w];
        re = fmaf(v, ctab[t], re);
        im = fmaf(v, stab[t], im);
        t = (t + kx) & 127;
      }
      int idx = (h0 + hr) * 16 + kx;
      XwRe[idx] = re;
      XwIm[idx] = -im;  // e^{-i theta}
    }
  }
  __syncthreads();
  // stage 2: DFT along h for the 32 kept rows (0..15, 112..127)
  for (int e = tid; e < 512; e += 256) {
    int m = e >> 4, kx = e & 15;
    int ky = (m < 16) ? m : (m + 96);
    float re = 0.f, im = 0.f;
    for (int h = 0; h < 128; ++h) {
      int t = (ky * h) & 127;
      float c = ctab[t], s = stab[t];
      float ar = XwRe[h * 16 + kx], ai = XwIm[h * 16 + kx];
      re += ar * c + ai * s;  // (ar+i*ai)*(c - i*s)
      im += ai * c - ar * s;
    }
    size_t off = (size_t)bc * 512 + e;
    XfRe[off] = re;
    XfIm[off] = im;
  }
}

// ---------------- per-mode complex channel mixing (in-place) ----------------
__global__ __launch_bounds__(256) void mode_mix_kernel(
    float* __restrict__ XfRe, float* __restrict__ XfIm,
    const float* __restrict__ w1r, const float* __restrict__ w1i,
    const float* __restrict__ w2r, const float* __restrict__ w2i) {
  __shared__ float Wr[4096];
  __shared__ float Wi[4096];
  __shared__ float Ar[1024];
  __shared__ float Ai[1024];
  const int tid = threadIdx.x;
  const int mode = blockIdx.x;  // m*16+kx, m in 0..31
  const int m = mode >> 4, kx = mode & 15;
  const float* wr = (m < 16) ? w1r : w2r;
  const float* wi = (m < 16) ? w1i : w2i;
  const int woff = (m & 15) * 16 + kx;
  for (int e = tid; e < 4096; e += 256) {  // W[i][o] slice for this mode
    Wr[e] = wr[(size_t)e * 256 + woff];
    Wi[e] = wi[(size_t)e * 256 + woff];
  }
  for (int e = tid; e < 1024; e += 256) {  // A[b][i] slice
    Ar[e] = XfRe[(size_t)e * 512 + mode];
    Ai[e] = XfIm[(size_t)e * 512 + mode];
  }
  __syncthreads();
  const int o = tid & 63;
  const int b0 = tid >> 6;
  float outR[4], outI[4];
#pragma unroll
  for (int bb = 0; bb < 4; ++bb) {
    const int b = b0 * 4 + bb;
    float re = 0.f, im = 0.f;
    for (int i = 0; i < 64; ++i) {
      float ar = Ar[b * 64 + i], ai = Ai[b * 64 + i];
      float br = Wr[i * 64 + o], bi = Wi[i * 64 + o];
      re += ar * br - ai * bi;
      im += ar * bi + ai * br;
    }
    outR[bb] = re;
    outI[bb] = im;
  }
#pragma unroll
  for (int bb = 0; bb < 4; ++bb) {
    const int b = b0 * 4 + bb;
    size_t off = (size_t)(b * 64 + o) * 512 + mode;
    XfRe[off] = outR[bb];
    XfIm[off] = outI[bb];
  }
}

// ---------------- inverse DFT along h ----------------
__global__ __launch_bounds__(256) void inv_h_kernel(
    const float* __restrict__ GfRe, const float* __restrict__ GfIm,
    float* __restrict__ Y1Re, float* __restrict__ Y1Im) {
  __shared__ float Gr[512];
  __shared__ float Gi[512];
  __shared__ float ctab[128];
  __shared__ float stab[128];
  const int tid = threadIdx.x;
  const int bo = blockIdx.x;  // b*64+o
  if (tid < 128) {
    float s, c;
    sincosf((float)((double)tid * (6.283185307179586476925287 / 128.0)), &s, &c);
    ctab[tid] = c;
    stab[tid] = s;
  }
  for (int e = tid; e < 512; e += 256) {
    Gr[e] = GfRe[(size_t)bo * 512 + e];
    Gi[e] = GfIm[(size_t)bo * 512 + e];
  }
  __syncthreads();
  for (int e = tid; e < 2048; e += 256) {
    int h = e >> 4, kx = e & 15;
    float re = 0.f, im = 0.f;
#pragma unroll
    for (int m = 0; m < 32; ++m) {
      int ky = (m < 16) ? m : (m + 96);
      int t = (ky * h) & 127;
      float c = ctab[t], s = stab[t];
      float gr = Gr[m * 16 + kx], gi = Gi[m * 16 + kx];
      re += gr * c - gi * s;  // e^{+i theta}
      im += gr * s + gi * c;
    }
    size_t off = (size_t)bo * 2048 + e;
    Y1Re[off] = re;
    Y1Im[off] = im;
  }
}

// ---------------- inverse c2r along w + 1x1 conv + bias ----------------
__global__ __launch_bounds__(256) void invw_conv_kernel(
    const float* __restrict__ x,
    const float* __restrict__ Y1Re, const float* __restrict__ Y1Im,
    const float* __restrict__ convw, const float* __restrict__ convb,
    float* __restrict__ y) {
  __shared__ __align__(16) float xrow[64 * 128];
  __shared__ float cw[4096];
  __shared__ float yr[1024];
  __shared__ float yi[1024];
  __shared__ float cb[64];
  __shared__ float ctab[128];
  __shared__ float stab[128];
  const int tid = threadIdx.x;
  const int b = blockIdx.x >> 7, h = blockIdx.x & 127;
  if (tid < 128) {
    float s, c;
    sincosf((float)((double)tid * (6.283185307179586476925287 / 128.0)), &s, &c);
    ctab[tid] = c;
    stab[tid] = s;
  }
  const float4* x4 = (const float4*)x;
  for (int e = tid; e < 2048; e += 256) {
    int c = e >> 5, w4 = e & 31;
    ((float4*)xrow)[c * 32 + w4] = x4[((size_t)(b * 64 + c) * 128 + h) * 32 + w4];
  }
  for (int e = tid; e < 4096; e += 256) cw[e] = convw[e];
  if (tid < 64) cb[tid] = convb[tid];
  for (int e = tid; e < 1024; e += 256) {
    int o = e >> 4, kx = e & 15;
    size_t off = ((size_t)(b * 64 + o) * 128 + h) * 16 + kx;
    yr[e] = Y1Re[off];
    yi[e] = Y1Im[off];
  }
  __syncthreads();
  for (int e = tid; e < 8192; e += 256) {
    int o = e >> 7, w = e & 127;
    const float* yro = yr + o * 16;
    const float* yio = yi + o * 16;
    float acc = yro[0];  // imag of kx=0 bin ignored (pocketfft c2r convention)
#pragma unroll
    for (int kx = 1; kx < 16; ++kx) {
      int t = (kx * w) & 127;
      acc += 2.f * (yro[kx] * ctab[t] - yio[kx] * stab[t]);
    }
    acc *= (1.f / 16384.f);
    float a2 = cb[o];
#pragma unroll 8
    for (int c = 0; c < 64; ++c) a2 = fmaf(xrow[c * 128 + w], cw[o * 64 + c], a2);
    y[((size_t)(b * 64 + o) * 128 + h) * 128 + w] = acc + a2;
  }
}

// ---------------- KAN weight prep: transposed + scaled, float4-packed -------
__global__ __launch_bounds__(256) void prep_w_kernel(
    const float* __restrict__ base_w, const float* __restrict__ spline_w,
    const float* __restrict__ scaler, float* __restrict__ Wq) {
  int idx = blockIdx.x * 256 + threadIdx.x;
  if (idx >= 576 * 64) return;
  int k = idx >> 6, o = idx & 63;
  float val;
  if (k < 64) {
    val = base_w[o * 64 + k];
  } else {
    int c = (k - 64) >> 3, j = (k - 64) & 7;
    val = spline_w[(o * 64 + c) * 8 + j] * scaler[o * 64 + c];
  }
  Wq[((k >> 2) * 64 + o) * 4 + (k & 3)] = val;
}

// ---------------- cubic B-spline bases (GRID_SIZE=5, order=3, 8 bases) ------
// Consistent knot array: K[t] = fl32(fl32((t-3)*0.4f) - 1.0f), matching the
// reference's  arange(-3,9,f32) * 0.4f - 1.0f  arithmetic. Gap/overlap-free.
__device__ __forceinline__ void bspline8(float v, float* bs) {
  float K[12];
#pragma unroll
  for (int t = 0; t < 12; ++t)
    K[t] = __fsub_rn(__fmul_rn((float)(t - 3), 0.4f), 1.0f);
  float b0[11];
#pragma unroll
  for (int t = 0; t < 11; ++t)
    b0[t] = (v >= K[t] && v < K[t + 1]) ? 1.f : 0.f;
  float b1[10];
#pragma unroll
  for (int t = 0; t < 10; ++t)
    b1[t] = ((v - K[t]) * b0[t] + (K[t + 2] - v) * b0[t + 1]) * 2.5f;
  float b2[9];
#pragma unroll
  for (int t = 0; t < 9; ++t)
    b2[t] = ((v - K[t]) * b1[t] + (K[t + 3] - v) * b1[t + 1]) * 1.25f;
#pragma unroll
  for (int t = 0; t < 8; ++t)
    bs[t] = ((v - K[t]) * b2[t] + (K[t + 4] - v) * b2[t + 1]) * (1.f / 1.2f);
}

// ---------------- KAN layer (in-place safe; optional exact GELU) ------------
template <bool GELU>
__global__ __launch_bounds__(256) void kan_kernel(
    const float* __restrict__ in, float* __restrict__ out,
    const float4* __restrict__ Wq) {
  __shared__ __align__(16) float F[16 * 580];  // 16 pixels x 576 features (pad 580)
  const int tid = threadIdx.x;
  const int n0 = blockIdx.x * 16;  // flat pixel base: b*16384 + h*128 + w
  const size_t abase = (size_t)(n0 >> 14) * (64 * 16384) + (size_t)(n0 & 16383);
  const int p = tid & 15, c0 = tid >> 4;
  // phase 1: features
  float bs[8];
#pragma unroll
  for (int ci = 0; ci < 4; ++ci) {
    const int c = c0 * 4 + ci;
    float v = in[abase + (size_t)c * 16384 + p];
    float sg = 1.f / (1.f + expf(-v));
    F[p * 580 + c] = v * sg;  // silu
    bspline8(v, bs);
    float4* dst = (float4*)&F[p * 580 + 64 + c * 8];
    dst[0] = make_float4(bs[0], bs[1], bs[2], bs[3]);
    dst[1] = make_float4(bs[4], bs[5], bs[6], bs[7]);
  }
  __syncthreads();
  // phase 2: out[p][o] = sum_k F[p][k] * Wt[k][o]
  const int o = tid & 63, g = tid >> 6;
  float acc[4] = {0.f, 0.f, 0.f, 0.f};
#pragma unroll 2
  for (int kc = 0; kc < 144; ++kc) {
    const float4 w4 = Wq[kc * 64 + o];
#pragma unroll
    for (int pp = 0; pp < 4; ++pp) {
      const float4 f4 = *((const float4*)&F[(g * 4 + pp) * 580 + kc * 4]);
      float a = acc[pp];
      a = fmaf(f4.x, w4.x, a);
      a = fmaf(f4.y, w4.y, a);
      a = fmaf(f4.z, w4.z, a);
      a = fmaf(f4.w, w4.w, a);
      acc[pp] = a;
    }
  }
  __syncthreads();
  // stage outputs (padded stride 65 -> conflict-free)
#pragma unroll
  for (int pp = 0; pp < 4; ++pp) F[(g * 4 + pp) * 65 + o] = acc[pp];
  __syncthreads();
#pragma unroll
  for (int ci = 0; ci < 4; ++ci) {
    const int c = c0 * 4 + ci;
    float v = F[p * 65 + c];
    if (GELU) v = 0.5f * v * (1.f + erff(v * 0.70710678118654752f));
    out[abase + (size_t)c * 16384 + p] = v;
  }
}

// ---------------------------------------------------------------------------
extern "C" void kernel_launch(void* const* d_in, const int* in_sizes, int n_in,
                              void* d_out, int out_size, void* d_ws, size_t ws_size,
                              hipStream_t stream) {
  const float* x    = (const float*)d_in[0];
  const float* w1r  = (const float*)d_in[1];
  const float* w1i  = (const float*)d_in[2];
  const float* w2r  = (const float*)d_in[3];
  const float* w2i  = (const float*)d_in[4];
  const float* cw   = (const float*)d_in[5];
  const float* cb   = (const float*)d_in[6];
  const float* k1b  = (const float*)d_in[7];
  const float* k1s  = (const float*)d_in[8];
  const float* k1sc = (const float*)d_in[9];
  const float* k2b  = (const float*)d_in[10];
  const float* k2s  = (const float*)d_in[11];
  const float* k2sc = (const float*)d_in[12];

  char* ws = (char*)d_ws;
  float* XfRe = (float*)(ws + 0);          // 2 MB   (16*64*32*16 f32)
  float* XfIm = (float*)(ws + 2097152);    // 2 MB
  float* Y1Re = (float*)(ws + 4194304);    // 8 MB   (16*64*128*16 f32)
  float* Y1Im = (float*)(ws + 12582912);   // 8 MB
  float* Wq1  = (float*)(ws + 20971520);   // 147456 B
  float* Wq2  = (float*)(ws + 21118976);   // 147456 B
  float* y = (float*)d_out;                // d_out doubles as the big intermediate

  prep_w_kernel<<<144, 256, 0, stream>>>(k1b, k1s, k1sc, Wq1);
  prep_w_kernel<<<144, 256, 0, stream>>>(k2b, k2s, k2sc, Wq2);
  fwd_dft_kernel<<<1024, 256, 0, stream>>>(x, XfRe, XfIm);
  mode_mix_kernel<<<512, 256, 0, stream>>>(XfRe, XfIm, w1r, w1i, w2r, w2i);
  inv_h_kernel<<<1024, 256, 0, stream>>>(XfRe, XfIm, Y1Re, Y1Im);
  invw_conv_kernel<<<2048, 256, 0, stream>>>(x, Y1Re, Y1Im, cw, cb, y);
  kan_kernel<false><<<16384, 256, 0, stream>>>(y, y, (const float4*)Wq1);
  kan_kernel<true><<<16384, 256, 0, stream>>>(y, y, (const float4*)Wq2);
}

// Round 4
// 654.889 us; speedup vs baseline: 1.8092x; 1.8092x over previous
//
#include <hip/hip_runtime.h>

// ---------------------------------------------------------------------------
// KAN-FNO block, MI355X.
//   1. fwd_dft:   truncated separable rfft2 -> Xf[b,c,32,16]
//   2. mode_mix:  per-mode 16x64x64 complex GEMM (in-place on Xf)
//   3. inv_h:     inverse DFT along h -> Y1[b,o,128,16]
//   4. invw_conv: inverse c2r along w + 1x1 conv + bias -> y (d_out scratch)
//   5. kan_fused: BOTH KAN layers via MFMA f16 (features fp16 in LDS,
//                 weights as register fragments) + exact GELU, in-place.
// R4: KAN moved from scalar fp32 VALU (2x470us, VALUBusy~108%, MfmaUtil 0)
//     to mfma_f32_16x16x32_f16 with fused layers.
// ---------------------------------------------------------------------------

typedef _Float16 half8 __attribute__((ext_vector_type(8)));
typedef float f32x4 __attribute__((ext_vector_type(4)));

// ---------------- forward truncated rfft2 ----------------
__global__ __launch_bounds__(256) void fwd_dft_kernel(
    const float* __restrict__ x, float* __restrict__ XfRe, float* __restrict__ XfIm) {
  __shared__ __align__(16) float img[64 * 132];
  __shared__ float XwRe[128 * 16];
  __shared__ float XwIm[128 * 16];
  __shared__ float ctab[128];
  __shared__ float stab[128];
  const int tid = threadIdx.x;
  const int bc = blockIdx.x;
  const float4* src4 = (const float4*)(x + (size_t)bc * 16384);
  if (tid < 128) {
    float s, c;
    sincosf((float)((double)tid * (6.283185307179586476925287 / 128.0)), &s, &c);
    ctab[tid] = c;
    stab[tid] = s;
  }
  for (int h0 = 0; h0 < 128; h0 += 64) {
    __syncthreads();
    for (int e = tid; e < 2048; e += 256) {
      int r = e >> 5, w4 = e & 31;
      float4 v = src4[(h0 + r) * 32 + w4];
      *((float4*)&img[r * 132 + w4 * 4]) = v;
    }
    __syncthreads();
    for (int e = tid; e < 1024; e += 256) {
      int hr = e >> 4, kx = e & 15;
      const float* row = img + hr * 132;
      float re = 0.f, im = 0.f;
      int t = 0;
#pragma unroll 8
      for (int w = 0; w < 128; ++w) {
        float v = row[w];
        re = fmaf(v, ctab[t], re);
        im = fmaf(v, stab[t], im);
        t = (t + kx) & 127;
      }
      int idx = (h0 + hr) * 16 + kx;
      XwRe[idx] = re;
      XwIm[idx] = -im;
    }
  }
  __syncthreads();
  for (int e = tid; e < 512; e += 256) {
    int m = e >> 4, kx = e & 15;
    int ky = (m < 16) ? m : (m + 96);
    float re = 0.f, im = 0.f;
    for (int h = 0; h < 128; ++h) {
      int t = (ky * h) & 127;
      float c = ctab[t], s = stab[t];
      float ar = XwRe[h * 16 + kx], ai = XwIm[h * 16 + kx];
      re += ar * c + ai * s;
      im += ai * c - ar * s;
    }
    size_t off = (size_t)bc * 512 + e;
    XfRe[off] = re;
    XfIm[off] = im;
  }
}

// ---------------- per-mode complex channel mixing (in-place) ----------------
__global__ __launch_bounds__(256) void mode_mix_kernel(
    float* __restrict__ XfRe, float* __restrict__ XfIm,
    const float* __restrict__ w1r, const float* __restrict__ w1i,
    const float* __restrict__ w2r, const float* __restrict__ w2i) {
  __shared__ float Wr[4096];
  __shared__ float Wi[4096];
  __shared__ float Ar[1024];
  __shared__ float Ai[1024];
  const int tid = threadIdx.x;
  const int mode = blockIdx.x;
  const int m = mode >> 4, kx = mode & 15;
  const float* wr = (m < 16) ? w1r : w2r;
  const float* wi = (m < 16) ? w1i : w2i;
  const int woff = (m & 15) * 16 + kx;
  for (int e = tid; e < 4096; e += 256) {
    Wr[e] = wr[(size_t)e * 256 + woff];
    Wi[e] = wi[(size_t)e * 256 + woff];
  }
  for (int e = tid; e < 1024; e += 256) {
    Ar[e] = XfRe[(size_t)e * 512 + mode];
    Ai[e] = XfIm[(size_t)e * 512 + mode];
  }
  __syncthreads();
  const int o = tid & 63;
  const int b0 = tid >> 6;
  float outR[4], outI[4];
#pragma unroll
  for (int bb = 0; bb < 4; ++bb) {
    const int b = b0 * 4 + bb;
    float re = 0.f, im = 0.f;
    for (int i = 0; i < 64; ++i) {
      float ar = Ar[b * 64 + i], ai = Ai[b * 64 + i];
      float br = Wr[i * 64 + o], bi = Wi[i * 64 + o];
      re += ar * br - ai * bi;
      im += ar * bi + ai * br;
    }
    outR[bb] = re;
    outI[bb] = im;
  }
#pragma unroll
  for (int bb = 0; bb < 4; ++bb) {
    const int b = b0 * 4 + bb;
    size_t off = (size_t)(b * 64 + o) * 512 + mode;
    XfRe[off] = outR[bb];
    XfIm[off] = outI[bb];
  }
}

// ---------------- inverse DFT along h ----------------
__global__ __launch_bounds__(256) void inv_h_kernel(
    const float* __restrict__ GfRe, const float* __restrict__ GfIm,
    float* __restrict__ Y1Re, float* __restrict__ Y1Im) {
  __shared__ float Gr[512];
  __shared__ float Gi[512];
  __shared__ float ctab[128];
  __shared__ float stab[128];
  const int tid = threadIdx.x;
  const int bo = blockIdx.x;
  if (tid < 128) {
    float s, c;
    sincosf((float)((double)tid * (6.283185307179586476925287 / 128.0)), &s, &c);
    ctab[tid] = c;
    stab[tid] = s;
  }
  for (int e = tid; e < 512; e += 256) {
    Gr[e] = GfRe[(size_t)bo * 512 + e];
    Gi[e] = GfIm[(size_t)bo * 512 + e];
  }
  __syncthreads();
  for (int e = tid; e < 2048; e += 256) {
    int h = e >> 4, kx = e & 15;
    float re = 0.f, im = 0.f;
#pragma unroll
    for (int m = 0; m < 32; ++m) {
      int ky = (m < 16) ? m : (m + 96);
      int t = (ky * h) & 127;
      float c = ctab[t], s = stab[t];
      float gr = Gr[m * 16 + kx], gi = Gi[m * 16 + kx];
      re += gr * c - gi * s;
      im += gr * s + gi * c;
    }
    size_t off = (size_t)bo * 2048 + e;
    Y1Re[off] = re;
    Y1Im[off] = im;
  }
}

// ---------------- inverse c2r along w + 1x1 conv + bias ----------------
__global__ __launch_bounds__(256) void invw_conv_kernel(
    const float* __restrict__ x,
    const float* __restrict__ Y1Re, const float* __restrict__ Y1Im,
    const float* __restrict__ convw, const float* __restrict__ convb,
    float* __restrict__ y) {
  __shared__ __align__(16) float xrow[64 * 128];
  __shared__ float cw[4096];
  __shared__ float yr[1024];
  __shared__ float yi[1024];
  __shared__ float cb[64];
  __shared__ float ctab[128];
  __shared__ float stab[128];
  const int tid = threadIdx.x;
  const int b = blockIdx.x >> 7, h = blockIdx.x & 127;
  if (tid < 128) {
    float s, c;
    sincosf((float)((double)tid * (6.283185307179586476925287 / 128.0)), &s, &c);
    ctab[tid] = c;
    stab[tid] = s;
  }
  const float4* x4 = (const float4*)x;
  for (int e = tid; e < 2048; e += 256) {
    int c = e >> 5, w4 = e & 31;
    ((float4*)xrow)[c * 32 + w4] = x4[((size_t)(b * 64 + c) * 128 + h) * 32 + w4];
  }
  for (int e = tid; e < 4096; e += 256) cw[e] = convw[e];
  if (tid < 64) cb[tid] = convb[tid];
  for (int e = tid; e < 1024; e += 256) {
    int o = e >> 4, kx = e & 15;
    size_t off = ((size_t)(b * 64 + o) * 128 + h) * 16 + kx;
    yr[e] = Y1Re[off];
    yi[e] = Y1Im[off];
  }
  __syncthreads();
  for (int e = tid; e < 8192; e += 256) {
    int o = e >> 7, w = e & 127;
    const float* yro = yr + o * 16;
    const float* yio = yi + o * 16;
    float acc = yro[0];  // imag of kx=0 bin ignored (pocketfft c2r convention)
#pragma unroll
    for (int kx = 1; kx < 16; ++kx) {
      int t = (kx * w) & 127;
      acc += 2.f * (yro[kx] * ctab[t] - yio[kx] * stab[t]);
    }
    acc *= (1.f / 16384.f);
    float a2 = cb[o];
#pragma unroll 8
    for (int c = 0; c < 64; ++c) a2 = fmaf(xrow[c * 128 + w], cw[o * 64 + c], a2);
    y[((size_t)(b * 64 + o) * 128 + h) * 128 + w] = acc + a2;
  }
}

// ---------------- KAN weight prep: fp16 fragment-order -----------------
// out[(nt*18+ks)*64 + lane] = half8 of W[k0..k0+7][n],
// n = nt*16 + (lane&15), k0 = ks*32 + (lane>>4)*8.
__global__ __launch_bounds__(256) void prep_bfrag_kernel(
    const float* __restrict__ base_w, const float* __restrict__ spline_w,
    const float* __restrict__ scaler, half8* __restrict__ out) {
  int idx = blockIdx.x * 256 + threadIdx.x;
  if (idx >= 4608) return;
  int lane = idx & 63;
  int ks = (idx >> 6) % 18;
  int nt = idx / (64 * 18);
  int n = nt * 16 + (lane & 15);
  int k0 = ks * 32 + (lane >> 4) * 8;
  half8 hv;
#pragma unroll
  for (int j = 0; j < 8; ++j) {
    int k = k0 + j;
    float val;
    if (k < 64) {
      val = base_w[n * 64 + k];
    } else {
      int c = (k - 64) >> 3, jj = (k - 64) & 7;
      val = spline_w[(n * 64 + c) * 8 + jj] * scaler[n * 64 + c];
    }
    hv[j] = (_Float16)val;
  }
  out[idx] = hv;
}

// ---------------- KAN features: silu + 8 cubic B-spline bases ---------------
// Closed-form uniform cubic pieces (4 nonzero bases); knots match the
// reference's fp32 arange*0.4f-1.0f arithmetic. C2-continuity makes ulp-level
// knot/interval disagreement harmless (<<f16 rounding).
__device__ __forceinline__ void kan_features(float v, float* f9) {
  float sg = 1.f / (1.f + __expf(-v));
  f9[0] = v * sg;
  const float Klo = __fsub_rn(__fmul_rn(-3.f, 0.4f), 1.f);
  const float Khi = __fsub_rn(__fmul_rn(8.f, 0.4f), 1.f);
  int i = (int)floorf((v - Klo) * 2.5f);
  i = min(max(i, 0), 10);
  if (!(v >= Klo && v < Khi)) i = -100;  // all bases zero outside grid
  float Ki = __fsub_rn(__fmul_rn((float)(i - 3), 0.4f), 1.f);
  float t = (v - Ki) * 2.5f;
  float t2 = t * t, t3 = t2 * t;
  float p0 = t3 * (1.f / 6.f);
  float omt = 1.f - t;
  float p3 = omt * omt * omt * (1.f / 6.f);
  float p1 = (1.f + 3.f * t + 3.f * t2 - 3.f * t3) * (1.f / 6.f);
  float p2 = (3.f * t3 - 6.f * t2 + 4.f) * (1.f / 6.f);
#pragma unroll
  for (int j = 0; j < 8; ++j) {
    int d = i - j;
    f9[1 + j] = (d == 0) ? p0 : (d == 1) ? p1 : (d == 2) ? p2 : (d == 3) ? p3 : 0.f;
  }
}

// Write one (px,c)'s 9 features into swizzled fp16 LDS tile A[64][576].
__device__ __forceinline__ void write_feat(char* A, int px, int c, float v) {
  float f9[9];
  kan_features(v, f9);
  unsigned swz = (unsigned)(((px & 7) ^ ((px >> 3) & 7)) << 4);
  unsigned rb = (unsigned)px * 1152u;
  *(_Float16*)(A + ((rb + (unsigned)c * 2u) ^ swz)) = (_Float16)f9[0];
  half8 hv;
#pragma unroll
  for (int j = 0; j < 8; ++j) hv[j] = (_Float16)f9[1 + j];
  *(half8*)(A + ((rb + 128u + (unsigned)c * 16u) ^ swz)) = hv;
}

__device__ __forceinline__ void gemm_tile(const char* A, const half8* Bf,
                                          const unsigned* rdbase, unsigned swz,
                                          f32x4* acc) {
#pragma unroll
  for (int ks = 0; ks < 18; ++ks) {
#pragma unroll
    for (int mt = 0; mt < 4; ++mt) {
      half8 a = *(const half8*)(A + ((rdbase[mt] + (unsigned)ks * 64u) ^ swz));
      acc[mt] = __builtin_amdgcn_mfma_f32_16x16x32_f16(a, Bf[ks], acc[mt], 0, 0, 0);
    }
  }
}

// ---------------- fused 2x KAN layer + GELU (in-place on y) -----------------
// Block: 64 pixels (contiguous in w), 256 threads = 4 waves.
// Wave nt owns output columns nt*16..nt*16+15; loops over 4 m-tiles of 16 px.
__global__ __launch_bounds__(256, 2) void kan_fused_kernel(
    float* __restrict__ y, const half8* __restrict__ Bq1,
    const half8* __restrict__ Bq2) {
  __shared__ __align__(16) char A[64 * 1152];  // 64 px x 576 k, fp16, swizzled
  const int tid = threadIdx.x;
  const int l = tid & 63;
  const int nt = tid >> 6;
  const int rit = l & 15, g = l >> 4;
  const int n0 = blockIdx.x * 64;
  const int b = n0 >> 14;
  const int rem = n0 & 16383;
  const int h = rem >> 7, w0 = rem & 127;
  float* base = y + (size_t)b * 1048576 + (size_t)h * 128 + w0;

  // ---- layer-1 features from global ----
  {
    const int cb = tid >> 4;          // 0..15
    const int px0 = (tid & 15) * 4;   // 0..60
#pragma unroll
    for (int ci = 0; ci < 4; ++ci) {
      const int c = cb + 16 * ci;
      float4 v4 = *(const float4*)(base + (size_t)c * 16384 + px0);
      write_feat(A, px0 + 0, c, v4.x);
      write_feat(A, px0 + 1, c, v4.y);
      write_feat(A, px0 + 2, c, v4.z);
      write_feat(A, px0 + 3, c, v4.w);
    }
  }
  // ---- weight fragments layer 1 (held in VGPRs, reused over 4 m-tiles) ----
  half8 Bf[18];
#pragma unroll
  for (int ks = 0; ks < 18; ++ks) Bf[ks] = Bq1[(nt * 18 + ks) * 64 + l];

  unsigned rdbase[4];
  unsigned swzmask = (unsigned)(((0) ^ (0)) << 4);  // per-mt row swz folded below
  unsigned rswz[4];
#pragma unroll
  for (int mt = 0; mt < 4; ++mt) {
    int row = mt * 16 + rit;
    rdbase[mt] = (unsigned)row * 1152u + (unsigned)g * 16u;
    rswz[mt] = (unsigned)(((row & 7) ^ ((row >> 3) & 7)) << 4);
    rdbase[mt] ^= 0;  // keep rdbase pre-XOR; apply rswz per access
  }
  __syncthreads();

  f32x4 acc[4];
#pragma unroll
  for (int mt = 0; mt < 4; ++mt) acc[mt] = {0.f, 0.f, 0.f, 0.f};
  // GEMM 1 (swizzle depends on row -> per-mt XOR; fold into rdbase since
  // rdbase bits 4-6 are (g*16) only and ks*64 adds bits>=6 w/o carry)
#pragma unroll
  for (int ks = 0; ks < 18; ++ks) {
#pragma unroll
    for (int mt = 0; mt < 4; ++mt) {
      half8 a = *(const half8*)(A + ((rdbase[mt] + (unsigned)ks * 64u) ^ rswz[mt]));
      acc[mt] = __builtin_amdgcn_mfma_f32_16x16x32_f16(a, Bf[ks], acc[mt], 0, 0, 0);
    }
  }
  __syncthreads();  // all reads of A done before overwrite

  // ---- layer-2 weight fragments (overlap load with feature rebuild) ----
#pragma unroll
  for (int ks = 0; ks < 18; ++ks) Bf[ks] = Bq2[(nt * 18 + ks) * 64 + l];

  // ---- layer-2 features from layer-1 accumulators ----
  {
    const int c = nt * 16 + rit;  // C/D: col = lane&15 -> this lane's out chan
#pragma unroll
    for (int mt = 0; mt < 4; ++mt)
#pragma unroll
      for (int r = 0; r < 4; ++r)
        write_feat(A, mt * 16 + g * 4 + r, c, acc[mt][r]);  // row=(lane>>4)*4+r
  }
  __syncthreads();

#pragma unroll
  for (int mt = 0; mt < 4; ++mt) acc[mt] = {0.f, 0.f, 0.f, 0.f};
#pragma unroll
  for (int ks = 0; ks < 18; ++ks) {
#pragma unroll
    for (int mt = 0; mt < 4; ++mt) {
      half8 a = *(const half8*)(A + ((rdbase[mt] + (unsigned)ks * 64u) ^ rswz[mt]));
      acc[mt] = __builtin_amdgcn_mfma_f32_16x16x32_f16(a, Bf[ks], acc[mt], 0, 0, 0);
    }
  }

  // ---- exact GELU + store ----
  {
    float* dst = base + (size_t)(nt * 16 + rit) * 16384;
#pragma unroll
    for (int mt = 0; mt < 4; ++mt)
#pragma unroll
      for (int r = 0; r < 4; ++r) {
        float v = acc[mt][r];
        v = 0.5f * v * (1.f + erff(v * 0.70710678118654752f));
        dst[mt * 16 + g * 4 + r] = v;
      }
  }
}

// ---------------------------------------------------------------------------
extern "C" void kernel_launch(void* const* d_in, const int* in_sizes, int n_in,
                              void* d_out, int out_size, void* d_ws, size_t ws_size,
                              hipStream_t stream) {
  const float* x    = (const float*)d_in[0];
  const float* w1r  = (const float*)d_in[1];
  const float* w1i  = (const float*)d_in[2];
  const float* w2r  = (const float*)d_in[3];
  const float* w2i  = (const float*)d_in[4];
  const float* cw   = (const float*)d_in[5];
  const float* cb   = (const float*)d_in[6];
  const float* k1b  = (const float*)d_in[7];
  const float* k1s  = (const float*)d_in[8];
  const float* k1sc = (const float*)d_in[9];
  const float* k2b  = (const float*)d_in[10];
  const float* k2s  = (const float*)d_in[11];
  const float* k2sc = (const float*)d_in[12];

  char* ws = (char*)d_ws;
  float* XfRe = (float*)(ws + 0);          // 2 MB
  float* XfIm = (float*)(ws + 2097152);    // 2 MB
  float* Y1Re = (float*)(ws + 4194304);    // 8 MB
  float* Y1Im = (float*)(ws + 12582912);   // 8 MB
  half8* Bf1  = (half8*)(ws + 20971520);   // 73728 B
  half8* Bf2  = (half8*)(ws + 21045248);   // 73728 B
  float* y = (float*)d_out;                // d_out doubles as the intermediate

  prep_bfrag_kernel<<<18, 256, 0, stream>>>(k1b, k1s, k1sc, Bf1);
  prep_bfrag_kernel<<<18, 256, 0, stream>>>(k2b, k2s, k2sc, Bf2);
  fwd_dft_kernel<<<1024, 256, 0, stream>>>(x, XfRe, XfIm);
  mode_mix_kernel<<<512, 256, 0, stream>>>(XfRe, XfIm, w1r, w1i, w2r, w2i);
  inv_h_kernel<<<1024, 256, 0, stream>>>(XfRe, XfIm, Y1Re, Y1Im);
  invw_conv_kernel<<<2048, 256, 0, stream>>>(x, Y1Re, Y1Im, cw, cb, y);
  kan_fused_kernel<<<4096, 256, 0, stream>>>(y, Bf1, Bf2);
}

// Round 5
// 546.422 us; speedup vs baseline: 2.1683x; 1.1985x over previous
//
#include <hip/hip_runtime.h>

// ---------------------------------------------------------------------------
// KAN-FNO block, MI355X.
//   1. fwd_dft:   truncated separable rfft2 -> Xf[b,c,32,16]
//   2. mode_mix:  per-mode 16x64x64 complex GEMM (in-place on Xf)
//   3. inv_h:     inverse DFT along h -> Y1[b,o,128,16]
//   4. invw_conv: inverse c2r along w + 1x1 conv + bias -> y (d_out scratch)
//   5. kan_fused: BOTH KAN layers via MFMA f16 + exact GELU, in-place.
// R5: kan_fused was latency-bound (Occ 23% = 2 blocks/CU LDS cap, VALU 36%,
//     Mfma 4.7%). Now: 2x 16-px LDS slots (37,376 B -> 4 blocks/CU) with a
//     9-phase pipeline {GEMM(p) || features(p+1)} per phase; padded rows
//     (1168 B) instead of XOR swizzle (<=2-way banks); vector-only LDS writes
//     for layer-1; float4 output stores.
// ---------------------------------------------------------------------------

typedef _Float16 half8 __attribute__((ext_vector_type(8)));
typedef _Float16 half4 __attribute__((ext_vector_type(4)));
typedef float f32x4 __attribute__((ext_vector_type(4)));

#define ROWB 1168  // LDS bytes per pixel row: 576 fp16 = 1152 + 16 pad

// ---------------- forward truncated rfft2 ----------------
__global__ __launch_bounds__(256) void fwd_dft_kernel(
    const float* __restrict__ x, float* __restrict__ XfRe, float* __restrict__ XfIm) {
  __shared__ __align__(16) float img[64 * 132];
  __shared__ float XwRe[128 * 16];
  __shared__ float XwIm[128 * 16];
  __shared__ float ctab[128];
  __shared__ float stab[128];
  const int tid = threadIdx.x;
  const int bc = blockIdx.x;
  const float4* src4 = (const float4*)(x + (size_t)bc * 16384);
  if (tid < 128) {
    float s, c;
    sincosf((float)((double)tid * (6.283185307179586476925287 / 128.0)), &s, &c);
    ctab[tid] = c;
    stab[tid] = s;
  }
  for (int h0 = 0; h0 < 128; h0 += 64) {
    __syncthreads();
    for (int e = tid; e < 2048; e += 256) {
      int r = e >> 5, w4 = e & 31;
      float4 v = src4[(h0 + r) * 32 + w4];
      *((float4*)&img[r * 132 + w4 * 4]) = v;
    }
    __syncthreads();
    for (int e = tid; e < 1024; e += 256) {
      int hr = e >> 4, kx = e & 15;
      const float* row = img + hr * 132;
      float re = 0.f, im = 0.f;
      int t = 0;
#pragma unroll 8
      for (int w = 0; w < 128; ++w) {
        float v = row[w];
        re = fmaf(v, ctab[t], re);
        im = fmaf(v, stab[t], im);
        t = (t + kx) & 127;
      }
      int idx = (h0 + hr) * 16 + kx;
      XwRe[idx] = re;
      XwIm[idx] = -im;
    }
  }
  __syncthreads();
  for (int e = tid; e < 512; e += 256) {
    int m = e >> 4, kx = e & 15;
    int ky = (m < 16) ? m : (m + 96);
    float re = 0.f, im = 0.f;
    for (int h = 0; h < 128; ++h) {
      int t = (ky * h) & 127;
      float c = ctab[t], s = stab[t];
      float ar = XwRe[h * 16 + kx], ai = XwIm[h * 16 + kx];
      re += ar * c + ai * s;
      im += ai * c - ar * s;
    }
    size_t off = (size_t)bc * 512 + e;
    XfRe[off] = re;
    XfIm[off] = im;
  }
}

// ---------------- per-mode complex channel mixing (in-place) ----------------
__global__ __launch_bounds__(256) void mode_mix_kernel(
    float* __restrict__ XfRe, float* __restrict__ XfIm,
    const float* __restrict__ w1r, const float* __restrict__ w1i,
    const float* __restrict__ w2r, const float* __restrict__ w2i) {
  __shared__ float Wr[4096];
  __shared__ float Wi[4096];
  __shared__ float Ar[1024];
  __shared__ float Ai[1024];
  const int tid = threadIdx.x;
  const int mode = blockIdx.x;
  const int m = mode >> 4, kx = mode & 15;
  const float* wr = (m < 16) ? w1r : w2r;
  const float* wi = (m < 16) ? w1i : w2i;
  const int woff = (m & 15) * 16 + kx;
  for (int e = tid; e < 4096; e += 256) {
    Wr[e] = wr[(size_t)e * 256 + woff];
    Wi[e] = wi[(size_t)e * 256 + woff];
  }
  for (int e = tid; e < 1024; e += 256) {
    Ar[e] = XfRe[(size_t)e * 512 + mode];
    Ai[e] = XfIm[(size_t)e * 512 + mode];
  }
  __syncthreads();
  const int o = tid & 63;
  const int b0 = tid >> 6;
  float outR[4], outI[4];
#pragma unroll
  for (int bb = 0; bb < 4; ++bb) {
    const int b = b0 * 4 + bb;
    float re = 0.f, im = 0.f;
    for (int i = 0; i < 64; ++i) {
      float ar = Ar[b * 64 + i], ai = Ai[b * 64 + i];
      float br = Wr[i * 64 + o], bi = Wi[i * 64 + o];
      re += ar * br - ai * bi;
      im += ar * bi + ai * br;
    }
    outR[bb] = re;
    outI[bb] = im;
  }
#pragma unroll
  for (int bb = 0; bb < 4; ++bb) {
    const int b = b0 * 4 + bb;
    size_t off = (size_t)(b * 64 + o) * 512 + mode;
    XfRe[off] = outR[bb];
    XfIm[off] = outI[bb];
  }
}

// ---------------- inverse DFT along h ----------------
__global__ __launch_bounds__(256) void inv_h_kernel(
    const float* __restrict__ GfRe, const float* __restrict__ GfIm,
    float* __restrict__ Y1Re, float* __restrict__ Y1Im) {
  __shared__ float Gr[512];
  __shared__ float Gi[512];
  __shared__ float ctab[128];
  __shared__ float stab[128];
  const int tid = threadIdx.x;
  const int bo = blockIdx.x;
  if (tid < 128) {
    float s, c;
    sincosf((float)((double)tid * (6.283185307179586476925287 / 128.0)), &s, &c);
    ctab[tid] = c;
    stab[tid] = s;
  }
  for (int e = tid; e < 512; e += 256) {
    Gr[e] = GfRe[(size_t)bo * 512 + e];
    Gi[e] = GfIm[(size_t)bo * 512 + e];
  }
  __syncthreads();
  for (int e = tid; e < 2048; e += 256) {
    int h = e >> 4, kx = e & 15;
    float re = 0.f, im = 0.f;
#pragma unroll
    for (int m = 0; m < 32; ++m) {
      int ky = (m < 16) ? m : (m + 96);
      int t = (ky * h) & 127;
      float c = ctab[t], s = stab[t];
      float gr = Gr[m * 16 + kx], gi = Gi[m * 16 + kx];
      re += gr * c - gi * s;
      im += gr * s + gi * c;
    }
    size_t off = (size_t)bo * 2048 + e;
    Y1Re[off] = re;
    Y1Im[off] = im;
  }
}

// ---------------- inverse c2r along w + 1x1 conv + bias ----------------
__global__ __launch_bounds__(256) void invw_conv_kernel(
    const float* __restrict__ x,
    const float* __restrict__ Y1Re, const float* __restrict__ Y1Im,
    const float* __restrict__ convw, const float* __restrict__ convb,
    float* __restrict__ y) {
  __shared__ __align__(16) float xrow[64 * 128];
  __shared__ float cw[4096];
  __shared__ float yr[1024];
  __shared__ float yi[1024];
  __shared__ float cb[64];
  __shared__ float ctab[128];
  __shared__ float stab[128];
  const int tid = threadIdx.x;
  const int b = blockIdx.x >> 7, h = blockIdx.x & 127;
  if (tid < 128) {
    float s, c;
    sincosf((float)((double)tid * (6.283185307179586476925287 / 128.0)), &s, &c);
    ctab[tid] = c;
    stab[tid] = s;
  }
  const float4* x4 = (const float4*)x;
  for (int e = tid; e < 2048; e += 256) {
    int c = e >> 5, w4 = e & 31;
    ((float4*)xrow)[c * 32 + w4] = x4[((size_t)(b * 64 + c) * 128 + h) * 32 + w4];
  }
  for (int e = tid; e < 4096; e += 256) cw[e] = convw[e];
  if (tid < 64) cb[tid] = convb[tid];
  for (int e = tid; e < 1024; e += 256) {
    int o = e >> 4, kx = e & 15;
    size_t off = ((size_t)(b * 64 + o) * 128 + h) * 16 + kx;
    yr[e] = Y1Re[off];
    yi[e] = Y1Im[off];
  }
  __syncthreads();
  for (int e = tid; e < 8192; e += 256) {
    int o = e >> 7, w = e & 127;
    const float* yro = yr + o * 16;
    const float* yio = yi + o * 16;
    float acc = yro[0];  // imag of kx=0 bin ignored (pocketfft c2r convention)
#pragma unroll
    for (int kx = 1; kx < 16; ++kx) {
      int t = (kx * w) & 127;
      acc += 2.f * (yro[kx] * ctab[t] - yio[kx] * stab[t]);
    }
    acc *= (1.f / 16384.f);
    float a2 = cb[o];
#pragma unroll 8
    for (int c = 0; c < 64; ++c) a2 = fmaf(xrow[c * 128 + w], cw[o * 64 + c], a2);
    y[((size_t)(b * 64 + o) * 128 + h) * 128 + w] = acc + a2;
  }
}

// ---------------- KAN weight prep: fp16 fragment-order -----------------
// out[(nt*18+ks)*64 + lane] = half8 of W[k0..k0+7][n],
// n = nt*16 + (lane&15), k0 = ks*32 + (lane>>4)*8.
__global__ __launch_bounds__(256) void prep_bfrag_kernel(
    const float* __restrict__ base_w, const float* __restrict__ spline_w,
    const float* __restrict__ scaler, half8* __restrict__ out) {
  int idx = blockIdx.x * 256 + threadIdx.x;
  if (idx >= 4608) return;
  int lane = idx & 63;
  int ks = (idx >> 6) % 18;
  int nt = idx / (64 * 18);
  int n = nt * 16 + (lane & 15);
  int k0 = ks * 32 + (lane >> 4) * 8;
  half8 hv;
#pragma unroll
  for (int j = 0; j < 8; ++j) {
    int k = k0 + j;
    float val;
    if (k < 64) {
      val = base_w[n * 64 + k];
    } else {
      int c = (k - 64) >> 3, jj = (k - 64) & 7;
      val = spline_w[(n * 64 + c) * 8 + jj] * scaler[n * 64 + c];
    }
    hv[j] = (_Float16)val;
  }
  out[idx] = hv;
}

// ---------------- KAN feature math ----------------
__device__ __forceinline__ float fast_silu(float v) {
  return v * (1.f / (1.f + __expf(-v)));
}

// Closed-form uniform cubic B-spline: 8 bases as half8. Knots match the
// reference's fp32 arange*0.4f-1.0f arithmetic; C2 continuity makes interval
// misclassification at knot ulps harmless (<< f16 rounding). Validated R4.
__device__ __forceinline__ half8 spline8h(float v) {
  const float Klo = __fsub_rn(__fmul_rn(-3.f, 0.4f), 1.f);
  const float Khi = __fsub_rn(__fmul_rn(8.f, 0.4f), 1.f);
  int i = (int)floorf((v - Klo) * 2.5f);
  i = min(max(i, 0), 10);
  bool inr = (v >= Klo && v < Khi);
  float Ki = __fsub_rn(__fmul_rn((float)(i - 3), 0.4f), 1.f);
  float t = (v - Ki) * 2.5f;
  float t2 = t * t, t3 = t2 * t;
  float p0 = t3 * (1.f / 6.f);
  float omt = 1.f - t;
  float p3 = omt * omt * omt * (1.f / 6.f);
  float p1 = (1.f + 3.f * t + 3.f * t2 - 3.f * t3) * (1.f / 6.f);
  float p2 = (3.f * t3 - 6.f * t2 + 4.f) * (1.f / 6.f);
  if (!inr) { p0 = 0.f; p1 = 0.f; p2 = 0.f; p3 = 0.f; }
  half8 h;
#pragma unroll
  for (int j = 0; j < 8; ++j) {
    int d = i - j;
    float f = (d == 0) ? p0 : (d == 1) ? p1 : (d == 2) ? p2 : (d == 3) ? p3 : 0.f;
    h[j] = (_Float16)f;
  }
  return h;
}

__device__ __forceinline__ float gelu_exact(float v) {
  return 0.5f * v * (1.f + erff(v * 0.70710678118654752f));
}

// Layer-1 features: thread owns (pixel pxl, channels cg*4..cg*4+3).
// silu -> one half4; splines -> 4x half8. All vector LDS writes.
__device__ __forceinline__ void feat_quad(char* S, const float* __restrict__ src,
                                          int pxl, int cg) {
  float v[4];
#pragma unroll
  for (int ci = 0; ci < 4; ++ci)
    v[ci] = src[(size_t)(cg * 4 + ci) * 16384 + pxl];
  char* row = S + pxl * ROWB;
  half4 s4;
#pragma unroll
  for (int ci = 0; ci < 4; ++ci) s4[ci] = (_Float16)fast_silu(v[ci]);
  *(half4*)(row + cg * 8) = s4;
#pragma unroll
  for (int ci = 0; ci < 4; ++ci)
    *(half8*)(row + 128 + (cg * 4 + ci) * 16) = spline8h(v[ci]);
}

// Layer-2 features from layer-1 accumulator (C/D map: col=lane&15 -> channel,
// row=(lane>>4)*4+reg -> pixel within group).
__device__ __forceinline__ void w2feat(char* S, int g, int nt, int rit, f32x4 a) {
  const int c = nt * 16 + rit;
#pragma unroll
  for (int r = 0; r < 4; ++r) {
    char* row = S + (g * 4 + r) * ROWB;
    float v = a[r];
    *(_Float16*)(row + c * 2) = (_Float16)fast_silu(v);
    *(half8*)(row + 128 + c * 16) = spline8h(v);
  }
}

// One 16x16x576 GEMM slice: 18 MFMAs on a 16-px LDS slot.
__device__ __forceinline__ void gemm_slot(const char* S, const half8* Bf,
                                          int rit, int g, f32x4& acc) {
  const char* pa = S + rit * ROWB + g * 16;
#pragma unroll
  for (int ks = 0; ks < 18; ++ks) {
    half8 a = *(const half8*)(pa + ks * 64);
    acc = __builtin_amdgcn_mfma_f32_16x16x32_f16(a, Bf[ks], acc, 0, 0, 0);
  }
}

__device__ __forceinline__ void store_grp(float* gbase, int nt, int rit, int g,
                                          f32x4 a) {
  float4 o;
  o.x = gelu_exact(a[0]);
  o.y = gelu_exact(a[1]);
  o.z = gelu_exact(a[2]);
  o.w = gelu_exact(a[3]);
  *(float4*)(gbase + (size_t)(nt * 16 + rit) * 16384 + g * 4) = o;
}

// ---------------- fused 2x KAN layer + GELU (in-place on y) -----------------
// Block: 64 pixels, 256 threads = 4 waves. 9-phase pipeline over two 16-px
// LDS slots: each phase = {GEMM(group p) || feature-build(group p+1)}.
__global__ __launch_bounds__(256, 4) void kan_fused_kernel(
    float* __restrict__ y, const half8* __restrict__ Bq1,
    const half8* __restrict__ Bq2) {
  __shared__ __align__(16) char Abuf[2 * 16 * ROWB];  // 37,376 B -> 4 blocks/CU
  char* A0 = Abuf;
  char* A1 = Abuf + 16 * ROWB;
  const int tid = threadIdx.x;
  const int l = tid & 63;
  const int nt = tid >> 6;
  const int rit = l & 15, g = l >> 4;
  const int pxl = tid & 15, cg = tid >> 4;
  const int n0 = blockIdx.x * 64;
  const int b = n0 >> 14;
  float* base = y + (size_t)b * 1048576 + (n0 & 16383);

  half8 B1[18], B2[18];
#pragma unroll
  for (int ks = 0; ks < 18; ++ks) B1[ks] = Bq1[(nt * 18 + ks) * 64 + l];
#pragma unroll
  for (int ks = 0; ks < 18; ++ks) B2[ks] = Bq2[(nt * 18 + ks) * 64 + l];

  const f32x4 z = {0.f, 0.f, 0.f, 0.f};
  f32x4 a10 = z, a11 = z, a12 = z, a13 = z;
  f32x4 a20 = z, a21 = z, a22 = z, a23 = z;

  // P0
  feat_quad(A0, base, pxl, cg);
  __syncthreads();
  // P1..P3: layer-1 GEMM(p) || features(p+1)
  gemm_slot(A0, B1, rit, g, a10); feat_quad(A1, base + 16, pxl, cg);
  __syncthreads();
  gemm_slot(A1, B1, rit, g, a11); feat_quad(A0, base + 32, pxl, cg);
  __syncthreads();
  gemm_slot(A0, B1, rit, g, a12); feat_quad(A1, base + 48, pxl, cg);
  __syncthreads();
  // P4: last layer-1 GEMM || first layer-2 feature build
  gemm_slot(A1, B1, rit, g, a13); w2feat(A0, g, nt, rit, a10);
  __syncthreads();
  // P5..P8: layer-2 GEMM(p) || layer-2 features(p+1); store after own GEMM
  gemm_slot(A0, B2, rit, g, a20); w2feat(A1, g, nt, rit, a11);
  store_grp(base, nt, rit, g, a20);
  __syncthreads();
  gemm_slot(A1, B2, rit, g, a21); w2feat(A0, g, nt, rit, a12);
  store_grp(base + 16, nt, rit, g, a21);
  __syncthreads();
  gemm_slot(A0, B2, rit, g, a22); w2feat(A1, g, nt, rit, a13);
  store_grp(base + 32, nt, rit, g, a22);
  __syncthreads();
  gemm_slot(A1, B2, rit, g, a23);
  store_grp(base + 48, nt, rit, g, a23);
}

// ---------------------------------------------------------------------------
extern "C" void kernel_launch(void* const* d_in, const int* in_sizes, int n_in,
                              void* d_out, int out_size, void* d_ws, size_t ws_size,
                              hipStream_t stream) {
  const float* x    = (const float*)d_in[0];
  const float* w1r  = (const float*)d_in[1];
  const float* w1i  = (const float*)d_in[2];
  const float* w2r  = (const float*)d_in[3];
  const float* w2i  = (const float*)d_in[4];
  const float* cw   = (const float*)d_in[5];
  const float* cb   = (const float*)d_in[6];
  const float* k1b  = (const float*)d_in[7];
  const float* k1s  = (const float*)d_in[8];
  const float* k1sc = (const float*)d_in[9];
  const float* k2b  = (const float*)d_in[10];
  const float* k2s  = (const float*)d_in[11];
  const float* k2sc = (const float*)d_in[12];

  char* ws = (char*)d_ws;
  float* XfRe = (float*)(ws + 0);          // 2 MB
  float* XfIm = (float*)(ws + 2097152);    // 2 MB
  float* Y1Re = (float*)(ws + 4194304);    // 8 MB
  float* Y1Im = (float*)(ws + 12582912);   // 8 MB
  half8* Bf1  = (half8*)(ws + 20971520);   // 73728 B
  half8* Bf2  = (half8*)(ws + 21045248);   // 73728 B
  float* y = (float*)d_out;                // d_out doubles as the intermediate

  prep_bfrag_kernel<<<18, 256, 0, stream>>>(k1b, k1s, k1sc, Bf1);
  prep_bfrag_kernel<<<18, 256, 0, stream>>>(k2b, k2s, k2sc, Bf2);
  fwd_dft_kernel<<<1024, 256, 0, stream>>>(x, XfRe, XfIm);
  mode_mix_kernel<<<512, 256, 0, stream>>>(XfRe, XfIm, w1r, w1i, w2r, w2i);
  inv_h_kernel<<<1024, 256, 0, stream>>>(XfRe, XfIm, Y1Re, Y1Im);
  invw_conv_kernel<<<2048, 256, 0, stream>>>(x, Y1Re, Y1Im, cw, cb, y);
  kan_fused_kernel<<<4096, 256, 0, stream>>>(y, Bf1, Bf2);
}

// Round 6
// 538.833 us; speedup vs baseline: 2.1988x; 1.0141x over previous
//
#include <hip/hip_runtime.h>

// ---------------------------------------------------------------------------
// KAN-FNO block, MI355X.
//   1. fwd_dft:   truncated separable rfft2 -> Xf[b,c,32,16]
//   2. mode_mix:  per-mode 16x64x64 complex GEMM (in-place on Xf), XCD-swizzled
//   3. inv_h:     inverse DFT along h -> Y1[b,o,128,16]
//   4. invw_conv: inverse c2r along w + 1x1 conv + bias -> y (d_out scratch)
//   5. kan_fused: BOTH KAN layers via MFMA f16 + exact GELU, in-place.
// R6: kan_fused had 450MB HBM traffic (2.4x read / 4.4x write amplification
//     from 64B-per-channel strided access). Now: y-tile staged through LDS
//     with full-line coalesced float4 loads (256B/channel/instr), feature
//     inputs register-cached; output GELU'd into an LDS bounce and stored
//     with one cooperative fully-coalesced pass. mode_mix gets a bijective
//     XCD-chunked block swizzle (kx-sibling blocks share weight lines).
// ---------------------------------------------------------------------------

typedef _Float16 half8 __attribute__((ext_vector_type(8)));
typedef _Float16 half4 __attribute__((ext_vector_type(4)));
typedef float f32x4 __attribute__((ext_vector_type(4)));

#define ROWB 1168  // LDS bytes per pixel row: 576 fp16 = 1152 + 16 pad

// ---------------- forward truncated rfft2 ----------------
__global__ __launch_bounds__(256) void fwd_dft_kernel(
    const float* __restrict__ x, float* __restrict__ XfRe, float* __restrict__ XfIm) {
  __shared__ __align__(16) float img[64 * 132];
  __shared__ float XwRe[128 * 16];
  __shared__ float XwIm[128 * 16];
  __shared__ float ctab[128];
  __shared__ float stab[128];
  const int tid = threadIdx.x;
  const int bc = blockIdx.x;
  const float4* src4 = (const float4*)(x + (size_t)bc * 16384);
  if (tid < 128) {
    float s, c;
    sincosf((float)((double)tid * (6.283185307179586476925287 / 128.0)), &s, &c);
    ctab[tid] = c;
    stab[tid] = s;
  }
  for (int h0 = 0; h0 < 128; h0 += 64) {
    __syncthreads();
    for (int e = tid; e < 2048; e += 256) {
      int r = e >> 5, w4 = e & 31;
      float4 v = src4[(h0 + r) * 32 + w4];
      *((float4*)&img[r * 132 + w4 * 4]) = v;
    }
    __syncthreads();
    for (int e = tid; e < 1024; e += 256) {
      int hr = e >> 4, kx = e & 15;
      const float* row = img + hr * 132;
      float re = 0.f, im = 0.f;
      int t = 0;
#pragma unroll 8
      for (int w = 0; w < 128; ++w) {
        float v = row[w];
        re = fmaf(v, ctab[t], re);
        im = fmaf(v, stab[t], im);
        t = (t + kx) & 127;
      }
      int idx = (h0 + hr) * 16 + kx;
      XwRe[idx] = re;
      XwIm[idx] = -im;
    }
  }
  __syncthreads();
  for (int e = tid; e < 512; e += 256) {
    int m = e >> 4, kx = e & 15;
    int ky = (m < 16) ? m : (m + 96);
    float re = 0.f, im = 0.f;
    for (int h = 0; h < 128; ++h) {
      int t = (ky * h) & 127;
      float c = ctab[t], s = stab[t];
      float ar = XwRe[h * 16 + kx], ai = XwIm[h * 16 + kx];
      re += ar * c + ai * s;
      im += ai * c - ar * s;
    }
    size_t off = (size_t)bc * 512 + e;
    XfRe[off] = re;
    XfIm[off] = im;
  }
}

// ---------------- per-mode complex channel mixing (in-place) ----------------
__global__ __launch_bounds__(256) void mode_mix_kernel(
    float* __restrict__ XfRe, float* __restrict__ XfIm,
    const float* __restrict__ w1r, const float* __restrict__ w1i,
    const float* __restrict__ w2r, const float* __restrict__ w2i) {
  __shared__ float Wr[4096];
  __shared__ float Wi[4096];
  __shared__ float Ar[1024];
  __shared__ float Ai[1024];
  const int tid = threadIdx.x;
  // XCD-chunked bijective swizzle (512 blocks % 8 XCDs == 0): each XCD gets
  // 64 consecutive modes -> kx-sibling blocks sharing W cache lines co-locate.
  const int bid = blockIdx.x;
  const int mode = ((bid & 7) << 6) | (bid >> 3);
  const int m = mode >> 4, kx = mode & 15;
  const float* wr = (m < 16) ? w1r : w2r;
  const float* wi = (m < 16) ? w1i : w2i;
  const int woff = (m & 15) * 16 + kx;
  for (int e = tid; e < 4096; e += 256) {
    Wr[e] = wr[(size_t)e * 256 + woff];
    Wi[e] = wi[(size_t)e * 256 + woff];
  }
  for (int e = tid; e < 1024; e += 256) {
    Ar[e] = XfRe[(size_t)e * 512 + mode];
    Ai[e] = XfIm[(size_t)e * 512 + mode];
  }
  __syncthreads();
  const int o = tid & 63;
  const int b0 = tid >> 6;
  float outR[4], outI[4];
#pragma unroll
  for (int bb = 0; bb < 4; ++bb) {
    const int b = b0 * 4 + bb;
    float re = 0.f, im = 0.f;
    for (int i = 0; i < 64; ++i) {
      float ar = Ar[b * 64 + i], ai = Ai[b * 64 + i];
      float br = Wr[i * 64 + o], bi = Wi[i * 64 + o];
      re += ar * br - ai * bi;
      im += ar * bi + ai * br;
    }
    outR[bb] = re;
    outI[bb] = im;
  }
#pragma unroll
  for (int bb = 0; bb < 4; ++bb) {
    const int b = b0 * 4 + bb;
    size_t off = (size_t)(b * 64 + o) * 512 + mode;
    XfRe[off] = outR[bb];
    XfIm[off] = outI[bb];
  }
}

// ---------------- inverse DFT along h ----------------
__global__ __launch_bounds__(256) void inv_h_kernel(
    const float* __restrict__ GfRe, const float* __restrict__ GfIm,
    float* __restrict__ Y1Re, float* __restrict__ Y1Im) {
  __shared__ float Gr[512];
  __shared__ float Gi[512];
  __shared__ float ctab[128];
  __shared__ float stab[128];
  const int tid = threadIdx.x;
  const int bo = blockIdx.x;
  if (tid < 128) {
    float s, c;
    sincosf((float)((double)tid * (6.283185307179586476925287 / 128.0)), &s, &c);
    ctab[tid] = c;
    stab[tid] = s;
  }
  for (int e = tid; e < 512; e += 256) {
    Gr[e] = GfRe[(size_t)bo * 512 + e];
    Gi[e] = GfIm[(size_t)bo * 512 + e];
  }
  __syncthreads();
  for (int e = tid; e < 2048; e += 256) {
    int h = e >> 4, kx = e & 15;
    float re = 0.f, im = 0.f;
#pragma unroll
    for (int m = 0; m < 32; ++m) {
      int ky = (m < 16) ? m : (m + 96);
      int t = (ky * h) & 127;
      float c = ctab[t], s = stab[t];
      float gr = Gr[m * 16 + kx], gi = Gi[m * 16 + kx];
      re += gr * c - gi * s;
      im += gr * s + gi * c;
    }
    size_t off = (size_t)bo * 2048 + e;
    Y1Re[off] = re;
    Y1Im[off] = im;
  }
}

// ---------------- inverse c2r along w + 1x1 conv + bias ----------------
__global__ __launch_bounds__(256) void invw_conv_kernel(
    const float* __restrict__ x,
    const float* __restrict__ Y1Re, const float* __restrict__ Y1Im,
    const float* __restrict__ convw, const float* __restrict__ convb,
    float* __restrict__ y) {
  __shared__ __align__(16) float xrow[64 * 128];
  __shared__ float cw[4096];
  __shared__ float yr[1024];
  __shared__ float yi[1024];
  __shared__ float cb[64];
  __shared__ float ctab[128];
  __shared__ float stab[128];
  const int tid = threadIdx.x;
  const int b = blockIdx.x >> 7, h = blockIdx.x & 127;
  if (tid < 128) {
    float s, c;
    sincosf((float)((double)tid * (6.283185307179586476925287 / 128.0)), &s, &c);
    ctab[tid] = c;
    stab[tid] = s;
  }
  const float4* x4 = (const float4*)x;
  for (int e = tid; e < 2048; e += 256) {
    int c = e >> 5, w4 = e & 31;
    ((float4*)xrow)[c * 32 + w4] = x4[((size_t)(b * 64 + c) * 128 + h) * 32 + w4];
  }
  for (int e = tid; e < 4096; e += 256) cw[e] = convw[e];
  if (tid < 64) cb[tid] = convb[tid];
  for (int e = tid; e < 1024; e += 256) {
    int o = e >> 4, kx = e & 15;
    size_t off = ((size_t)(b * 64 + o) * 128 + h) * 16 + kx;
    yr[e] = Y1Re[off];
    yi[e] = Y1Im[off];
  }
  __syncthreads();
  for (int e = tid; e < 8192; e += 256) {
    int o = e >> 7, w = e & 127;
    const float* yro = yr + o * 16;
    const float* yio = yi + o * 16;
    float acc = yro[0];  // imag of kx=0 bin ignored (pocketfft c2r convention)
#pragma unroll
    for (int kx = 1; kx < 16; ++kx) {
      int t = (kx * w) & 127;
      acc += 2.f * (yro[kx] * ctab[t] - yio[kx] * stab[t]);
    }
    acc *= (1.f / 16384.f);
    float a2 = cb[o];
#pragma unroll 8
    for (int c = 0; c < 64; ++c) a2 = fmaf(xrow[c * 128 + w], cw[o * 64 + c], a2);
    y[((size_t)(b * 64 + o) * 128 + h) * 128 + w] = acc + a2;
  }
}

// ---------------- KAN weight prep: fp16 fragment-order -----------------
__global__ __launch_bounds__(256) void prep_bfrag_kernel(
    const float* __restrict__ base_w, const float* __restrict__ spline_w,
    const float* __restrict__ scaler, half8* __restrict__ out) {
  int idx = blockIdx.x * 256 + threadIdx.x;
  if (idx >= 4608) return;
  int lane = idx & 63;
  int ks = (idx >> 6) % 18;
  int nt = idx / (64 * 18);
  int n = nt * 16 + (lane & 15);
  int k0 = ks * 32 + (lane >> 4) * 8;
  half8 hv;
#pragma unroll
  for (int j = 0; j < 8; ++j) {
    int k = k0 + j;
    float val;
    if (k < 64) {
      val = base_w[n * 64 + k];
    } else {
      int c = (k - 64) >> 3, jj = (k - 64) & 7;
      val = spline_w[(n * 64 + c) * 8 + jj] * scaler[n * 64 + c];
    }
    hv[j] = (_Float16)val;
  }
  out[idx] = hv;
}

// ---------------- KAN feature math ----------------
__device__ __forceinline__ float fast_silu(float v) {
  return v * (1.f / (1.f + __expf(-v)));
}

__device__ __forceinline__ half8 spline8h(float v) {
  const float Klo = __fsub_rn(__fmul_rn(-3.f, 0.4f), 1.f);
  const float Khi = __fsub_rn(__fmul_rn(8.f, 0.4f), 1.f);
  int i = (int)floorf((v - Klo) * 2.5f);
  i = min(max(i, 0), 10);
  bool inr = (v >= Klo && v < Khi);
  float Ki = __fsub_rn(__fmul_rn((float)(i - 3), 0.4f), 1.f);
  float t = (v - Ki) * 2.5f;
  float t2 = t * t, t3 = t2 * t;
  float p0 = t3 * (1.f / 6.f);
  float omt = 1.f - t;
  float p3 = omt * omt * omt * (1.f / 6.f);
  float p1 = (1.f + 3.f * t + 3.f * t2 - 3.f * t3) * (1.f / 6.f);
  float p2 = (3.f * t3 - 6.f * t2 + 4.f) * (1.f / 6.f);
  if (!inr) { p0 = 0.f; p1 = 0.f; p2 = 0.f; p3 = 0.f; }
  half8 h;
#pragma unroll
  for (int j = 0; j < 8; ++j) {
    int d = i - j;
    float f = (d == 0) ? p0 : (d == 1) ? p1 : (d == 2) ? p2 : (d == 3) ? p3 : 0.f;
    h[j] = (_Float16)f;
  }
  return h;
}

__device__ __forceinline__ float gelu_exact(float v) {
  return 0.5f * v * (1.f + erff(v * 0.70710678118654752f));
}

// Layer-1 features from register-cached inputs (no global access).
__device__ __forceinline__ void feat_quad_v(char* S, const float* v4, int pxl,
                                            int cg) {
  char* row = S + pxl * ROWB;
  half4 s4;
#pragma unroll
  for (int ci = 0; ci < 4; ++ci) s4[ci] = (_Float16)fast_silu(v4[ci]);
  *(half4*)(row + cg * 8) = s4;
#pragma unroll
  for (int ci = 0; ci < 4; ++ci)
    *(half8*)(row + 128 + (cg * 4 + ci) * 16) = spline8h(v4[ci]);
}

// Layer-2 features from layer-1 accumulator (C/D map: col=lane&15 -> channel,
// row=(lane>>4)*4+reg -> pixel within group).
__device__ __forceinline__ void w2feat(char* S, int g, int nt, int rit, f32x4 a) {
  const int c = nt * 16 + rit;
#pragma unroll
  for (int r = 0; r < 4; ++r) {
    char* row = S + (g * 4 + r) * ROWB;
    float v = a[r];
    *(_Float16*)(row + c * 2) = (_Float16)fast_silu(v);
    *(half8*)(row + 128 + c * 16) = spline8h(v);
  }
}

// One 16x16x576 GEMM slice: 18 MFMAs on a 16-px LDS slot.
__device__ __forceinline__ void gemm_slot(const char* S, const half8* Bf,
                                          int rit, int g, f32x4& acc) {
  const char* pa = S + rit * ROWB + g * 16;
#pragma unroll
  for (int ks = 0; ks < 18; ++ks) {
    half8 a = *(const half8*)(pa + ks * 64);
    acc = __builtin_amdgcn_mfma_f32_16x16x32_f16(a, Bf[ks], acc, 0, 0, 0);
  }
}

// GELU + write one acc group into the f32 [64][65] LDS bounce.
__device__ __forceinline__ void bounce_acc(float* bnc, int c, int px0, f32x4 a) {
  float* row = bnc + c * 65 + px0;
#pragma unroll
  for (int r = 0; r < 4; ++r) row[r] = gelu_exact(a[r]);
}

// ---------------- fused 2x KAN layer + GELU (in-place on y) -----------------
// Block: 64 pixels, 256 threads = 4 waves. 9-phase pipeline over two 16-px
// LDS slots. I/O fully coalesced via an LDS bounce in the A0 region (free
// before P0 and after P7).
__global__ __launch_bounds__(256, 4) void kan_fused_kernel(
    float* __restrict__ y, const half8* __restrict__ Bq1,
    const half8* __restrict__ Bq2) {
  __shared__ __align__(16) char Abuf[2 * 16 * ROWB];  // 37,376 B -> 4 blocks/CU
  char* A0 = Abuf;
  char* A1 = Abuf + 16 * ROWB;
  float* ybounce = (float*)Abuf;  // [64][65] f32 = 16,640 B (inside A0)
  const int tid = threadIdx.x;
  const int l = tid & 63;
  const int nt = tid >> 6;
  const int rit = l & 15, g = l >> 4;
  const int pxl = tid & 15, cg = tid >> 4;
  const int n0 = blockIdx.x * 64;
  const int b = n0 >> 14;
  float* base = y + (size_t)b * 1048576 + (n0 & 16383);

  // ---- fully-coalesced y-tile load: 256 B contiguous per channel/wave ----
  float4 ld[4];
#pragma unroll
  for (int i = 0; i < 4; ++i) {
    int idx = i * 256 + tid;
    int c = idx >> 4, q = idx & 15;
    ld[i] = *(const float4*)(base + (size_t)c * 16384 + q * 4);
  }
#pragma unroll
  for (int i = 0; i < 4; ++i) {
    int idx = i * 256 + tid;
    int c = idx >> 4, q = idx & 15;
    float* r = ybounce + c * 65 + q * 4;
    r[0] = ld[i].x; r[1] = ld[i].y; r[2] = ld[i].z; r[3] = ld[i].w;
  }
  __syncthreads();
  // ---- redistribute: register-cache this thread's 16 feature inputs ----
  float yv[16];
#pragma unroll
  for (int p = 0; p < 4; ++p)
#pragma unroll
    for (int ci = 0; ci < 4; ++ci)
      yv[p * 4 + ci] = ybounce[(cg * 4 + ci) * 65 + p * 16 + pxl];
  __syncthreads();

  half8 B1[18], B2[18];
#pragma unroll
  for (int ks = 0; ks < 18; ++ks) B1[ks] = Bq1[(nt * 18 + ks) * 64 + l];
#pragma unroll
  for (int ks = 0; ks < 18; ++ks) B2[ks] = Bq2[(nt * 18 + ks) * 64 + l];

  const f32x4 z = {0.f, 0.f, 0.f, 0.f};
  f32x4 a10 = z, a11 = z, a12 = z, a13 = z;
  f32x4 a20 = z, a21 = z, a22 = z, a23 = z;

  // P0
  feat_quad_v(A0, yv + 0, pxl, cg);
  __syncthreads();
  // P1..P3: layer-1 GEMM(p) || features(p+1)
  gemm_slot(A0, B1, rit, g, a10); feat_quad_v(A1, yv + 4, pxl, cg);
  __syncthreads();
  gemm_slot(A1, B1, rit, g, a11); feat_quad_v(A0, yv + 8, pxl, cg);
  __syncthreads();
  gemm_slot(A0, B1, rit, g, a12); feat_quad_v(A1, yv + 12, pxl, cg);
  __syncthreads();
  // P4: last layer-1 GEMM || first layer-2 feature build
  gemm_slot(A1, B1, rit, g, a13); w2feat(A0, g, nt, rit, a10);
  __syncthreads();
  // P5..P7: layer-2 GEMM(p) || layer-2 features(p+1)
  gemm_slot(A0, B2, rit, g, a20); w2feat(A1, g, nt, rit, a11);
  __syncthreads();
  gemm_slot(A1, B2, rit, g, a21); w2feat(A0, g, nt, rit, a12);
  __syncthreads();
  gemm_slot(A0, B2, rit, g, a22); w2feat(A1, g, nt, rit, a13);
  __syncthreads();
  // P8: last GEMM (reads A1) || GELU-bounce a20..a22 into A0 region
  const int cch = nt * 16 + rit;
  gemm_slot(A1, B2, rit, g, a23);
  bounce_acc(ybounce, cch, 0 + g * 4, a20);
  bounce_acc(ybounce, cch, 16 + g * 4, a21);
  bounce_acc(ybounce, cch, 32 + g * 4, a22);
  __syncthreads();
  bounce_acc(ybounce, cch, 48 + g * 4, a23);
  __syncthreads();
  // ---- cooperative fully-coalesced store ----
#pragma unroll
  for (int i = 0; i < 4; ++i) {
    int idx = i * 256 + tid;
    int c = idx >> 4, q = idx & 15;
    const float* r = ybounce + c * 65 + q * 4;
    float4 v;
    v.x = r[0]; v.y = r[1]; v.z = r[2]; v.w = r[3];
    *(float4*)(base + (size_t)c * 16384 + q * 4) = v;
  }
}

// ---------------------------------------------------------------------------
extern "C" void kernel_launch(void* const* d_in, const int* in_sizes, int n_in,
                              void* d_out, int out_size, void* d_ws, size_t ws_size,
                              hipStream_t stream) {
  const float* x    = (const float*)d_in[0];
  const float* w1r  = (const float*)d_in[1];
  const float* w1i  = (const float*)d_in[2];
  const float* w2r  = (const float*)d_in[3];
  const float* w2i  = (const float*)d_in[4];
  const float* cw   = (const float*)d_in[5];
  const float* cb   = (const float*)d_in[6];
  const float* k1b  = (const float*)d_in[7];
  const float* k1s  = (const float*)d_in[8];
  const float* k1sc = (const float*)d_in[9];
  const float* k2b  = (const float*)d_in[10];
  const float* k2s  = (const float*)d_in[11];
  const float* k2sc = (const float*)d_in[12];

  char* ws = (char*)d_ws;
  float* XfRe = (float*)(ws + 0);          // 2 MB
  float* XfIm = (float*)(ws + 2097152);    // 2 MB
  float* Y1Re = (float*)(ws + 4194304);    // 8 MB
  float* Y1Im = (float*)(ws + 12582912);   // 8 MB
  half8* Bf1  = (half8*)(ws + 20971520);   // 73728 B
  half8* Bf2  = (half8*)(ws + 21045248);   // 73728 B
  float* y = (float*)d_out;                // d_out doubles as the intermediate

  prep_bfrag_kernel<<<18, 256, 0, stream>>>(k1b, k1s, k1sc, Bf1);
  prep_bfrag_kernel<<<18, 256, 0, stream>>>(k2b, k2s, k2sc, Bf2);
  fwd_dft_kernel<<<1024, 256, 0, stream>>>(x, XfRe, XfIm);
  mode_mix_kernel<<<512, 256, 0, stream>>>(XfRe, XfIm, w1r, w1i, w2r, w2i);
  inv_h_kernel<<<1024, 256, 0, stream>>>(XfRe, XfIm, Y1Re, Y1Im);
  invw_conv_kernel<<<2048, 256, 0, stream>>>(x, Y1Re, Y1Im, cw, cb, y);
  kan_fused_kernel<<<4096, 256, 0, stream>>>(y, Bf1, Bf2);
}

// Round 7
// 425.849 us; speedup vs baseline: 2.7822x; 1.2653x over previous
//
#include <hip/hip_runtime.h>

// ---------------------------------------------------------------------------
// KAN-FNO block, MI355X.
//   1. fwd_dft:   truncated separable rfft2 -> Xf[b,c,32,16]
//   2. mode_mix:  per-mode 16x64x64 complex GEMM (in-place on Xf), XCD-swizzled
//   3. inv_h:     inverse DFT along h -> Y1[b,o,128,16]
//   4. invw_conv: inverse c2r along w + 1x1 conv + bias -> y (d_out scratch)
//   5. kan_fused: BOTH KAN layers via MFMA f16 + exact GELU, in-place.
// R7: kan_fused is VALU-instruction bound (49% VALUBusy, 6.5% Mfma, 42% Occ).
//     (a) spline basis scatter rewritten: pack 4 nonzero bases into a 64-bit
//         payload (2x cvt_pkrtz) and position it with branchless 128-bit
//         variable shifts -> one b128 LDS write; kills the 8x cmp/select/cvt
//         chain (~35% fewer VALU ops per eval).
//     (b) K-split B fragments: 9 half8 (36 VGPR) loaded per K-half inside the
//         GEMM phase instead of 72+72 resident -> peak live regs ~110, so
//         occupancy reaches the 4-block LDS cap (50%).
// ---------------------------------------------------------------------------

typedef _Float16 half8 __attribute__((ext_vector_type(8)));
typedef float f32x4 __attribute__((ext_vector_type(4)));
typedef unsigned u32x2 __attribute__((ext_vector_type(2)));
typedef unsigned u32x4 __attribute__((ext_vector_type(4)));
typedef unsigned long long u64;

#define ROWB 1168  // LDS bytes per pixel row: 576 fp16 = 1152 + 16 pad

// ---------------- forward truncated rfft2 ----------------
__global__ __launch_bounds__(256) void fwd_dft_kernel(
    const float* __restrict__ x, float* __restrict__ XfRe, float* __restrict__ XfIm) {
  __shared__ __align__(16) float img[64 * 132];
  __shared__ float XwRe[128 * 16];
  __shared__ float XwIm[128 * 16];
  __shared__ float ctab[128];
  __shared__ float stab[128];
  const int tid = threadIdx.x;
  const int bc = blockIdx.x;
  const float4* src4 = (const float4*)(x + (size_t)bc * 16384);
  if (tid < 128) {
    float s, c;
    sincosf((float)((double)tid * (6.283185307179586476925287 / 128.0)), &s, &c);
    ctab[tid] = c;
    stab[tid] = s;
  }
  for (int h0 = 0; h0 < 128; h0 += 64) {
    __syncthreads();
    for (int e = tid; e < 2048; e += 256) {
      int r = e >> 5, w4 = e & 31;
      float4 v = src4[(h0 + r) * 32 + w4];
      *((float4*)&img[r * 132 + w4 * 4]) = v;
    }
    __syncthreads();
    for (int e = tid; e < 1024; e += 256) {
      int hr = e >> 4, kx = e & 15;
      const float* row = img + hr * 132;
      float re = 0.f, im = 0.f;
      int t = 0;
#pragma unroll 8
      for (int w = 0; w < 128; ++w) {
        float v = row[w];
        re = fmaf(v, ctab[t], re);
        im = fmaf(v, stab[t], im);
        t = (t + kx) & 127;
      }
      int idx = (h0 + hr) * 16 + kx;
      XwRe[idx] = re;
      XwIm[idx] = -im;
    }
  }
  __syncthreads();
  for (int e = tid; e < 512; e += 256) {
    int m = e >> 4, kx = e & 15;
    int ky = (m < 16) ? m : (m + 96);
    float re = 0.f, im = 0.f;
    for (int h = 0; h < 128; ++h) {
      int t = (ky * h) & 127;
      float c = ctab[t], s = stab[t];
      float ar = XwRe[h * 16 + kx], ai = XwIm[h * 16 + kx];
      re += ar * c + ai * s;
      im += ai * c - ar * s;
    }
    size_t off = (size_t)bc * 512 + e;
    XfRe[off] = re;
    XfIm[off] = im;
  }
}

// ---------------- per-mode complex channel mixing (in-place) ----------------
__global__ __launch_bounds__(256) void mode_mix_kernel(
    float* __restrict__ XfRe, float* __restrict__ XfIm,
    const float* __restrict__ w1r, const float* __restrict__ w1i,
    const float* __restrict__ w2r, const float* __restrict__ w2i) {
  __shared__ float Wr[4096];
  __shared__ float Wi[4096];
  __shared__ float Ar[1024];
  __shared__ float Ai[1024];
  const int tid = threadIdx.x;
  const int bid = blockIdx.x;
  const int mode = ((bid & 7) << 6) | (bid >> 3);  // XCD-chunked bijective
  const int m = mode >> 4, kx = mode & 15;
  const float* wr = (m < 16) ? w1r : w2r;
  const float* wi = (m < 16) ? w1i : w2i;
  const int woff = (m & 15) * 16 + kx;
  for (int e = tid; e < 4096; e += 256) {
    Wr[e] = wr[(size_t)e * 256 + woff];
    Wi[e] = wi[(size_t)e * 256 + woff];
  }
  for (int e = tid; e < 1024; e += 256) {
    Ar[e] = XfRe[(size_t)e * 512 + mode];
    Ai[e] = XfIm[(size_t)e * 512 + mode];
  }
  __syncthreads();
  const int o = tid & 63;
  const int b0 = tid >> 6;
  float outR[4], outI[4];
#pragma unroll
  for (int bb = 0; bb < 4; ++bb) {
    const int b = b0 * 4 + bb;
    float re = 0.f, im = 0.f;
    for (int i = 0; i < 64; ++i) {
      float ar = Ar[b * 64 + i], ai = Ai[b * 64 + i];
      float br = Wr[i * 64 + o], bi = Wi[i * 64 + o];
      re += ar * br - ai * bi;
      im += ar * bi + ai * br;
    }
    outR[bb] = re;
    outI[bb] = im;
  }
#pragma unroll
  for (int bb = 0; bb < 4; ++bb) {
    const int b = b0 * 4 + bb;
    size_t off = (size_t)(b * 64 + o) * 512 + mode;
    XfRe[off] = outR[bb];
    XfIm[off] = outI[bb];
  }
}

// ---------------- inverse DFT along h ----------------
__global__ __launch_bounds__(256) void inv_h_kernel(
    const float* __restrict__ GfRe, const float* __restrict__ GfIm,
    float* __restrict__ Y1Re, float* __restrict__ Y1Im) {
  __shared__ float Gr[512];
  __shared__ float Gi[512];
  __shared__ float ctab[128];
  __shared__ float stab[128];
  const int tid = threadIdx.x;
  const int bo = blockIdx.x;
  if (tid < 128) {
    float s, c;
    sincosf((float)((double)tid * (6.283185307179586476925287 / 128.0)), &s, &c);
    ctab[tid] = c;
    stab[tid] = s;
  }
  for (int e = tid; e < 512; e += 256) {
    Gr[e] = GfRe[(size_t)bo * 512 + e];
    Gi[e] = GfIm[(size_t)bo * 512 + e];
  }
  __syncthreads();
  for (int e = tid; e < 2048; e += 256) {
    int h = e >> 4, kx = e & 15;
    float re = 0.f, im = 0.f;
#pragma unroll
    for (int m = 0; m < 32; ++m) {
      int ky = (m < 16) ? m : (m + 96);
      int t = (ky * h) & 127;
      float c = ctab[t], s = stab[t];
      float gr = Gr[m * 16 + kx], gi = Gi[m * 16 + kx];
      re += gr * c - gi * s;
      im += gr * s + gi * c;
    }
    size_t off = (size_t)bo * 2048 + e;
    Y1Re[off] = re;
    Y1Im[off] = im;
  }
}

// ---------------- inverse c2r along w + 1x1 conv + bias ----------------
__global__ __launch_bounds__(256) void invw_conv_kernel(
    const float* __restrict__ x,
    const float* __restrict__ Y1Re, const float* __restrict__ Y1Im,
    const float* __restrict__ convw, const float* __restrict__ convb,
    float* __restrict__ y) {
  __shared__ __align__(16) float xrow[64 * 128];
  __shared__ float cw[4096];
  __shared__ float yr[1024];
  __shared__ float yi[1024];
  __shared__ float cb[64];
  __shared__ float ctab[128];
  __shared__ float stab[128];
  const int tid = threadIdx.x;
  const int b = blockIdx.x >> 7, h = blockIdx.x & 127;
  if (tid < 128) {
    float s, c;
    sincosf((float)((double)tid * (6.283185307179586476925287 / 128.0)), &s, &c);
    ctab[tid] = c;
    stab[tid] = s;
  }
  const float4* x4 = (const float4*)x;
  for (int e = tid; e < 2048; e += 256) {
    int c = e >> 5, w4 = e & 31;
    ((float4*)xrow)[c * 32 + w4] = x4[((size_t)(b * 64 + c) * 128 + h) * 32 + w4];
  }
  for (int e = tid; e < 4096; e += 256) cw[e] = convw[e];
  if (tid < 64) cb[tid] = convb[tid];
  for (int e = tid; e < 1024; e += 256) {
    int o = e >> 4, kx = e & 15;
    size_t off = ((size_t)(b * 64 + o) * 128 + h) * 16 + kx;
    yr[e] = Y1Re[off];
    yi[e] = Y1Im[off];
  }
  __syncthreads();
  for (int e = tid; e < 8192; e += 256) {
    int o = e >> 7, w = e & 127;
    const float* yro = yr + o * 16;
    const float* yio = yi + o * 16;
    float acc = yro[0];  // imag of kx=0 bin ignored (pocketfft c2r convention)
#pragma unroll
    for (int kx = 1; kx < 16; ++kx) {
      int t = (kx * w) & 127;
      acc += 2.f * (yro[kx] * ctab[t] - yio[kx] * stab[t]);
    }
    acc *= (1.f / 16384.f);
    float a2 = cb[o];
#pragma unroll 8
    for (int c = 0; c < 64; ++c) a2 = fmaf(xrow[c * 128 + w], cw[o * 64 + c], a2);
    y[((size_t)(b * 64 + o) * 128 + h) * 128 + w] = acc + a2;
  }
}

// ---------------- KAN weight prep: fp16 fragment-order -----------------
__global__ __launch_bounds__(256) void prep_bfrag_kernel(
    const float* __restrict__ base_w, const float* __restrict__ spline_w,
    const float* __restrict__ scaler, half8* __restrict__ out) {
  int idx = blockIdx.x * 256 + threadIdx.x;
  if (idx >= 4608) return;
  int lane = idx & 63;
  int ks = (idx >> 6) % 18;
  int nt = idx / (64 * 18);
  int n = nt * 16 + (lane & 15);
  int k0 = ks * 32 + (lane >> 4) * 8;
  half8 hv;
#pragma unroll
  for (int j = 0; j < 8; ++j) {
    int k = k0 + j;
    float val;
    if (k < 64) {
      val = base_w[n * 64 + k];
    } else {
      int c = (k - 64) >> 3, jj = (k - 64) & 7;
      val = spline_w[(n * 64 + c) * 8 + jj] * scaler[n * 64 + c];
    }
    hv[j] = (_Float16)val;
  }
  out[idx] = hv;
}

// ---------------- KAN feature math ----------------
__device__ __forceinline__ float fast_silu(float v) {
  return v * (1.f / (1.f + __expf(-v)));
}

// Cubic B-spline: compute the 4 nonzero bases [p3,p2,p1,p0], pack into a
// 64-bit fp16 payload, position at basis index (i-3) via branchless 128-bit
// shift, single b128 LDS write (16 bytes = 8 basis slots). Knot arithmetic
// matches reference fp32 arange*0.4f-1.0f; C2 continuity makes ulp-level
// interval choice harmless (validated R4-R6).
__device__ __forceinline__ void spline_scatter(char* p16, float v) {
  const float Klo = __fsub_rn(__fmul_rn(-3.f, 0.4f), 1.0f);
  float u = (v - Klo) * 2.5f;
  float uc = fminf(fmaxf(u, 0.f), 10.5f);
  int i = (int)uc;
  float t = u - (float)i;
  float t2 = t * t, t3 = t2 * t;
  float omt = 1.f - t;
  float p0 = t3 * (1.f / 6.f);
  float p3 = omt * omt * (omt * (1.f / 6.f));
  float p1 = fmaf(t3, -0.5f, fmaf(t2, 0.5f, fmaf(t, 0.5f, 1.f / 6.f)));
  float p2 = fmaf(t3, 0.5f, fmaf(t2, -1.f, 2.f / 3.f));
  bool ok = (u >= 0.f) && (u < 11.f);
  auto hA = __builtin_amdgcn_cvt_pkrtz(p3, p2);  // [p3,p2] fp16
  auto hB = __builtin_amdgcn_cvt_pkrtz(p1, p0);  // [p1,p0] fp16
  unsigned a32 = ok ? __builtin_bit_cast(unsigned, hA) : 0u;
  unsigned b32 = ok ? __builtin_bit_cast(unsigned, hB) : 0u;
  u64 P = ((u64)b32 << 32) | a32;  // bytes: p3,p2,p1,p0 (low->high)
  int sh = i << 4;                 // bit position of j=i-3 start + 48
  u64 tA = P >> ((48 - sh) & 63);
  u64 tB = P << ((sh - 48) & 63);
  u64 tC = P >> ((112 - sh) & 63);
  u64 tD = P << ((sh - 112) & 63);
  u64 lo = (sh < 64) ? tA : ((sh < 112) ? tB : 0ull);
  u64 hi = (sh < 64) ? 0ull : ((sh < 128) ? tC : tD);
  u32x4 st = {(unsigned)lo, (unsigned)(lo >> 32), (unsigned)hi, (unsigned)(hi >> 32)};
  *(u32x4*)p16 = st;
}

__device__ __forceinline__ float gelu_exact(float v) {
  return 0.5f * v * (1.f + erff(v * 0.70710678118654752f));
}

// Layer-1 features from register-cached inputs (no global access).
__device__ __forceinline__ void feat_quad_v(char* S, const float* v4, int pxl,
                                            int cg) {
  char* row = S + pxl * ROWB;
  auto sA = __builtin_amdgcn_cvt_pkrtz(fast_silu(v4[0]), fast_silu(v4[1]));
  auto sB = __builtin_amdgcn_cvt_pkrtz(fast_silu(v4[2]), fast_silu(v4[3]));
  u32x2 sil = {__builtin_bit_cast(unsigned, sA), __builtin_bit_cast(unsigned, sB)};
  *(u32x2*)(row + cg * 8) = sil;
#pragma unroll
  for (int ci = 0; ci < 4; ++ci)
    spline_scatter(row + 128 + (cg * 4 + ci) * 16, v4[ci]);
}

// Layer-2 features from layer-1 accumulator (C/D map: col=lane&15 -> channel,
// row=(lane>>4)*4+reg -> pixel within group).
__device__ __forceinline__ void w2feat(char* S, int g, int nt, int rit, f32x4 a) {
  const int c = nt * 16 + rit;
#pragma unroll
  for (int r = 0; r < 4; ++r) {
    char* row = S + (g * 4 + r) * ROWB;
    float v = a[r];
    *(_Float16*)(row + c * 2) = (_Float16)fast_silu(v);
    spline_scatter(row + 128 + c * 16, v);
  }
}

// One 16x16x576 GEMM slice, K-split: load 9 B-frags (36 VGPR), 9 MFMA, reload.
__device__ __forceinline__ void gemm_slot_ks(const char* S, const half8* Bq,
                                             int nt, int l, int rit, int g,
                                             f32x4& acc) {
  const half8* bq = Bq + (size_t)nt * 18 * 64 + l;
  const char* pa = S + rit * ROWB + g * 16;
#pragma unroll
  for (int kh = 0; kh < 2; ++kh) {
    half8 bfr[9];
#pragma unroll
    for (int ks = 0; ks < 9; ++ks) bfr[ks] = bq[(kh * 9 + ks) * 64];
#pragma unroll
    for (int ks = 0; ks < 9; ++ks) {
      half8 a = *(const half8*)(pa + (kh * 9 + ks) * 64);
      acc = __builtin_amdgcn_mfma_f32_16x16x32_f16(a, bfr[ks], acc, 0, 0, 0);
    }
  }
}

// GELU + write one acc group into the f32 [64][65] LDS bounce.
__device__ __forceinline__ void bounce_acc(float* bnc, int c, int px0, f32x4 a) {
  float* row = bnc + c * 65 + px0;
#pragma unroll
  for (int r = 0; r < 4; ++r) row[r] = gelu_exact(a[r]);
}

// ---------------- fused 2x KAN layer + GELU (in-place on y) -----------------
// Block: 64 pixels, 256 threads = 4 waves. 9-phase pipeline over two 16-px
// LDS slots. I/O fully coalesced via an LDS bounce in the A0 region.
__global__ __launch_bounds__(256, 4) void kan_fused_kernel(
    float* __restrict__ y, const half8* __restrict__ Bq1,
    const half8* __restrict__ Bq2) {
  __shared__ __align__(16) char Abuf[2 * 16 * ROWB];  // 37,376 B -> 4 blocks/CU
  char* A0 = Abuf;
  char* A1 = Abuf + 16 * ROWB;
  float* ybounce = (float*)Abuf;  // [64][65] f32 = 16,640 B (inside A0)
  const int tid = threadIdx.x;
  const int l = tid & 63;
  const int nt = tid >> 6;
  const int rit = l & 15, g = l >> 4;
  const int pxl = tid & 15, cg = tid >> 4;
  const int n0 = blockIdx.x * 64;
  const int b = n0 >> 14;
  float* base = y + (size_t)b * 1048576 + (n0 & 16383);

  // ---- fully-coalesced y-tile load: 256 B contiguous per channel/wave ----
  float4 ld[4];
#pragma unroll
  for (int i = 0; i < 4; ++i) {
    int idx = i * 256 + tid;
    int c = idx >> 4, q = idx & 15;
    ld[i] = *(const float4*)(base + (size_t)c * 16384 + q * 4);
  }
#pragma unroll
  for (int i = 0; i < 4; ++i) {
    int idx = i * 256 + tid;
    int c = idx >> 4, q = idx & 15;
    float* r = ybounce + c * 65 + q * 4;
    r[0] = ld[i].x; r[1] = ld[i].y; r[2] = ld[i].z; r[3] = ld[i].w;
  }
  __syncthreads();
  // ---- redistribute: register-cache this thread's 16 feature inputs ----
  float yv[16];
#pragma unroll
  for (int p = 0; p < 4; ++p)
#pragma unroll
    for (int ci = 0; ci < 4; ++ci)
      yv[p * 4 + ci] = ybounce[(cg * 4 + ci) * 65 + p * 16 + pxl];
  __syncthreads();

  const f32x4 z = {0.f, 0.f, 0.f, 0.f};
  f32x4 a10 = z, a11 = z, a12 = z, a13 = z;
  f32x4 a20 = z, a21 = z, a22 = z, a23 = z;

  // P0
  feat_quad_v(A0, yv + 0, pxl, cg);
  __syncthreads();
  // P1..P3: layer-1 GEMM(p) || features(p+1)
  gemm_slot_ks(A0, Bq1, nt, l, rit, g, a10); feat_quad_v(A1, yv + 4, pxl, cg);
  __syncthreads();
  gemm_slot_ks(A1, Bq1, nt, l, rit, g, a11); feat_quad_v(A0, yv + 8, pxl, cg);
  __syncthreads();
  gemm_slot_ks(A0, Bq1, nt, l, rit, g, a12); feat_quad_v(A1, yv + 12, pxl, cg);
  __syncthreads();
  // P4: last layer-1 GEMM || first layer-2 feature build
  gemm_slot_ks(A1, Bq1, nt, l, rit, g, a13); w2feat(A0, g, nt, rit, a10);
  __syncthreads();
  // P5..P7: layer-2 GEMM(p) || layer-2 features(p+1)
  gemm_slot_ks(A0, Bq2, nt, l, rit, g, a20); w2feat(A1, g, nt, rit, a11);
  __syncthreads();
  gemm_slot_ks(A1, Bq2, nt, l, rit, g, a21); w2feat(A0, g, nt, rit, a12);
  __syncthreads();
  gemm_slot_ks(A0, Bq2, nt, l, rit, g, a22); w2feat(A1, g, nt, rit, a13);
  __syncthreads();
  // P8: last GEMM (reads A1) || GELU-bounce a20..a22 into A0 region
  const int cch = nt * 16 + rit;
  gemm_slot_ks(A1, Bq2, nt, l, rit, g, a23);
  bounce_acc(ybounce, cch, 0 + g * 4, a20);
  bounce_acc(ybounce, cch, 16 + g * 4, a21);
  bounce_acc(ybounce, cch, 32 + g * 4, a22);
  __syncthreads();
  bounce_acc(ybounce, cch, 48 + g * 4, a23);
  __syncthreads();
  // ---- cooperative fully-coalesced store ----
#pragma unroll
  for (int i = 0; i < 4; ++i) {
    int idx = i * 256 + tid;
    int c = idx >> 4, q = idx & 15;
    const float* r = ybounce + c * 65 + q * 4;
    float4 v;
    v.x = r[0]; v.y = r[1]; v.z = r[2]; v.w = r[3];
    *(float4*)(base + (size_t)c * 16384 + q * 4) = v;
  }
}

// ---------------------------------------------------------------------------
extern "C" void kernel_launch(void* const* d_in, const int* in_sizes, int n_in,
                              void* d_out, int out_size, void* d_ws, size_t ws_size,
                              hipStream_t stream) {
  const float* x    = (const float*)d_in[0];
  const float* w1r  = (const float*)d_in[1];
  const float* w1i  = (const float*)d_in[2];
  const float* w2r  = (const float*)d_in[3];
  const float* w2i  = (const float*)d_in[4];
  const float* cw   = (const float*)d_in[5];
  const float* cb   = (const float*)d_in[6];
  const float* k1b  = (const float*)d_in[7];
  const float* k1s  = (const float*)d_in[8];
  const float* k1sc = (const float*)d_in[9];
  const float* k2b  = (const float*)d_in[10];
  const float* k2s  = (const float*)d_in[11];
  const float* k2sc = (const float*)d_in[12];

  char* ws = (char*)d_ws;
  float* XfRe = (float*)(ws + 0);          // 2 MB
  float* XfIm = (float*)(ws + 2097152);    // 2 MB
  float* Y1Re = (float*)(ws + 4194304);    // 8 MB
  float* Y1Im = (float*)(ws + 12582912);   // 8 MB
  half8* Bf1  = (half8*)(ws + 20971520);   // 73728 B
  half8* Bf2  = (half8*)(ws + 21045248);   // 73728 B
  float* y = (float*)d_out;                // d_out doubles as the intermediate

  prep_bfrag_kernel<<<18, 256, 0, stream>>>(k1b, k1s, k1sc, Bf1);
  prep_bfrag_kernel<<<18, 256, 0, stream>>>(k2b, k2s, k2sc, Bf2);
  fwd_dft_kernel<<<1024, 256, 0, stream>>>(x, XfRe, XfIm);
  mode_mix_kernel<<<512, 256, 0, stream>>>(XfRe, XfIm, w1r, w1i, w2r, w2i);
  inv_h_kernel<<<1024, 256, 0, stream>>>(XfRe, XfIm, Y1Re, Y1Im);
  invw_conv_kernel<<<2048, 256, 0, stream>>>(x, Y1Re, Y1Im, cw, cb, y);
  kan_fused_kernel<<<4096, 256, 0, stream>>>(y, Bf1, Bf2);
}

// Round 8
// 251.425 us; speedup vs baseline: 4.7123x; 1.6937x over previous
//
#include <hip/hip_runtime.h>

// ---------------------------------------------------------------------------
// KAN-FNO block, MI355X.
//   1. fwd_dft:   truncated separable rfft2 -> Xf[b,c,32,16]
//   2. mode_mix:  per-mode 16x64x64 complex GEMM (in-place on Xf), XCD-swizzled
//   3. inv_h:     inverse DFT along h -> Y1h fp16 [b][h][o][re16|im16], x2^-10
//   4. kan_mega:  c2r-along-w GEMM + 1x1-conv GEMM + bias (all MFMA) feeding
//                 BOTH KAN layers (MFMA f16) + exact GELU -> y. One kernel.
// R8: invw_conv (199us, scalar VALU, MfmaUtil 0) eliminated: its two pieces
//     are GEMMs in the same (M=64px, N=64ch) shape as the KAN layers:
//       x1 = T[w][32k] x Yc[k][o]    (fp16 trig table, K=32, 1 MFMA/tile)
//       x2 = Xh[px][cin] x W[cin][o] (K=64, 2 MFMA/tile)
//     accumulated in the KAN C/D layout so conv accs feed w2feat directly.
//     inv_h emits Y1 as fp16 fragments (scaled 2^-10; T carries 1/16).
// ---------------------------------------------------------------------------

typedef _Float16 half8 __attribute__((ext_vector_type(8)));
typedef float f32x4 __attribute__((ext_vector_type(4)));
typedef unsigned u32x4 __attribute__((ext_vector_type(4)));
typedef unsigned long long u64;

#define ROWB 1168  // KAN feature row: 576 fp16 = 1152 + 16 pad
#define ROWX 144   // conv A-tile row: 64 fp16 = 128 + 16 pad (16B aligned)

// ---------------- forward truncated rfft2 ----------------
__global__ __launch_bounds__(256) void fwd_dft_kernel(
    const float* __restrict__ x, float* __restrict__ XfRe, float* __restrict__ XfIm) {
  __shared__ __align__(16) float img[64 * 132];
  __shared__ float XwRe[128 * 16];
  __shared__ float XwIm[128 * 16];
  __shared__ float ctab[128];
  __shared__ float stab[128];
  const int tid = threadIdx.x;
  const int bc = blockIdx.x;
  const float4* src4 = (const float4*)(x + (size_t)bc * 16384);
  if (tid < 128) {
    float s, c;
    sincosf((float)((double)tid * (6.283185307179586476925287 / 128.0)), &s, &c);
    ctab[tid] = c;
    stab[tid] = s;
  }
  for (int h0 = 0; h0 < 128; h0 += 64) {
    __syncthreads();
    for (int e = tid; e < 2048; e += 256) {
      int r = e >> 5, w4 = e & 31;
      float4 v = src4[(h0 + r) * 32 + w4];
      *((float4*)&img[r * 132 + w4 * 4]) = v;
    }
    __syncthreads();
    for (int e = tid; e < 1024; e += 256) {
      int hr = e >> 4, kx = e & 15;
      const float* row = img + hr * 132;
      float re = 0.f, im = 0.f;
      int t = 0;
#pragma unroll 8
      for (int w = 0; w < 128; ++w) {
        float v = row[w];
        re = fmaf(v, ctab[t], re);
        im = fmaf(v, stab[t], im);
        t = (t + kx) & 127;
      }
      int idx = (h0 + hr) * 16 + kx;
      XwRe[idx] = re;
      XwIm[idx] = -im;
    }
  }
  __syncthreads();
  for (int e = tid; e < 512; e += 256) {
    int m = e >> 4, kx = e & 15;
    int ky = (m < 16) ? m : (m + 96);
    float re = 0.f, im = 0.f;
    for (int h = 0; h < 128; ++h) {
      int t = (ky * h) & 127;
      float c = ctab[t], s = stab[t];
      float ar = XwRe[h * 16 + kx], ai = XwIm[h * 16 + kx];
      re += ar * c + ai * s;
      im += ai * c - ar * s;
    }
    size_t off = (size_t)bc * 512 + e;
    XfRe[off] = re;
    XfIm[off] = im;
  }
}

// ---------------- per-mode complex channel mixing (in-place) ----------------
__global__ __launch_bounds__(256) void mode_mix_kernel(
    float* __restrict__ XfRe, float* __restrict__ XfIm,
    const float* __restrict__ w1r, const float* __restrict__ w1i,
    const float* __restrict__ w2r, const float* __restrict__ w2i) {
  __shared__ float Wr[4096];
  __shared__ float Wi[4096];
  __shared__ float Ar[1024];
  __shared__ float Ai[1024];
  const int tid = threadIdx.x;
  const int bid = blockIdx.x;
  const int mode = ((bid & 7) << 6) | (bid >> 3);  // XCD-chunked bijective
  const int m = mode >> 4, kx = mode & 15;
  const float* wr = (m < 16) ? w1r : w2r;
  const float* wi = (m < 16) ? w1i : w2i;
  const int woff = (m & 15) * 16 + kx;
  for (int e = tid; e < 4096; e += 256) {
    Wr[e] = wr[(size_t)e * 256 + woff];
    Wi[e] = wi[(size_t)e * 256 + woff];
  }
  for (int e = tid; e < 1024; e += 256) {
    Ar[e] = XfRe[(size_t)e * 512 + mode];
    Ai[e] = XfIm[(size_t)e * 512 + mode];
  }
  __syncthreads();
  const int o = tid & 63;
  const int b0 = tid >> 6;
  float outR[4], outI[4];
#pragma unroll
  for (int bb = 0; bb < 4; ++bb) {
    const int b = b0 * 4 + bb;
    float re = 0.f, im = 0.f;
    for (int i = 0; i < 64; ++i) {
      float ar = Ar[b * 64 + i], ai = Ai[b * 64 + i];
      float br = Wr[i * 64 + o], bi = Wi[i * 64 + o];
      re += ar * br - ai * bi;
      im += ar * bi + ai * br;
    }
    outR[bb] = re;
    outI[bb] = im;
  }
#pragma unroll
  for (int bb = 0; bb < 4; ++bb) {
    const int b = b0 * 4 + bb;
    size_t off = (size_t)(b * 64 + o) * 512 + mode;
    XfRe[off] = outR[bb];
    XfIm[off] = outI[bb];
  }
}

// ---------------- inverse DFT along h -> fp16 fragment layout ---------------
// Y1h[b][h][o][k], k: 0..15 = Re(kx), 16..31 = Im(kx). Values scaled 2^-10
// (the c2r trig table carries the remaining 1/16 of the irfft2 1/16384).
__global__ __launch_bounds__(256) void inv_h_kernel(
    const float* __restrict__ GfRe, const float* __restrict__ GfIm,
    _Float16* __restrict__ Y1h) {
  __shared__ float Gr[512];
  __shared__ float Gi[512];
  __shared__ float ctab[128];
  __shared__ float stab[128];
  const int tid = threadIdx.x;
  const int bo = blockIdx.x;
  const int bb = bo >> 6, o = bo & 63;
  if (tid < 128) {
    float s, c;
    sincosf((float)((double)tid * (6.283185307179586476925287 / 128.0)), &s, &c);
    ctab[tid] = c;
    stab[tid] = s;
  }
  for (int e = tid; e < 512; e += 256) {
    Gr[e] = GfRe[(size_t)bo * 512 + e];
    Gi[e] = GfIm[(size_t)bo * 512 + e];
  }
  __syncthreads();
  for (int e = tid; e < 2048; e += 256) {
    int h = e >> 4, kx = e & 15;
    float re = 0.f, im = 0.f;
#pragma unroll
    for (int m = 0; m < 32; ++m) {
      int ky = (m < 16) ? m : (m + 96);
      int t = (ky * h) & 127;
      float c = ctab[t], s = stab[t];
      float gr = Gr[m * 16 + kx], gi = Gi[m * 16 + kx];
      re += gr * c - gi * s;
      im += gr * s + gi * c;
    }
    _Float16* dst = Y1h + ((size_t)(bb * 128 + h) * 64 + o) * 32;
    dst[kx] = (_Float16)(re * 9.765625e-4f);       // * 2^-10
    dst[16 + kx] = (_Float16)(im * 9.765625e-4f);
  }
}

// ---------------- KAN weight prep: fp16 fragment-order -----------------
__global__ __launch_bounds__(256) void prep_bfrag_kernel(
    const float* __restrict__ base_w, const float* __restrict__ spline_w,
    const float* __restrict__ scaler, half8* __restrict__ out) {
  int idx = blockIdx.x * 256 + threadIdx.x;
  if (idx >= 4608) return;
  int lane = idx & 63;
  int ks = (idx >> 6) % 18;
  int nt = idx / (64 * 18);
  int n = nt * 16 + (lane & 15);
  int k0 = ks * 32 + (lane >> 4) * 8;
  half8 hv;
#pragma unroll
  for (int j = 0; j < 8; ++j) {
    int k = k0 + j;
    float val;
    if (k < 64) {
      val = base_w[n * 64 + k];
    } else {
      int c = (k - 64) >> 3, jj = (k - 64) & 7;
      val = spline_w[(n * 64 + c) * 8 + jj] * scaler[n * 64 + c];
    }
    hv[j] = (_Float16)val;
  }
  out[idx] = hv;
}

// ---------------- conv-W fragments + c2r trig table -----------------
// Wfrag[(nt*2+ks)*64+l][j] = convw[cout=nt*16+(l&15)][cin=ks*32+(l>>4)*8+j]
// Tfrag[w*4+g][j]: k=g*8+j; k<16: Re coeff (kx=0 -> 1, else 2cos); k>=16:
// Im coeff (kx=0 -> 0 = pocketfft "imag of bin 0 ignored", else -2sin).
// Scaled by 1/16 (Y1h carries 2^-10; product = coeff/16384).
__global__ __launch_bounds__(256) void prep_conv_kernel(
    const float* __restrict__ convw, half8* __restrict__ Wfrag,
    half8* __restrict__ Tfrag) {
  int idx = blockIdx.x * 256 + threadIdx.x;
  if (idx < 512) {
    int l = idx & 63, ks = (idx >> 6) & 1, nt = idx >> 7;
    int cout = nt * 16 + (l & 15);
    int cin0 = ks * 32 + (l >> 4) * 8;
    half8 hv;
#pragma unroll
    for (int j = 0; j < 8; ++j) hv[j] = (_Float16)convw[cout * 64 + cin0 + j];
    Wfrag[idx] = hv;
  } else if (idx < 1024) {
    int e = idx - 512;
    int w = e >> 2, g = e & 3;
    half8 hv;
#pragma unroll
    for (int j = 0; j < 8; ++j) {
      int k = g * 8 + j;
      float coeff;
      if (k < 16) {
        int t = (k * w) & 127;
        coeff = (k == 0) ? 1.f
                         : 2.f * cosf((float)((double)t * (6.283185307179586476925287 / 128.0)));
      } else {
        int kx = k - 16;
        int t = (kx * w) & 127;
        coeff = (kx == 0) ? 0.f
                          : -2.f * sinf((float)((double)t * (6.283185307179586476925287 / 128.0)));
      }
      hv[j] = (_Float16)(coeff * 0.0625f);
    }
    Tfrag[e] = hv;
  }
}

// ---------------- KAN feature math ----------------
__device__ __forceinline__ float fast_silu(float v) {
  return v * (1.f / (1.f + __expf(-v)));
}

// Cubic B-spline: 4 nonzero bases packed into a 64-bit fp16 payload, placed
// at basis offset via branchless 128-bit shift, one b128 LDS write.
__device__ __forceinline__ void spline_scatter(char* p16, float v) {
  const float Klo = __fsub_rn(__fmul_rn(-3.f, 0.4f), 1.0f);
  float u = (v - Klo) * 2.5f;
  float uc = fminf(fmaxf(u, 0.f), 10.5f);
  int i = (int)uc;
  float t = u - (float)i;
  float t2 = t * t, t3 = t2 * t;
  float omt = 1.f - t;
  float p0 = t3 * (1.f / 6.f);
  float p3 = omt * omt * (omt * (1.f / 6.f));
  float p1 = fmaf(t3, -0.5f, fmaf(t2, 0.5f, fmaf(t, 0.5f, 1.f / 6.f)));
  float p2 = fmaf(t3, 0.5f, fmaf(t2, -1.f, 2.f / 3.f));
  bool ok = (u >= 0.f) && (u < 11.f);
  auto hA = __builtin_amdgcn_cvt_pkrtz(p3, p2);
  auto hB = __builtin_amdgcn_cvt_pkrtz(p1, p0);
  unsigned a32 = ok ? __builtin_bit_cast(unsigned, hA) : 0u;
  unsigned b32 = ok ? __builtin_bit_cast(unsigned, hB) : 0u;
  u64 P = ((u64)b32 << 32) | a32;
  int sh = i << 4;
  u64 tA = P >> ((48 - sh) & 63);
  u64 tB = P << ((sh - 48) & 63);
  u64 tC = P >> ((112 - sh) & 63);
  u64 tD = P << ((sh - 112) & 63);
  u64 lo = (sh < 64) ? tA : ((sh < 112) ? tB : 0ull);
  u64 hi = (sh < 64) ? 0ull : ((sh < 128) ? tC : tD);
  u32x4 st = {(unsigned)lo, (unsigned)(lo >> 32), (unsigned)hi, (unsigned)(hi >> 32)};
  *(u32x4*)p16 = st;
}

__device__ __forceinline__ float gelu_exact(float v) {
  return 0.5f * v * (1.f + erff(v * 0.70710678118654752f));
}

// Features from an accumulator tile (C/D map: col=lane&15 -> channel,
// row=(lane>>4)*4+reg -> pixel within group).
__device__ __forceinline__ void w2feat(char* S, int g, int nt, int rit, f32x4 a) {
  const int c = nt * 16 + rit;
#pragma unroll
  for (int r = 0; r < 4; ++r) {
    char* row = S + (g * 4 + r) * ROWB;
    float v = a[r];
    *(_Float16*)(row + c * 2) = (_Float16)fast_silu(v);
    spline_scatter(row + 128 + c * 16, v);
  }
}

// One 16x16x576 GEMM slice, K-split: load 9 B-frags (36 VGPR), 9 MFMA, reload.
__device__ __forceinline__ void gemm_slot_ks(const char* S, const half8* Bq,
                                             int nt, int l, int rit, int g,
                                             f32x4& acc) {
  const half8* bq = Bq + (size_t)nt * 18 * 64 + l;
  const char* pa = S + rit * ROWB + g * 16;
#pragma unroll
  for (int kh = 0; kh < 2; ++kh) {
    half8 bfr[9];
#pragma unroll
    for (int ks = 0; ks < 9; ++ks) bfr[ks] = bq[(kh * 9 + ks) * 64];
#pragma unroll
    for (int ks = 0; ks < 9; ++ks) {
      half8 a = *(const half8*)(pa + (kh * 9 + ks) * 64);
      acc = __builtin_amdgcn_mfma_f32_16x16x32_f16(a, bfr[ks], acc, 0, 0, 0);
    }
  }
}

// GELU + write one acc group into the f32 [64][65] LDS bounce.
__device__ __forceinline__ void bounce_acc(float* bnc, int c, int px0, f32x4 a) {
  float* row = bnc + c * 65 + px0;
#pragma unroll
  for (int r = 0; r < 4; ++r) row[r] = gelu_exact(a[r]);
}

// ---------------- mega kernel: c2r + conv + bias + 2x KAN + GELU ------------
// Block: 64 pixels (one w-half-row), 256 threads = 4 waves. Phases:
//   stage Xh -> [conv+c2r GEMM, w2feat grp0] -> 7 pipelined {GEMM || w2feat}
//   phases -> final GEMM + GELU bounce -> coalesced store.
__global__ __launch_bounds__(256, 4) void kan_mega_kernel(
    const float* __restrict__ x, float* __restrict__ y,
    const _Float16* __restrict__ Y1h,
    const half8* __restrict__ Bq1, const half8* __restrict__ Bq2,
    const half8* __restrict__ Wfrag, const half8* __restrict__ Tfrag,
    const float* __restrict__ convb) {
  __shared__ __align__(16) char Abuf[2 * 16 * ROWB];  // 37,376 B -> 4 blocks/CU
  char* A0 = Abuf;
  char* A1 = Abuf + 16 * ROWB;
  float* ybounce = (float*)A1;  // [64][65] f32 = 16,640 B (A1 region, end only)
  const int tid = threadIdx.x;
  const int l = tid & 63;
  const int nt = tid >> 6;
  const int rit = l & 15, g = l >> 4;
  const int n0 = blockIdx.x * 64;
  const int b = n0 >> 14;
  const int rem = n0 & 16383;
  const int hrow = rem >> 7, w0 = rem & 127;
  float* base = y + (size_t)b * 1048576 + (size_t)hrow * 128 + w0;
  const float* xbase = x + (size_t)b * 1048576 + (size_t)hrow * 128 + w0;

  // early fragment loads (global; latency hides under staging)
  half8 By = ((const half8*)Y1h)[((size_t)(b * 128 + hrow) * 64 + nt * 16 + rit) * 4 + g];
  half8 Wf0 = Wfrag[(nt * 2 + 0) * 64 + l];
  half8 Wf1 = Wfrag[(nt * 2 + 1) * 64 + l];
  half8 Tf0 = Tfrag[(w0 + 0 + rit) * 4 + g];
  half8 Tf1 = Tfrag[(w0 + 16 + rit) * 4 + g];
  half8 Tf2 = Tfrag[(w0 + 32 + rit) * 4 + g];
  half8 Tf3 = Tfrag[(w0 + 48 + rit) * 4 + g];
  const float cbv = convb[nt * 16 + rit];

  // ---- stage Xh[64 px][64 cin] fp16 into A0 (conv A-operand) ----
  {
    const int c = tid >> 2, lq = tid & 3;
    const float* bx = xbase + (size_t)c * 16384;
#pragma unroll
    for (int s = 0; s < 4; ++s) {
      float4 v = *(const float4*)(bx + lq * 4 + s * 16);
      const float* vp = (const float*)&v;
#pragma unroll
      for (int j = 0; j < 4; ++j)
        *(_Float16*)(A0 + (lq * 4 + s * 16 + j) * ROWX + c * 2) = (_Float16)vp[j];
    }
  }
  __syncthreads();

  const f32x4 z = {0.f, 0.f, 0.f, 0.f};
  f32x4 a00 = z, a01 = z, a02 = z, a03 = z;
  // conv + c2r + bias, one acc tile per 16-px group
#define CONV_TILE(acc, mt, TF)                                                \
  {                                                                           \
    const char* pa = A0 + (mt * 16 + rit) * ROWX;                             \
    acc = __builtin_amdgcn_mfma_f32_16x16x32_f16(TF, By, z, 0, 0, 0);         \
    half8 xa0 = *(const half8*)(pa + g * 16);                                 \
    acc = __builtin_amdgcn_mfma_f32_16x16x32_f16(xa0, Wf0, acc, 0, 0, 0);     \
    half8 xa1 = *(const half8*)(pa + 64 + g * 16);                            \
    acc = __builtin_amdgcn_mfma_f32_16x16x32_f16(xa1, Wf1, acc, 0, 0, 0);     \
    acc[0] += cbv; acc[1] += cbv; acc[2] += cbv; acc[3] += cbv;               \
  }
  CONV_TILE(a00, 0, Tf0)
  CONV_TILE(a01, 1, Tf1)
  CONV_TILE(a02, 2, Tf2)
  CONV_TILE(a03, 3, Tf3)
#undef CONV_TILE
  // same phase: layer-1 features grp0 into A1 (Xh in A0 untouched)
  w2feat(A1, g, nt, rit, a00);
  __syncthreads();

  f32x4 a10 = z, a11 = z, a12 = z, a13 = z;
  f32x4 a20 = z, a21 = z, a22 = z, a23 = z;
  // P1..P3: layer-1 GEMM(p) || features(p+1)
  gemm_slot_ks(A1, Bq1, nt, l, rit, g, a10); w2feat(A0, g, nt, rit, a01);
  __syncthreads();
  gemm_slot_ks(A0, Bq1, nt, l, rit, g, a11); w2feat(A1, g, nt, rit, a02);
  __syncthreads();
  gemm_slot_ks(A1, Bq1, nt, l, rit, g, a12); w2feat(A0, g, nt, rit, a03);
  __syncthreads();
  // P4: last layer-1 GEMM || first layer-2 feature build
  gemm_slot_ks(A0, Bq1, nt, l, rit, g, a13); w2feat(A1, g, nt, rit, a10);
  __syncthreads();
  // P5..P7: layer-2 GEMM(p) || layer-2 features(p+1)
  gemm_slot_ks(A1, Bq2, nt, l, rit, g, a20); w2feat(A0, g, nt, rit, a11);
  __syncthreads();
  gemm_slot_ks(A0, Bq2, nt, l, rit, g, a21); w2feat(A1, g, nt, rit, a12);
  __syncthreads();
  gemm_slot_ks(A1, Bq2, nt, l, rit, g, a22); w2feat(A0, g, nt, rit, a13);
  __syncthreads();
  // P8: last GEMM (reads A0) || GELU-bounce into A1 region
  const int cch = nt * 16 + rit;
  gemm_slot_ks(A0, Bq2, nt, l, rit, g, a23);
  bounce_acc(ybounce, cch, 0 + g * 4, a20);
  bounce_acc(ybounce, cch, 16 + g * 4, a21);
  bounce_acc(ybounce, cch, 32 + g * 4, a22);
  bounce_acc(ybounce, cch, 48 + g * 4, a23);
  __syncthreads();
  // ---- cooperative fully-coalesced store ----
#pragma unroll
  for (int i = 0; i < 4; ++i) {
    int idx = i * 256 + tid;
    int c = idx >> 4, q = idx & 15;
    const float* r = ybounce + c * 65 + q * 4;
    float4 v;
    v.x = r[0]; v.y = r[1]; v.z = r[2]; v.w = r[3];
    *(float4*)(base + (size_t)c * 16384 + q * 4) = v;
  }
}

// ---------------------------------------------------------------------------
extern "C" void kernel_launch(void* const* d_in, const int* in_sizes, int n_in,
                              void* d_out, int out_size, void* d_ws, size_t ws_size,
                              hipStream_t stream) {
  const float* x    = (const float*)d_in[0];
  const float* w1r  = (const float*)d_in[1];
  const float* w1i  = (const float*)d_in[2];
  const float* w2r  = (const float*)d_in[3];
  const float* w2i  = (const float*)d_in[4];
  const float* cw   = (const float*)d_in[5];
  const float* cb   = (const float*)d_in[6];
  const float* k1b  = (const float*)d_in[7];
  const float* k1s  = (const float*)d_in[8];
  const float* k1sc = (const float*)d_in[9];
  const float* k2b  = (const float*)d_in[10];
  const float* k2s  = (const float*)d_in[11];
  const float* k2sc = (const float*)d_in[12];

  char* ws = (char*)d_ws;
  float*     XfRe  = (float*)(ws + 0);          // 2 MB
  float*     XfIm  = (float*)(ws + 2097152);    // 2 MB
  _Float16*  Y1h   = (_Float16*)(ws + 4194304); // 8 MB (16*128*64*32 fp16)
  half8*     Bf1   = (half8*)(ws + 12582912);   // 73728 B
  half8*     Bf2   = (half8*)(ws + 12656640);   // 73728 B
  half8*     Wfrag = (half8*)(ws + 12730368);   // 8192 B
  half8*     Tfrag = (half8*)(ws + 12738560);   // 8192 B
  float* y = (float*)d_out;

  prep_bfrag_kernel<<<18, 256, 0, stream>>>(k1b, k1s, k1sc, Bf1);
  prep_bfrag_kernel<<<18, 256, 0, stream>>>(k2b, k2s, k2sc, Bf2);
  prep_conv_kernel<<<4, 256, 0, stream>>>(cw, Wfrag, Tfrag);
  fwd_dft_kernel<<<1024, 256, 0, stream>>>(x, XfRe, XfIm);
  mode_mix_kernel<<<512, 256, 0, stream>>>(XfRe, XfIm, w1r, w1i, w2r, w2i);
  inv_h_kernel<<<1024, 256, 0, stream>>>(XfRe, XfIm, Y1h);
  kan_mega_kernel<<<4096, 256, 0, stream>>>(x, y, Y1h, Bf1, Bf2, Wfrag, Tfrag, cb);
}

// Round 9
// 250.211 us; speedup vs baseline: 4.7352x; 1.0048x over previous
//
#include <hip/hip_runtime.h>

// ---------------------------------------------------------------------------
// KAN-FNO block, MI355X.
//   1. fwd_dft:   truncated separable rfft2 -> Xf[b,c,32,16]
//   2. mode_mix:  per-mode 16x64x64 complex GEMM (in-place on Xf), XCD-swizzled
//   3. inv_h:     inverse DFT along h -> Y1h fp16 [b][h][o][re16|im16], x2^-10
//                 (R9: output staged in LDS, stored as full 64B lines)
//   4. kan_mega:  c2r-along-w GEMM + 1x1-conv GEMM + bias (all MFMA) feeding
//                 BOTH KAN layers (MFMA f16) + exact GELU -> y. One kernel.
// R9: R8's residual jumped 13us -> 133us; only changed kernel was inv_h,
//     whose fp16 output became scattered 2-byte global stores (64 sub-dword
//     transactions per wave instr). Now compute -> LDS sh[128][32] fp16,
//     then cooperative store: 4 lanes x dwordx4 = one exact 64B line per row.
//     kan_mega unchanged from R8 (118us, absmax 0.0078).
// ---------------------------------------------------------------------------

typedef _Float16 half8 __attribute__((ext_vector_type(8)));
typedef float f32x4 __attribute__((ext_vector_type(4)));
typedef unsigned u32x4 __attribute__((ext_vector_type(4)));
typedef unsigned long long u64;

#define ROWB 1168  // KAN feature row: 576 fp16 = 1152 + 16 pad
#define ROWX 144   // conv A-tile row: 64 fp16 = 128 + 16 pad (16B aligned)

// ---------------- forward truncated rfft2 ----------------
__global__ __launch_bounds__(256) void fwd_dft_kernel(
    const float* __restrict__ x, float* __restrict__ XfRe, float* __restrict__ XfIm) {
  __shared__ __align__(16) float img[64 * 132];
  __shared__ float XwRe[128 * 16];
  __shared__ float XwIm[128 * 16];
  __shared__ float ctab[128];
  __shared__ float stab[128];
  const int tid = threadIdx.x;
  const int bc = blockIdx.x;
  const float4* src4 = (const float4*)(x + (size_t)bc * 16384);
  if (tid < 128) {
    float s, c;
    sincosf((float)((double)tid * (6.283185307179586476925287 / 128.0)), &s, &c);
    ctab[tid] = c;
    stab[tid] = s;
  }
  for (int h0 = 0; h0 < 128; h0 += 64) {
    __syncthreads();
    for (int e = tid; e < 2048; e += 256) {
      int r = e >> 5, w4 = e & 31;
      float4 v = src4[(h0 + r) * 32 + w4];
      *((float4*)&img[r * 132 + w4 * 4]) = v;
    }
    __syncthreads();
    for (int e = tid; e < 1024; e += 256) {
      int hr = e >> 4, kx = e & 15;
      const float* row = img + hr * 132;
      float re = 0.f, im = 0.f;
      int t = 0;
#pragma unroll 8
      for (int w = 0; w < 128; ++w) {
        float v = row[w];
        re = fmaf(v, ctab[t], re);
        im = fmaf(v, stab[t], im);
        t = (t + kx) & 127;
      }
      int idx = (h0 + hr) * 16 + kx;
      XwRe[idx] = re;
      XwIm[idx] = -im;
    }
  }
  __syncthreads();
  for (int e = tid; e < 512; e += 256) {
    int m = e >> 4, kx = e & 15;
    int ky = (m < 16) ? m : (m + 96);
    float re = 0.f, im = 0.f;
    for (int h = 0; h < 128; ++h) {
      int t = (ky * h) & 127;
      float c = ctab[t], s = stab[t];
      float ar = XwRe[h * 16 + kx], ai = XwIm[h * 16 + kx];
      re += ar * c + ai * s;
      im += ai * c - ar * s;
    }
    size_t off = (size_t)bc * 512 + e;
    XfRe[off] = re;
    XfIm[off] = im;
  }
}

// ---------------- per-mode complex channel mixing (in-place) ----------------
__global__ __launch_bounds__(256) void mode_mix_kernel(
    float* __restrict__ XfRe, float* __restrict__ XfIm,
    const float* __restrict__ w1r, const float* __restrict__ w1i,
    const float* __restrict__ w2r, const float* __restrict__ w2i) {
  __shared__ float Wr[4096];
  __shared__ float Wi[4096];
  __shared__ float Ar[1024];
  __shared__ float Ai[1024];
  const int tid = threadIdx.x;
  const int bid = blockIdx.x;
  const int mode = ((bid & 7) << 6) | (bid >> 3);  // XCD-chunked bijective
  const int m = mode >> 4, kx = mode & 15;
  const float* wr = (m < 16) ? w1r : w2r;
  const float* wi = (m < 16) ? w1i : w2i;
  const int woff = (m & 15) * 16 + kx;
  for (int e = tid; e < 4096; e += 256) {
    Wr[e] = wr[(size_t)e * 256 + woff];
    Wi[e] = wi[(size_t)e * 256 + woff];
  }
  for (int e = tid; e < 1024; e += 256) {
    Ar[e] = XfRe[(size_t)e * 512 + mode];
    Ai[e] = XfIm[(size_t)e * 512 + mode];
  }
  __syncthreads();
  const int o = tid & 63;
  const int b0 = tid >> 6;
  float outR[4], outI[4];
#pragma unroll
  for (int bb = 0; bb < 4; ++bb) {
    const int b = b0 * 4 + bb;
    float re = 0.f, im = 0.f;
    for (int i = 0; i < 64; ++i) {
      float ar = Ar[b * 64 + i], ai = Ai[b * 64 + i];
      float br = Wr[i * 64 + o], bi = Wi[i * 64 + o];
      re += ar * br - ai * bi;
      im += ar * bi + ai * br;
    }
    outR[bb] = re;
    outI[bb] = im;
  }
#pragma unroll
  for (int bb = 0; bb < 4; ++bb) {
    const int b = b0 * 4 + bb;
    size_t off = (size_t)(b * 64 + o) * 512 + mode;
    XfRe[off] = outR[bb];
    XfIm[off] = outI[bb];
  }
}

// ---------------- inverse DFT along h -> fp16 fragment layout ---------------
// Y1h[b][h][o][k], k: 0..15 = Re(kx), 16..31 = Im(kx). Values scaled 2^-10
// (the c2r trig table carries the remaining 1/16 of the irfft2 1/16384).
// R9: results staged in LDS; global stores are exact 64B lines (4x dwordx4).
__global__ __launch_bounds__(256) void inv_h_kernel(
    const float* __restrict__ GfRe, const float* __restrict__ GfIm,
    _Float16* __restrict__ Y1h) {
  __shared__ float Gr[512];
  __shared__ float Gi[512];
  __shared__ float ctab[128];
  __shared__ float stab[128];
  __shared__ __align__(16) _Float16 sh[128 * 32];  // 8 KB staging
  const int tid = threadIdx.x;
  const int bo = blockIdx.x;
  const int bb = bo >> 6, o = bo & 63;
  if (tid < 128) {
    float s, c;
    sincosf((float)((double)tid * (6.283185307179586476925287 / 128.0)), &s, &c);
    ctab[tid] = c;
    stab[tid] = s;
  }
  for (int e = tid; e < 512; e += 256) {
    Gr[e] = GfRe[(size_t)bo * 512 + e];
    Gi[e] = GfIm[(size_t)bo * 512 + e];
  }
  __syncthreads();
  for (int e = tid; e < 2048; e += 256) {
    int h = e >> 4, kx = e & 15;
    float re = 0.f, im = 0.f;
#pragma unroll
    for (int m = 0; m < 32; ++m) {
      int ky = (m < 16) ? m : (m + 96);
      int t = (ky * h) & 127;
      float c = ctab[t], s = stab[t];
      float gr = Gr[m * 16 + kx], gi = Gi[m * 16 + kx];
      re += gr * c - gi * s;
      im += gr * s + gi * c;
    }
    sh[h * 32 + kx] = (_Float16)(re * 9.765625e-4f);       // * 2^-10
    sh[h * 32 + 16 + kx] = (_Float16)(im * 9.765625e-4f);
  }
  __syncthreads();
  // cooperative store: row (bb,h,o) = 64 B = 4 lanes x 16 B, fully coalesced
#pragma unroll
  for (int i = 0; i < 2; ++i) {
    int idx = i * 256 + tid;
    int h = idx >> 2, q = idx & 3;
    u32x4 v = ((const u32x4*)(sh + h * 32))[q];
    *(u32x4*)(Y1h + ((size_t)(bb * 128 + h) * 64 + o) * 32 + q * 8) = v;
  }
}

// ---------------- KAN weight prep: fp16 fragment-order -----------------
__global__ __launch_bounds__(256) void prep_bfrag_kernel(
    const float* __restrict__ base_w, const float* __restrict__ spline_w,
    const float* __restrict__ scaler, half8* __restrict__ out) {
  int idx = blockIdx.x * 256 + threadIdx.x;
  if (idx >= 4608) return;
  int lane = idx & 63;
  int ks = (idx >> 6) % 18;
  int nt = idx / (64 * 18);
  int n = nt * 16 + (lane & 15);
  int k0 = ks * 32 + (lane >> 4) * 8;
  half8 hv;
#pragma unroll
  for (int j = 0; j < 8; ++j) {
    int k = k0 + j;
    float val;
    if (k < 64) {
      val = base_w[n * 64 + k];
    } else {
      int c = (k - 64) >> 3, jj = (k - 64) & 7;
      val = spline_w[(n * 64 + c) * 8 + jj] * scaler[n * 64 + c];
    }
    hv[j] = (_Float16)val;
  }
  out[idx] = hv;
}

// ---------------- conv-W fragments + c2r trig table -----------------
// Wfrag[(nt*2+ks)*64+l][j] = convw[cout=nt*16+(l&15)][cin=ks*32+(l>>4)*8+j]
// Tfrag[w*4+g][j]: k=g*8+j; k<16: Re coeff (kx=0 -> 1, else 2cos); k>=16:
// Im coeff (kx=0 -> 0 = pocketfft "imag of bin 0 ignored", else -2sin).
// Scaled by 1/16 (Y1h carries 2^-10; product = coeff/16384).
__global__ __launch_bounds__(256) void prep_conv_kernel(
    const float* __restrict__ convw, half8* __restrict__ Wfrag,
    half8* __restrict__ Tfrag) {
  int idx = blockIdx.x * 256 + threadIdx.x;
  if (idx < 512) {
    int l = idx & 63, ks = (idx >> 6) & 1, nt = idx >> 7;
    int cout = nt * 16 + (l & 15);
    int cin0 = ks * 32 + (l >> 4) * 8;
    half8 hv;
#pragma unroll
    for (int j = 0; j < 8; ++j) hv[j] = (_Float16)convw[cout * 64 + cin0 + j];
    Wfrag[idx] = hv;
  } else if (idx < 1024) {
    int e = idx - 512;
    int w = e >> 2, g = e & 3;
    half8 hv;
#pragma unroll
    for (int j = 0; j < 8; ++j) {
      int k = g * 8 + j;
      float coeff;
      if (k < 16) {
        int t = (k * w) & 127;
        coeff = (k == 0) ? 1.f
                         : 2.f * cosf((float)((double)t * (6.283185307179586476925287 / 128.0)));
      } else {
        int kx = k - 16;
        int t = (kx * w) & 127;
        coeff = (kx == 0) ? 0.f
                          : -2.f * sinf((float)((double)t * (6.283185307179586476925287 / 128.0)));
      }
      hv[j] = (_Float16)(coeff * 0.0625f);
    }
    Tfrag[e] = hv;
  }
}

// ---------------- KAN feature math ----------------
__device__ __forceinline__ float fast_silu(float v) {
  return v * (1.f / (1.f + __expf(-v)));
}

// Cubic B-spline: 4 nonzero bases packed into a 64-bit fp16 payload, placed
// at basis offset via branchless 128-bit shift, one b128 LDS write.
__device__ __forceinline__ void spline_scatter(char* p16, float v) {
  const float Klo = __fsub_rn(__fmul_rn(-3.f, 0.4f), 1.0f);
  float u = (v - Klo) * 2.5f;
  float uc = fminf(fmaxf(u, 0.f), 10.5f);
  int i = (int)uc;
  float t = u - (float)i;
  float t2 = t * t, t3 = t2 * t;
  float omt = 1.f - t;
  float p0 = t3 * (1.f / 6.f);
  float p3 = omt * omt * (omt * (1.f / 6.f));
  float p1 = fmaf(t3, -0.5f, fmaf(t2, 0.5f, fmaf(t, 0.5f, 1.f / 6.f)));
  float p2 = fmaf(t3, 0.5f, fmaf(t2, -1.f, 2.f / 3.f));
  bool ok = (u >= 0.f) && (u < 11.f);
  auto hA = __builtin_amdgcn_cvt_pkrtz(p3, p2);
  auto hB = __builtin_amdgcn_cvt_pkrtz(p1, p0);
  unsigned a32 = ok ? __builtin_bit_cast(unsigned, hA) : 0u;
  unsigned b32 = ok ? __builtin_bit_cast(unsigned, hB) : 0u;
  u64 P = ((u64)b32 << 32) | a32;
  int sh = i << 4;
  u64 tA = P >> ((48 - sh) & 63);
  u64 tB = P << ((sh - 48) & 63);
  u64 tC = P >> ((112 - sh) & 63);
  u64 tD = P << ((sh - 112) & 63);
  u64 lo = (sh < 64) ? tA : ((sh < 112) ? tB : 0ull);
  u64 hi = (sh < 64) ? 0ull : ((sh < 128) ? tC : tD);
  u32x4 st = {(unsigned)lo, (unsigned)(lo >> 32), (unsigned)hi, (unsigned)(hi >> 32)};
  *(u32x4*)p16 = st;
}

__device__ __forceinline__ float gelu_exact(float v) {
  return 0.5f * v * (1.f + erff(v * 0.70710678118654752f));
}

// Features from an accumulator tile (C/D map: col=lane&15 -> channel,
// row=(lane>>4)*4+reg -> pixel within group).
__device__ __forceinline__ void w2feat(char* S, int g, int nt, int rit, f32x4 a) {
  const int c = nt * 16 + rit;
#pragma unroll
  for (int r = 0; r < 4; ++r) {
    char* row = S + (g * 4 + r) * ROWB;
    float v = a[r];
    *(_Float16*)(row + c * 2) = (_Float16)fast_silu(v);
    spline_scatter(row + 128 + c * 16, v);
  }
}

// One 16x16x576 GEMM slice, K-split: load 9 B-frags (36 VGPR), 9 MFMA, reload.
__device__ __forceinline__ void gemm_slot_ks(const char* S, const half8* Bq,
                                             int nt, int l, int rit, int g,
                                             f32x4& acc) {
  const half8* bq = Bq + (size_t)nt * 18 * 64 + l;
  const char* pa = S + rit * ROWB + g * 16;
#pragma unroll
  for (int kh = 0; kh < 2; ++kh) {
    half8 bfr[9];
#pragma unroll
    for (int ks = 0; ks < 9; ++ks) bfr[ks] = bq[(kh * 9 + ks) * 64];
#pragma unroll
    for (int ks = 0; ks < 9; ++ks) {
      half8 a = *(const half8*)(pa + (kh * 9 + ks) * 64);
      acc = __builtin_amdgcn_mfma_f32_16x16x32_f16(a, bfr[ks], acc, 0, 0, 0);
    }
  }
}

// GELU + write one acc group into the f32 [64][65] LDS bounce.
__device__ __forceinline__ void bounce_acc(float* bnc, int c, int px0, f32x4 a) {
  float* row = bnc + c * 65 + px0;
#pragma unroll
  for (int r = 0; r < 4; ++r) row[r] = gelu_exact(a[r]);
}

// ---------------- mega kernel: c2r + conv + bias + 2x KAN + GELU ------------
// Block: 64 pixels (one w-half-row), 256 threads = 4 waves. Phases:
//   stage Xh -> [conv+c2r GEMM, w2feat grp0] -> 7 pipelined {GEMM || w2feat}
//   phases -> final GEMM + GELU bounce -> coalesced store.
__global__ __launch_bounds__(256, 4) void kan_mega_kernel(
    const float* __restrict__ x, float* __restrict__ y,
    const _Float16* __restrict__ Y1h,
    const half8* __restrict__ Bq1, const half8* __restrict__ Bq2,
    const half8* __restrict__ Wfrag, const half8* __restrict__ Tfrag,
    const float* __restrict__ convb) {
  __shared__ __align__(16) char Abuf[2 * 16 * ROWB];  // 37,376 B -> 4 blocks/CU
  char* A0 = Abuf;
  char* A1 = Abuf + 16 * ROWB;
  float* ybounce = (float*)A1;  // [64][65] f32 = 16,640 B (A1 region, end only)
  const int tid = threadIdx.x;
  const int l = tid & 63;
  const int nt = tid >> 6;
  const int rit = l & 15, g = l >> 4;
  const int n0 = blockIdx.x * 64;
  const int b = n0 >> 14;
  const int rem = n0 & 16383;
  const int hrow = rem >> 7, w0 = rem & 127;
  float* base = y + (size_t)b * 1048576 + (size_t)hrow * 128 + w0;
  const float* xbase = x + (size_t)b * 1048576 + (size_t)hrow * 128 + w0;

  // early fragment loads (global; latency hides under staging)
  half8 By = ((const half8*)Y1h)[((size_t)(b * 128 + hrow) * 64 + nt * 16 + rit) * 4 + g];
  half8 Wf0 = Wfrag[(nt * 2 + 0) * 64 + l];
  half8 Wf1 = Wfrag[(nt * 2 + 1) * 64 + l];
  half8 Tf0 = Tfrag[(w0 + 0 + rit) * 4 + g];
  half8 Tf1 = Tfrag[(w0 + 16 + rit) * 4 + g];
  half8 Tf2 = Tfrag[(w0 + 32 + rit) * 4 + g];
  half8 Tf3 = Tfrag[(w0 + 48 + rit) * 4 + g];
  const float cbv = convb[nt * 16 + rit];

  // ---- stage Xh[64 px][64 cin] fp16 into A0 (conv A-operand) ----
  {
    const int c = tid >> 2, lq = tid & 3;
    const float* bx = xbase + (size_t)c * 16384;
#pragma unroll
    for (int s = 0; s < 4; ++s) {
      float4 v = *(const float4*)(bx + lq * 4 + s * 16);
      const float* vp = (const float*)&v;
#pragma unroll
      for (int j = 0; j < 4; ++j)
        *(_Float16*)(A0 + (lq * 4 + s * 16 + j) * ROWX + c * 2) = (_Float16)vp[j];
    }
  }
  __syncthreads();

  const f32x4 z = {0.f, 0.f, 0.f, 0.f};
  f32x4 a00 = z, a01 = z, a02 = z, a03 = z;
  // conv + c2r + bias, one acc tile per 16-px group
#define CONV_TILE(acc, mt, TF)                                                \
  {                                                                           \
    const char* pa = A0 + (mt * 16 + rit) * ROWX;                             \
    acc = __builtin_amdgcn_mfma_f32_16x16x32_f16(TF, By, z, 0, 0, 0);         \
    half8 xa0 = *(const half8*)(pa + g * 16);                                 \
    acc = __builtin_amdgcn_mfma_f32_16x16x32_f16(xa0, Wf0, acc, 0, 0, 0);     \
    half8 xa1 = *(const half8*)(pa + 64 + g * 16);                            \
    acc = __builtin_amdgcn_mfma_f32_16x16x32_f16(xa1, Wf1, acc, 0, 0, 0);     \
    acc[0] += cbv; acc[1] += cbv; acc[2] += cbv; acc[3] += cbv;               \
  }
  CONV_TILE(a00, 0, Tf0)
  CONV_TILE(a01, 1, Tf1)
  CONV_TILE(a02, 2, Tf2)
  CONV_TILE(a03, 3, Tf3)
#undef CONV_TILE
  // same phase: layer-1 features grp0 into A1 (Xh in A0 untouched)
  w2feat(A1, g, nt, rit, a00);
  __syncthreads();

  f32x4 a10 = z, a11 = z, a12 = z, a13 = z;
  f32x4 a20 = z, a21 = z, a22 = z, a23 = z;
  // P1..P3: layer-1 GEMM(p) || features(p+1)
  gemm_slot_ks(A1, Bq1, nt, l, rit, g, a10); w2feat(A0, g, nt, rit, a01);
  __syncthreads();
  gemm_slot_ks(A0, Bq1, nt, l, rit, g, a11); w2feat(A1, g, nt, rit, a02);
  __syncthreads();
  gemm_slot_ks(A1, Bq1, nt, l, rit, g, a12); w2feat(A0, g, nt, rit, a03);
  __syncthreads();
  // P4: last layer-1 GEMM || first layer-2 feature build
  gemm_slot_ks(A0, Bq1, nt, l, rit, g, a13); w2feat(A1, g, nt, rit, a10);
  __syncthreads();
  // P5..P7: layer-2 GEMM(p) || layer-2 features(p+1)
  gemm_slot_ks(A1, Bq2, nt, l, rit, g, a20); w2feat(A0, g, nt, rit, a11);
  __syncthreads();
  gemm_slot_ks(A0, Bq2, nt, l, rit, g, a21); w2feat(A1, g, nt, rit, a12);
  __syncthreads();
  gemm_slot_ks(A1, Bq2, nt, l, rit, g, a22); w2feat(A0, g, nt, rit, a13);
  __syncthreads();
  // P8: last GEMM (reads A0) || GELU-bounce into A1 region
  const int cch = nt * 16 + rit;
  gemm_slot_ks(A0, Bq2, nt, l, rit, g, a23);
  bounce_acc(ybounce, cch, 0 + g * 4, a20);
  bounce_acc(ybounce, cch, 16 + g * 4, a21);
  bounce_acc(ybounce, cch, 32 + g * 4, a22);
  bounce_acc(ybounce, cch, 48 + g * 4, a23);
  __syncthreads();
  // ---- cooperative fully-coalesced store ----
#pragma unroll
  for (int i = 0; i < 4; ++i) {
    int idx = i * 256 + tid;
    int c = idx >> 4, q = idx & 15;
    const float* r = ybounce + c * 65 + q * 4;
    float4 v;
    v.x = r[0]; v.y = r[1]; v.z = r[2]; v.w = r[3];
    *(float4*)(base + (size_t)c * 16384 + q * 4) = v;
  }
}

// ---------------------------------------------------------------------------
extern "C" void kernel_launch(void* const* d_in, const int* in_sizes, int n_in,
                              void* d_out, int out_size, void* d_ws, size_t ws_size,
                              hipStream_t stream) {
  const float* x    = (const float*)d_in[0];
  const float* w1r  = (const float*)d_in[1];
  const float* w1i  = (const float*)d_in[2];
  const float* w2r  = (const float*)d_in[3];
  const float* w2i  = (const float*)d_in[4];
  const float* cw   = (const float*)d_in[5];
  const float* cb   = (const float*)d_in[6];
  const float* k1b  = (const float*)d_in[7];
  const float* k1s  = (const float*)d_in[8];
  const float* k1sc = (const float*)d_in[9];
  const float* k2b  = (const float*)d_in[10];
  const float* k2s  = (const float*)d_in[11];
  const float* k2sc = (const float*)d_in[12];

  char* ws = (char*)d_ws;
  float*     XfRe  = (float*)(ws + 0);          // 2 MB
  float*     XfIm  = (float*)(ws + 2097152);    // 2 MB
  _Float16*  Y1h   = (_Float16*)(ws + 4194304); // 8 MB (16*128*64*32 fp16)
  half8*     Bf1   = (half8*)(ws + 12582912);   // 73728 B
  half8*     Bf2   = (half8*)(ws + 12656640);   // 73728 B
  half8*     Wfrag = (half8*)(ws + 12730368);   // 8192 B
  half8*     Tfrag = (half8*)(ws + 12738560);   // 8192 B
  float* y = (float*)d_out;

  prep_bfrag_kernel<<<18, 256, 0, stream>>>(k1b, k1s, k1sc, Bf1);
  prep_bfrag_kernel<<<18, 256, 0, stream>>>(k2b, k2s, k2sc, Bf2);
  prep_conv_kernel<<<4, 256, 0, stream>>>(cw, Wfrag, Tfrag);
  fwd_dft_kernel<<<1024, 256, 0, stream>>>(x, XfRe, XfIm);
  mode_mix_kernel<<<512, 256, 0, stream>>>(XfRe, XfIm, w1r, w1i, w2r, w2i);
  inv_h_kernel<<<1024, 256, 0, stream>>>(XfRe, XfIm, Y1h);
  kan_mega_kernel<<<4096, 256, 0, stream>>>(x, y, Y1h, Bf1, Bf2, Wfrag, Tfrag, cb);
}

// Round 10
// 174.332 us; speedup vs baseline: 6.7962x; 1.4353x over previous
//
#include <hip/hip_runtime.h>

// ---------------------------------------------------------------------------
// KAN-FNO block, MI355X.
//   1. fwd_dft:   truncated separable rfft2 via MFMA (2 GEMM stages, fp16
//                 trig fragment tables) -> Xf fp32 [b,c][mode=32x16]
//   2. mode_mix:  per-mode 16x64x64 complex GEMM (in-place on Xf), XCD-swizzled
//   3. inv_h:     inverse DFT along h via MFMA -> Y1h fp16 [b][h][o][re|im]x2^-10
//   4. kan_mega:  c2r-along-w GEMM + 1x1-conv GEMM + bias (all MFMA) feeding
//                 BOTH KAN layers (MFMA f16) + exact GELU -> y. One kernel.
// R10: residual ledger showed the DFT chain cost ~130us all along (hidden
//     below top-5; R7's "13us" was a cold-dispatch artifact). fwd_dft was
//     LDS-issue-bound (3 scalar ds_read per fma pair). Both fwd stages and
//     inv_h are now MFMA GEMMs with precomputed fp16 trig fragment tables
//     (integer-mod arg reduction -> same trig values as scalar version).
//     fp16 forward-path quantization is relative (~1e-3) -> ~4e-5 on x1.
// ---------------------------------------------------------------------------

typedef _Float16 half8 __attribute__((ext_vector_type(8)));
typedef float f32x4 __attribute__((ext_vector_type(4)));
typedef unsigned u32x2 __attribute__((ext_vector_type(2)));
typedef unsigned u32x4 __attribute__((ext_vector_type(4)));
typedef unsigned long long u64;

#define ROWB 1168  // KAN feature row: 576 fp16 = 1152 + 16 pad
#define ROWX 144   // conv A-tile row: 64 fp16 = 128 + 16 pad

__device__ __forceinline__ unsigned pk2(float a, float b) {
  auto h = __builtin_amdgcn_cvt_pkrtz(a, b);
  return __builtin_bit_cast(unsigned, h);
}

// ---------------- DFT trig fragment tables (fp16) ----------------
// T1f[(ks*2+nt)*64+l][j]: stage-1 B. w=ks*32+(l>>4)*8+j, kx=l&15.
//   nt=0: cos(2pi w kx/128); nt=1: -sin(...)  (e^{-i}, Xw_im = -sum v sin)
// A2c/A2s/A2sn[(mt*4+ks)*64+l][j]: stage-2 A. m'=mt*16+(l&15),
//   ky = m'<16?m':m'+96, h=ks*32+(l>>4)*8+j. c / s / -s of 2pi ky h/128.
// A3c/A3s/A3sn[mt*64+l][j]: inv-h A. h=mt*16+(l&15), m=(l>>4)*8+j,
//   ky = m<16?m:m+96. c / s / -s of 2pi ky h/128.
__global__ __launch_bounds__(256) void prep_dft_tables_kernel(
    half8* __restrict__ T1f, half8* __restrict__ A2c, half8* __restrict__ A2s,
    half8* __restrict__ A2sn, half8* __restrict__ A3c, half8* __restrict__ A3s,
    half8* __restrict__ A3sn) {
  int idx = blockIdx.x * 256 + threadIdx.x;
  if (idx >= 7 * 512) return;
  int tab = idx >> 9, e = idx & 511, l = e & 63, eg = e >> 6;
  int lg = l >> 4, li = l & 15;
  const double W0 = 6.283185307179586476925287 / 128.0;
  half8 hv;
#pragma unroll
  for (int j = 0; j < 8; ++j) {
    float val;
    if (tab == 0) {
      int ks = eg >> 1, nt = eg & 1;
      int w = ks * 32 + lg * 8 + j, kx = li;
      int t = (w * kx) & 127;
      float s, c;
      sincosf((float)((double)t * W0), &s, &c);
      val = nt ? -s : c;
    } else if (tab <= 3) {
      int mt = eg >> 2, ks = eg & 3;
      int mp = mt * 16 + li;
      int ky = mp < 16 ? mp : mp + 96;
      int h = ks * 32 + lg * 8 + j;
      int t = (ky * h) & 127;
      float s, c;
      sincosf((float)((double)t * W0), &s, &c);
      val = (tab == 1) ? c : (tab == 2) ? s : -s;
    } else {
      int h = eg * 16 + li;
      int m = lg * 8 + j;
      int ky = m < 16 ? m : m + 96;
      int t = (ky * h) & 127;
      float s, c;
      sincosf((float)((double)t * W0), &s, &c);
      val = (tab == 4) ? c : (tab == 5) ? s : -s;
    }
    hv[j] = (_Float16)val;
  }
  half8* dst = (tab == 0)   ? T1f
               : (tab == 1) ? A2c
               : (tab == 2) ? A2s
               : (tab == 3) ? A2sn
               : (tab == 4) ? A3c
               : (tab == 5) ? A3s
                            : A3sn;
  dst[e] = hv;
}

// ---------------- forward truncated rfft2, MFMA ----------------
// Block = one (b,c) image, 4 waves.
// Stage 1: Xw[h][n] (n<16 Re, n>=16 Im), M=128 N=32 K=128; wave -> mt {2w,2w+1}.
// Stage 2: Xf[m'][kx], M=32 N=32 K=128; wave -> tile (mt2=w&1, nt2=w>>1).
__global__ __launch_bounds__(256) void fwd_dft_kernel(
    const float* __restrict__ x, float* __restrict__ XfRe, float* __restrict__ XfIm,
    const half8* __restrict__ T1f, const half8* __restrict__ A2c,
    const half8* __restrict__ A2s, const half8* __restrict__ A2sn) {
  __shared__ __align__(16) char sImg[128 * 272];  // fp16 [h][w], 272B rows
  __shared__ __align__(16) char sXw[32 * 272];    // fp16 [n][h] transposed
  const int tid = threadIdx.x;
  const int l = tid & 63, wv = tid >> 6;
  const int rit = l & 15, g = l >> 4;
  const int bc = blockIdx.x;
  const float4* src4 = (const float4*)(x + (size_t)bc * 16384);

  half8 t1f[8];
#pragma unroll
  for (int i = 0; i < 8; ++i) t1f[i] = T1f[i * 64 + l];
  const int mt2 = wv & 1, nt2 = wv >> 1;
  const half8* a2op = (nt2 == 0) ? A2s : A2sn;
  half8 a2c[4], a2o[4];
#pragma unroll
  for (int ks = 0; ks < 4; ++ks) {
    a2c[ks] = A2c[(mt2 * 4 + ks) * 64 + l];
    a2o[ks] = a2op[(mt2 * 4 + ks) * 64 + l];
  }

  // stage x f32 -> fp16 sImg
#pragma unroll
  for (int i = 0; i < 16; ++i) {
    int idx = i * 256 + tid;
    int r = idx >> 5, c4 = idx & 31;
    float4 v = src4[idx];
    u32x2 p = {pk2(v.x, v.y), pk2(v.z, v.w)};
    *(u32x2*)(sImg + r * 272 + c4 * 8) = p;
  }
  __syncthreads();

  // stage 1 GEMM
  const f32x4 z = {0.f, 0.f, 0.f, 0.f};
  f32x4 s1[2][2];
  s1[0][0] = z; s1[0][1] = z; s1[1][0] = z; s1[1][1] = z;
#pragma unroll
  for (int ks = 0; ks < 4; ++ks) {
#pragma unroll
    for (int mi = 0; mi < 2; ++mi) {
      const char* pa = sImg + ((wv * 2 + mi) * 16 + rit) * 272 + ks * 64 + g * 16;
      half8 a = *(const half8*)pa;
      s1[mi][0] = __builtin_amdgcn_mfma_f32_16x16x32_f16(a, t1f[ks * 2 + 0], s1[mi][0], 0, 0, 0);
      s1[mi][1] = __builtin_amdgcn_mfma_f32_16x16x32_f16(a, t1f[ks * 2 + 1], s1[mi][1], 0, 0, 0);
    }
  }
  // C (row=h'=mt*16+g*4+r, col=n'=nt*16+rit) -> sXw[n'][h'], 4 rows packed b64
#pragma unroll
  for (int mi = 0; mi < 2; ++mi)
#pragma unroll
    for (int nt = 0; nt < 2; ++nt) {
      u32x2 p = {pk2(s1[mi][nt][0], s1[mi][nt][1]), pk2(s1[mi][nt][2], s1[mi][nt][3])};
      *(u32x2*)(sXw + (nt * 16 + rit) * 272 + ((wv * 2 + mi) * 16 + g * 4) * 2) = p;
    }
  __syncthreads();

  // stage 2 GEMM: one tile per wave
  f32x4 acc2 = z;
#pragma unroll
  for (int ks = 0; ks < 4; ++ks) {
    half8 bre = *(const half8*)(sXw + rit * 272 + ks * 64 + g * 16);
    half8 bim = *(const half8*)(sXw + (16 + rit) * 272 + ks * 64 + g * 16);
    half8 b1 = (nt2 == 0) ? bre : bim;
    half8 b2 = (nt2 == 0) ? bim : bre;
    acc2 = __builtin_amdgcn_mfma_f32_16x16x32_f16(a2c[ks], b1, acc2, 0, 0, 0);
    acc2 = __builtin_amdgcn_mfma_f32_16x16x32_f16(a2o[ks], b2, acc2, 0, 0, 0);
  }
  float* outp = ((nt2 == 0) ? XfRe : XfIm) + (size_t)bc * 512 + (mt2 * 16 + g * 4) * 16 + rit;
#pragma unroll
  for (int r = 0; r < 4; ++r) outp[r * 16] = acc2[r];
}

// ---------------- per-mode complex channel mixing (in-place) ----------------
__global__ __launch_bounds__(256) void mode_mix_kernel(
    float* __restrict__ XfRe, float* __restrict__ XfIm,
    const float* __restrict__ w1r, const float* __restrict__ w1i,
    const float* __restrict__ w2r, const float* __restrict__ w2i) {
  __shared__ float Wr[4096];
  __shared__ float Wi[4096];
  __shared__ float Ar[1024];
  __shared__ float Ai[1024];
  const int tid = threadIdx.x;
  const int bid = blockIdx.x;
  const int mode = ((bid & 7) << 6) | (bid >> 3);  // XCD-chunked bijective
  const int m = mode >> 4, kx = mode & 15;
  const float* wr = (m < 16) ? w1r : w2r;
  const float* wi = (m < 16) ? w1i : w2i;
  const int woff = (m & 15) * 16 + kx;
  for (int e = tid; e < 4096; e += 256) {
    Wr[e] = wr[(size_t)e * 256 + woff];
    Wi[e] = wi[(size_t)e * 256 + woff];
  }
  for (int e = tid; e < 1024; e += 256) {
    Ar[e] = XfRe[(size_t)e * 512 + mode];
    Ai[e] = XfIm[(size_t)e * 512 + mode];
  }
  __syncthreads();
  const int o = tid & 63;
  const int b0 = tid >> 6;
  float outR[4], outI[4];
#pragma unroll
  for (int bb = 0; bb < 4; ++bb) {
    const int b = b0 * 4 + bb;
    float re = 0.f, im = 0.f;
    for (int i = 0; i < 64; ++i) {
      float ar = Ar[b * 64 + i], ai = Ai[b * 64 + i];
      float br = Wr[i * 64 + o], bi = Wi[i * 64 + o];
      re += ar * br - ai * bi;
      im += ar * bi + ai * br;
    }
    outR[bb] = re;
    outI[bb] = im;
  }
#pragma unroll
  for (int bb = 0; bb < 4; ++bb) {
    const int b = b0 * 4 + bb;
    size_t off = (size_t)(b * 64 + o) * 512 + mode;
    XfRe[off] = outR[bb];
    XfIm[off] = outI[bb];
  }
}

// ---------------- inverse DFT along h, MFMA ----------------
// Block = one (b,o), 4 waves. Y[h][kx] (re/im), M=128 N=32 K=32 modes.
// Y_re = A3c x Gr + A3sn x Gi ; Y_im = A3s x Gr + A3c x Gi. Output x2^-10
// staged in LDS, stored as full 64B lines (Y1h[b][h][o][re16|im16]).
__global__ __launch_bounds__(256) void inv_h_kernel(
    const float* __restrict__ GfRe, const float* __restrict__ GfIm,
    _Float16* __restrict__ Y1h, const half8* __restrict__ A3c,
    const half8* __restrict__ A3s, const half8* __restrict__ A3sn) {
  __shared__ __align__(16) char Ysh[128 * 80];  // fp16 [h][32], 80B rows
  const int tid = threadIdx.x;
  const int l = tid & 63, wv = tid >> 6;
  const int rit = l & 15, g = l >> 4;
  const int bo = blockIdx.x;
  const int bb = bo >> 6, o = bo & 63;
  // B fragments: G[m=g*8+j][kx=rit] * 2^-10 -> fp16
  float gr[8], gi[8];
#pragma unroll
  for (int j = 0; j < 8; ++j) {
    size_t off = (size_t)bo * 512 + (size_t)(g * 8 + j) * 16 + rit;
    gr[j] = GfRe[off];
    gi[j] = GfIm[off];
  }
  u32x4 ur, ui;
#pragma unroll
  for (int p = 0; p < 4; ++p) {
    ur[p] = pk2(gr[2 * p] * 9.765625e-4f, gr[2 * p + 1] * 9.765625e-4f);
    ui[p] = pk2(gi[2 * p] * 9.765625e-4f, gi[2 * p + 1] * 9.765625e-4f);
  }
  half8 grF = __builtin_bit_cast(half8, ur);
  half8 giF = __builtin_bit_cast(half8, ui);
  half8 a3c[2], a3s[2], a3sn[2];
#pragma unroll
  for (int mi = 0; mi < 2; ++mi) {
    a3c[mi] = A3c[(wv * 2 + mi) * 64 + l];
    a3s[mi] = A3s[(wv * 2 + mi) * 64 + l];
    a3sn[mi] = A3sn[(wv * 2 + mi) * 64 + l];
  }
  const f32x4 z = {0.f, 0.f, 0.f, 0.f};
#pragma unroll
  for (int mi = 0; mi < 2; ++mi) {
    f32x4 ar = z, ai = z;
    ar = __builtin_amdgcn_mfma_f32_16x16x32_f16(a3c[mi], grF, ar, 0, 0, 0);
    ar = __builtin_amdgcn_mfma_f32_16x16x32_f16(a3sn[mi], giF, ar, 0, 0, 0);
    ai = __builtin_amdgcn_mfma_f32_16x16x32_f16(a3s[mi], grF, ai, 0, 0, 0);
    ai = __builtin_amdgcn_mfma_f32_16x16x32_f16(a3c[mi], giF, ai, 0, 0, 0);
#pragma unroll
    for (int r = 0; r < 4; ++r) {
      int h = (wv * 2 + mi) * 16 + g * 4 + r;
      *(_Float16*)(Ysh + h * 80 + rit * 2) = (_Float16)ar[r];
      *(_Float16*)(Ysh + h * 80 + (16 + rit) * 2) = (_Float16)ai[r];
    }
  }
  __syncthreads();
#pragma unroll
  for (int i = 0; i < 2; ++i) {
    int idx = i * 256 + tid;
    int h = idx >> 2, q = idx & 3;
    u32x4 v = *(const u32x4*)(Ysh + h * 80 + q * 16);
    *(u32x4*)(Y1h + ((size_t)(bb * 128 + h) * 64 + o) * 32 + q * 8) = v;
  }
}

// ---------------- KAN weight prep: fp16 fragment-order -----------------
__global__ __launch_bounds__(256) void prep_bfrag_kernel(
    const float* __restrict__ base_w, const float* __restrict__ spline_w,
    const float* __restrict__ scaler, half8* __restrict__ out) {
  int idx = blockIdx.x * 256 + threadIdx.x;
  if (idx >= 4608) return;
  int lane = idx & 63;
  int ks = (idx >> 6) % 18;
  int nt = idx / (64 * 18);
  int n = nt * 16 + (lane & 15);
  int k0 = ks * 32 + (lane >> 4) * 8;
  half8 hv;
#pragma unroll
  for (int j = 0; j < 8; ++j) {
    int k = k0 + j;
    float val;
    if (k < 64) {
      val = base_w[n * 64 + k];
    } else {
      int c = (k - 64) >> 3, jj = (k - 64) & 7;
      val = spline_w[(n * 64 + c) * 8 + jj] * scaler[n * 64 + c];
    }
    hv[j] = (_Float16)val;
  }
  out[idx] = hv;
}

// ---------------- conv-W fragments + c2r trig table -----------------
__global__ __launch_bounds__(256) void prep_conv_kernel(
    const float* __restrict__ convw, half8* __restrict__ Wfrag,
    half8* __restrict__ Tfrag) {
  int idx = blockIdx.x * 256 + threadIdx.x;
  if (idx < 512) {
    int l = idx & 63, ks = (idx >> 6) & 1, nt = idx >> 7;
    int cout = nt * 16 + (l & 15);
    int cin0 = ks * 32 + (l >> 4) * 8;
    half8 hv;
#pragma unroll
    for (int j = 0; j < 8; ++j) hv[j] = (_Float16)convw[cout * 64 + cin0 + j];
    Wfrag[idx] = hv;
  } else if (idx < 1024) {
    int e = idx - 512;
    int w = e >> 2, g = e & 3;
    half8 hv;
#pragma unroll
    for (int j = 0; j < 8; ++j) {
      int k = g * 8 + j;
      float coeff;
      if (k < 16) {
        int t = (k * w) & 127;
        coeff = (k == 0) ? 1.f
                         : 2.f * cosf((float)((double)t * (6.283185307179586476925287 / 128.0)));
      } else {
        int kx = k - 16;
        int t = (kx * w) & 127;
        coeff = (kx == 0) ? 0.f
                          : -2.f * sinf((float)((double)t * (6.283185307179586476925287 / 128.0)));
      }
      hv[j] = (_Float16)(coeff * 0.0625f);
    }
    Tfrag[e] = hv;
  }
}

// ---------------- KAN feature math ----------------
__device__ __forceinline__ float fast_silu(float v) {
  return v * (1.f / (1.f + __expf(-v)));
}

__device__ __forceinline__ void spline_scatter(char* p16, float v) {
  const float Klo = __fsub_rn(__fmul_rn(-3.f, 0.4f), 1.0f);
  float u = (v - Klo) * 2.5f;
  float uc = fminf(fmaxf(u, 0.f), 10.5f);
  int i = (int)uc;
  float t = u - (float)i;
  float t2 = t * t, t3 = t2 * t;
  float omt = 1.f - t;
  float p0 = t3 * (1.f / 6.f);
  float p3 = omt * omt * (omt * (1.f / 6.f));
  float p1 = fmaf(t3, -0.5f, fmaf(t2, 0.5f, fmaf(t, 0.5f, 1.f / 6.f)));
  float p2 = fmaf(t3, 0.5f, fmaf(t2, -1.f, 2.f / 3.f));
  bool ok = (u >= 0.f) && (u < 11.f);
  unsigned a32 = ok ? pk2(p3, p2) : 0u;
  unsigned b32 = ok ? pk2(p1, p0) : 0u;
  u64 P = ((u64)b32 << 32) | a32;
  int sh = i << 4;
  u64 tA = P >> ((48 - sh) & 63);
  u64 tB = P << ((sh - 48) & 63);
  u64 tC = P >> ((112 - sh) & 63);
  u64 tD = P << ((sh - 112) & 63);
  u64 lo = (sh < 64) ? tA : ((sh < 112) ? tB : 0ull);
  u64 hi = (sh < 64) ? 0ull : ((sh < 128) ? tC : tD);
  u32x4 st = {(unsigned)lo, (unsigned)(lo >> 32), (unsigned)hi, (unsigned)(hi >> 32)};
  *(u32x4*)p16 = st;
}

__device__ __forceinline__ float gelu_exact(float v) {
  return 0.5f * v * (1.f + erff(v * 0.70710678118654752f));
}

__device__ __forceinline__ void w2feat(char* S, int g, int nt, int rit, f32x4 a) {
  const int c = nt * 16 + rit;
#pragma unroll
  for (int r = 0; r < 4; ++r) {
    char* row = S + (g * 4 + r) * ROWB;
    float v = a[r];
    *(_Float16*)(row + c * 2) = (_Float16)fast_silu(v);
    spline_scatter(row + 128 + c * 16, v);
  }
}

__device__ __forceinline__ void gemm_slot_ks(const char* S, const half8* Bq,
                                             int nt, int l, int rit, int g,
                                             f32x4& acc) {
  const half8* bq = Bq + (size_t)nt * 18 * 64 + l;
  const char* pa = S + rit * ROWB + g * 16;
#pragma unroll
  for (int kh = 0; kh < 2; ++kh) {
    half8 bfr[9];
#pragma unroll
    for (int ks = 0; ks < 9; ++ks) bfr[ks] = bq[(kh * 9 + ks) * 64];
#pragma unroll
    for (int ks = 0; ks < 9; ++ks) {
      half8 a = *(const half8*)(pa + (kh * 9 + ks) * 64);
      acc = __builtin_amdgcn_mfma_f32_16x16x32_f16(a, bfr[ks], acc, 0, 0, 0);
    }
  }
}

__device__ __forceinline__ void bounce_acc(float* bnc, int c, int px0, f32x4 a) {
  float* row = bnc + c * 65 + px0;
#pragma unroll
  for (int r = 0; r < 4; ++r) row[r] = gelu_exact(a[r]);
}

// ---------------- mega kernel: c2r + conv + bias + 2x KAN + GELU ------------
__global__ __launch_bounds__(256, 4) void kan_mega_kernel(
    const float* __restrict__ x, float* __restrict__ y,
    const _Float16* __restrict__ Y1h,
    const half8* __restrict__ Bq1, const half8* __restrict__ Bq2,
    const half8* __restrict__ Wfrag, const half8* __restrict__ Tfrag,
    const float* __restrict__ convb) {
  __shared__ __align__(16) char Abuf[2 * 16 * ROWB];
  char* A0 = Abuf;
  char* A1 = Abuf + 16 * ROWB;
  float* ybounce = (float*)A1;
  const int tid = threadIdx.x;
  const int l = tid & 63;
  const int nt = tid >> 6;
  const int rit = l & 15, g = l >> 4;
  const int n0 = blockIdx.x * 64;
  const int b = n0 >> 14;
  const int rem = n0 & 16383;
  const int hrow = rem >> 7, w0 = rem & 127;
  float* base = y + (size_t)b * 1048576 + (size_t)hrow * 128 + w0;
  const float* xbase = x + (size_t)b * 1048576 + (size_t)hrow * 128 + w0;

  half8 By = ((const half8*)Y1h)[((size_t)(b * 128 + hrow) * 64 + nt * 16 + rit) * 4 + g];
  half8 Wf0 = Wfrag[(nt * 2 + 0) * 64 + l];
  half8 Wf1 = Wfrag[(nt * 2 + 1) * 64 + l];
  half8 Tf0 = Tfrag[(w0 + 0 + rit) * 4 + g];
  half8 Tf1 = Tfrag[(w0 + 16 + rit) * 4 + g];
  half8 Tf2 = Tfrag[(w0 + 32 + rit) * 4 + g];
  half8 Tf3 = Tfrag[(w0 + 48 + rit) * 4 + g];
  const float cbv = convb[nt * 16 + rit];

  {
    const int c = tid >> 2, lq = tid & 3;
    const float* bx = xbase + (size_t)c * 16384;
#pragma unroll
    for (int s = 0; s < 4; ++s) {
      float4 v = *(const float4*)(bx + lq * 4 + s * 16);
      const float* vp = (const float*)&v;
#pragma unroll
      for (int j = 0; j < 4; ++j)
        *(_Float16*)(A0 + (lq * 4 + s * 16 + j) * ROWX + c * 2) = (_Float16)vp[j];
    }
  }
  __syncthreads();

  const f32x4 z = {0.f, 0.f, 0.f, 0.f};
  f32x4 a00 = z, a01 = z, a02 = z, a03 = z;
#define CONV_TILE(acc, mt, TF)                                                \
  {                                                                           \
    const char* pa = A0 + (mt * 16 + rit) * ROWX;                             \
    acc = __builtin_amdgcn_mfma_f32_16x16x32_f16(TF, By, z, 0, 0, 0);         \
    half8 xa0 = *(const half8*)(pa + g * 16);                                 \
    acc = __builtin_amdgcn_mfma_f32_16x16x32_f16(xa0, Wf0, acc, 0, 0, 0);     \
    half8 xa1 = *(const half8*)(pa + 64 + g * 16);                            \
    acc = __builtin_amdgcn_mfma_f32_16x16x32_f16(xa1, Wf1, acc, 0, 0, 0);     \
    acc[0] += cbv; acc[1] += cbv; acc[2] += cbv; acc[3] += cbv;               \
  }
  CONV_TILE(a00, 0, Tf0)
  CONV_TILE(a01, 1, Tf1)
  CONV_TILE(a02, 2, Tf2)
  CONV_TILE(a03, 3, Tf3)
#undef CONV_TILE
  w2feat(A1, g, nt, rit, a00);
  __syncthreads();

  f32x4 a10 = z, a11 = z, a12 = z, a13 = z;
  f32x4 a20 = z, a21 = z, a22 = z, a23 = z;
  gemm_slot_ks(A1, Bq1, nt, l, rit, g, a10); w2feat(A0, g, nt, rit, a01);
  __syncthreads();
  gemm_slot_ks(A0, Bq1, nt, l, rit, g, a11); w2feat(A1, g, nt, rit, a02);
  __syncthreads();
  gemm_slot_ks(A1, Bq1, nt, l, rit, g, a12); w2feat(A0, g, nt, rit, a03);
  __syncthreads();
  gemm_slot_ks(A0, Bq1, nt, l, rit, g, a13); w2feat(A1, g, nt, rit, a10);
  __syncthreads();
  gemm_slot_ks(A1, Bq2, nt, l, rit, g, a20); w2feat(A0, g, nt, rit, a11);
  __syncthreads();
  gemm_slot_ks(A0, Bq2, nt, l, rit, g, a21); w2feat(A1, g, nt, rit, a12);
  __syncthreads();
  gemm_slot_ks(A1, Bq2, nt, l, rit, g, a22); w2feat(A0, g, nt, rit, a13);
  __syncthreads();
  const int cch = nt * 16 + rit;
  gemm_slot_ks(A0, Bq2, nt, l, rit, g, a23);
  bounce_acc(ybounce, cch, 0 + g * 4, a20);
  bounce_acc(ybounce, cch, 16 + g * 4, a21);
  bounce_acc(ybounce, cch, 32 + g * 4, a22);
  bounce_acc(ybounce, cch, 48 + g * 4, a23);
  __syncthreads();
#pragma unroll
  for (int i = 0; i < 4; ++i) {
    int idx = i * 256 + tid;
    int c = idx >> 4, q = idx & 15;
    const float* r = ybounce + c * 65 + q * 4;
    float4 v;
    v.x = r[0]; v.y = r[1]; v.z = r[2]; v.w = r[3];
    *(float4*)(base + (size_t)c * 16384 + q * 4) = v;
  }
}

// ---------------------------------------------------------------------------
extern "C" void kernel_launch(void* const* d_in, const int* in_sizes, int n_in,
                              void* d_out, int out_size, void* d_ws, size_t ws_size,
                              hipStream_t stream) {
  const float* x    = (const float*)d_in[0];
  const float* w1r  = (const float*)d_in[1];
  const float* w1i  = (const float*)d_in[2];
  const float* w2r  = (const float*)d_in[3];
  const float* w2i  = (const float*)d_in[4];
  const float* cw   = (const float*)d_in[5];
  const float* cb   = (const float*)d_in[6];
  const float* k1b  = (const float*)d_in[7];
  const float* k1s  = (const float*)d_in[8];
  const float* k1sc = (const float*)d_in[9];
  const float* k2b  = (const float*)d_in[10];
  const float* k2s  = (const float*)d_in[11];
  const float* k2sc = (const float*)d_in[12];

  char* ws = (char*)d_ws;
  float*     XfRe  = (float*)(ws + 0);           // 2 MB
  float*     XfIm  = (float*)(ws + 2097152);     // 2 MB
  _Float16*  Y1h   = (_Float16*)(ws + 4194304);  // 8 MB
  half8*     Bf1   = (half8*)(ws + 12582912);    // 73728 B
  half8*     Bf2   = (half8*)(ws + 12656640);    // 73728 B
  half8*     Wfrag = (half8*)(ws + 12730368);    // 8192 B
  half8*     Tfrag = (half8*)(ws + 12738560);    // 8192 B
  half8*     T1f   = (half8*)(ws + 12746752);    // 8192 B
  half8*     A2c   = (half8*)(ws + 12754944);
  half8*     A2s   = (half8*)(ws + 12763136);
  half8*     A2sn  = (half8*)(ws + 12771328);
  half8*     A3c   = (half8*)(ws + 12779520);
  half8*     A3s   = (half8*)(ws + 12787712);
  half8*     A3sn  = (half8*)(ws + 12795904);
  float* y = (float*)d_out;

  prep_dft_tables_kernel<<<14, 256, 0, stream>>>(T1f, A2c, A2s, A2sn, A3c, A3s, A3sn);
  prep_bfrag_kernel<<<18, 256, 0, stream>>>(k1b, k1s, k1sc, Bf1);
  prep_bfrag_kernel<<<18, 256, 0, stream>>>(k2b, k2s, k2sc, Bf2);
  prep_conv_kernel<<<4, 256, 0, stream>>>(cw, Wfrag, Tfrag);
  fwd_dft_kernel<<<1024, 256, 0, stream>>>(x, XfRe, XfIm, T1f, A2c, A2s, A2sn);
  mode_mix_kernel<<<512, 256, 0, stream>>>(XfRe, XfIm, w1r, w1i, w2r, w2i);
  inv_h_kernel<<<1024, 256, 0, stream>>>(XfRe, XfIm, Y1h, A3c, A3s, A3sn);
  kan_mega_kernel<<<4096, 256, 0, stream>>>(x, y, Y1h, Bf1, Bf2, Wfrag, Tfrag, cb);
}

// Round 11
// 140.961 us; speedup vs baseline: 8.4052x; 1.2367x over previous
//
#include <hip/hip_runtime.h>

// ---------------------------------------------------------------------------
// KAN-FNO block, MI355X.
//   1. fwd_dft:   truncated separable rfft2 via MFMA (2 GEMM stages, fp16
//                 trig fragment tables) -> Xf fp32 [b,c][mode=32x16]
//   2. mode_mix:  per-mode 16x64x64 complex GEMM (in-place on Xf), XCD-swizzled
//   3. inv_h:     inverse DFT along h via MFMA -> Y1h fp16 [b][h][o][re|im]x2^-10
//   4. kan_mega:  c2r-along-w GEMM + 1x1-conv GEMM + bias (all MFMA) feeding
//                 BOTH KAN layers (MFMA f16) + exact GELU -> y. One kernel.
// R11: (a) kan_mega's gemm_slot reloaded B-fragments from global every phase:
//      2.7 GB of L2 reads per dispatch for 147 KB of weights (L2-BW bound,
//      invisible in FETCH_SIZE). Now ONE B[18] register array (72 VGPR),
//      loaded once per layer; __launch_bounds__(256,3) raises the VGPR cap
//      to ~168 so the compiler keeps it resident instead of rematerializing
//      (the 256,4=128 cap forced remat in R5-R10; VGPR_Count=64 proved it).
//      (b) libm erff -> A&S 7.1.26 fast erf (|eps|<=1.5e-7, ~17 VALU).
//      (c) 4 prep launches merged into 1.
// ---------------------------------------------------------------------------

typedef _Float16 half8 __attribute__((ext_vector_type(8)));
typedef float f32x4 __attribute__((ext_vector_type(4)));
typedef unsigned u32x2 __attribute__((ext_vector_type(2)));
typedef unsigned u32x4 __attribute__((ext_vector_type(4)));
typedef unsigned long long u64;

#define ROWB 1168  // KAN feature row: 576 fp16 = 1152 + 16 pad
#define ROWX 144   // conv A-tile row: 64 fp16 = 128 + 16 pad

__device__ __forceinline__ unsigned pk2(float a, float b) {
  auto h = __builtin_amdgcn_cvt_pkrtz(a, b);
  return __builtin_bit_cast(unsigned, h);
}

// ---------------- merged prep kernel ----------------
// idx ranges: [0,3584) DFT tables (7 x 512) | [3584,8192) Bf1 | [8192,12800)
// Bf2 | [12800,13824) convW+trig. Layout docs per table as in R10.
__device__ __forceinline__ void prep_dft_elem(int idx7, half8* T1f, half8* A2c,
                                              half8* A2s, half8* A2sn,
                                              half8* A3c, half8* A3s,
                                              half8* A3sn) {
  int tab = idx7 >> 9, e = idx7 & 511, l = e & 63, eg = e >> 6;
  int lg = l >> 4, li = l & 15;
  const double W0 = 6.283185307179586476925287 / 128.0;
  half8 hv;
#pragma unroll
  for (int j = 0; j < 8; ++j) {
    float val;
    if (tab == 0) {
      int ks = eg >> 1, nt = eg & 1;
      int w = ks * 32 + lg * 8 + j, kx = li;
      int t = (w * kx) & 127;
      float s, c;
      sincosf((float)((double)t * W0), &s, &c);
      val = nt ? -s : c;
    } else if (tab <= 3) {
      int mt = eg >> 2, ks = eg & 3;
      int mp = mt * 16 + li;
      int ky = mp < 16 ? mp : mp + 96;
      int h = ks * 32 + lg * 8 + j;
      int t = (ky * h) & 127;
      float s, c;
      sincosf((float)((double)t * W0), &s, &c);
      val = (tab == 1) ? c : (tab == 2) ? s : -s;
    } else {
      int h = eg * 16 + li;
      int m = lg * 8 + j;
      int ky = m < 16 ? m : m + 96;
      int t = (ky * h) & 127;
      float s, c;
      sincosf((float)((double)t * W0), &s, &c);
      val = (tab == 4) ? c : (tab == 5) ? s : -s;
    }
    hv[j] = (_Float16)val;
  }
  half8* dst = (tab == 0)   ? T1f
               : (tab == 1) ? A2c
               : (tab == 2) ? A2s
               : (tab == 3) ? A2sn
               : (tab == 4) ? A3c
               : (tab == 5) ? A3s
                            : A3sn;
  dst[e] = hv;
}

__device__ __forceinline__ void prep_bfrag_elem(int idx, const float* base_w,
                                                const float* spline_w,
                                                const float* scaler,
                                                half8* out) {
  int lane = idx & 63;
  int ks = (idx >> 6) % 18;
  int nt = idx / (64 * 18);
  int n = nt * 16 + (lane & 15);
  int k0 = ks * 32 + (lane >> 4) * 8;
  half8 hv;
#pragma unroll
  for (int j = 0; j < 8; ++j) {
    int k = k0 + j;
    float val;
    if (k < 64) {
      val = base_w[n * 64 + k];
    } else {
      int c = (k - 64) >> 3, jj = (k - 64) & 7;
      val = spline_w[(n * 64 + c) * 8 + jj] * scaler[n * 64 + c];
    }
    hv[j] = (_Float16)val;
  }
  out[idx] = hv;
}

__device__ __forceinline__ void prep_conv_elem(int idx, const float* convw,
                                               half8* Wfrag, half8* Tfrag) {
  if (idx < 512) {
    int l = idx & 63, ks = (idx >> 6) & 1, nt = idx >> 7;
    int cout = nt * 16 + (l & 15);
    int cin0 = ks * 32 + (l >> 4) * 8;
    half8 hv;
#pragma unroll
    for (int j = 0; j < 8; ++j) hv[j] = (_Float16)convw[cout * 64 + cin0 + j];
    Wfrag[idx] = hv;
  } else {
    int e = idx - 512;
    int w = e >> 2, g = e & 3;
    half8 hv;
#pragma unroll
    for (int j = 0; j < 8; ++j) {
      int k = g * 8 + j;
      float coeff;
      if (k < 16) {
        int t = (k * w) & 127;
        coeff = (k == 0) ? 1.f
                         : 2.f * cosf((float)((double)t * (6.283185307179586476925287 / 128.0)));
      } else {
        int kx = k - 16;
        int t = (kx * w) & 127;
        coeff = (kx == 0) ? 0.f
                          : -2.f * sinf((float)((double)t * (6.283185307179586476925287 / 128.0)));
      }
      hv[j] = (_Float16)(coeff * 0.0625f);
    }
    Tfrag[e] = hv;
  }
}

__global__ __launch_bounds__(256) void prep_all_kernel(
    const float* __restrict__ k1b, const float* __restrict__ k1s,
    const float* __restrict__ k1sc, const float* __restrict__ k2b,
    const float* __restrict__ k2s, const float* __restrict__ k2sc,
    const float* __restrict__ convw,
    half8* __restrict__ Bf1, half8* __restrict__ Bf2,
    half8* __restrict__ Wfrag, half8* __restrict__ Tfrag,
    half8* __restrict__ T1f, half8* __restrict__ A2c, half8* __restrict__ A2s,
    half8* __restrict__ A2sn, half8* __restrict__ A3c, half8* __restrict__ A3s,
    half8* __restrict__ A3sn) {
  int idx = blockIdx.x * 256 + threadIdx.x;
  if (idx < 3584) {
    prep_dft_elem(idx, T1f, A2c, A2s, A2sn, A3c, A3s, A3sn);
  } else if (idx < 8192) {
    prep_bfrag_elem(idx - 3584, k1b, k1s, k1sc, Bf1);
  } else if (idx < 12800) {
    prep_bfrag_elem(idx - 8192, k2b, k2s, k2sc, Bf2);
  } else if (idx < 13824) {
    prep_conv_elem(idx - 12800, convw, Wfrag, Tfrag);
  }
}

// ---------------- forward truncated rfft2, MFMA ----------------
__global__ __launch_bounds__(256) void fwd_dft_kernel(
    const float* __restrict__ x, float* __restrict__ XfRe, float* __restrict__ XfIm,
    const half8* __restrict__ T1f, const half8* __restrict__ A2c,
    const half8* __restrict__ A2s, const half8* __restrict__ A2sn) {
  __shared__ __align__(16) char sImg[128 * 272];  // fp16 [h][w], 272B rows
  __shared__ __align__(16) char sXw[32 * 272];    // fp16 [n][h] transposed
  const int tid = threadIdx.x;
  const int l = tid & 63, wv = tid >> 6;
  const int rit = l & 15, g = l >> 4;
  const int bc = blockIdx.x;
  const float4* src4 = (const float4*)(x + (size_t)bc * 16384);

  half8 t1f[8];
#pragma unroll
  for (int i = 0; i < 8; ++i) t1f[i] = T1f[i * 64 + l];
  const int mt2 = wv & 1, nt2 = wv >> 1;
  const half8* a2op = (nt2 == 0) ? A2s : A2sn;
  half8 a2c[4], a2o[4];
#pragma unroll
  for (int ks = 0; ks < 4; ++ks) {
    a2c[ks] = A2c[(mt2 * 4 + ks) * 64 + l];
    a2o[ks] = a2op[(mt2 * 4 + ks) * 64 + l];
  }

#pragma unroll
  for (int i = 0; i < 16; ++i) {
    int idx = i * 256 + tid;
    int r = idx >> 5, c4 = idx & 31;
    float4 v = src4[idx];
    u32x2 p = {pk2(v.x, v.y), pk2(v.z, v.w)};
    *(u32x2*)(sImg + r * 272 + c4 * 8) = p;
  }
  __syncthreads();

  const f32x4 z = {0.f, 0.f, 0.f, 0.f};
  f32x4 s1[2][2];
  s1[0][0] = z; s1[0][1] = z; s1[1][0] = z; s1[1][1] = z;
#pragma unroll
  for (int ks = 0; ks < 4; ++ks) {
#pragma unroll
    for (int mi = 0; mi < 2; ++mi) {
      const char* pa = sImg + ((wv * 2 + mi) * 16 + rit) * 272 + ks * 64 + g * 16;
      half8 a = *(const half8*)pa;
      s1[mi][0] = __builtin_amdgcn_mfma_f32_16x16x32_f16(a, t1f[ks * 2 + 0], s1[mi][0], 0, 0, 0);
      s1[mi][1] = __builtin_amdgcn_mfma_f32_16x16x32_f16(a, t1f[ks * 2 + 1], s1[mi][1], 0, 0, 0);
    }
  }
#pragma unroll
  for (int mi = 0; mi < 2; ++mi)
#pragma unroll
    for (int nt = 0; nt < 2; ++nt) {
      u32x2 p = {pk2(s1[mi][nt][0], s1[mi][nt][1]), pk2(s1[mi][nt][2], s1[mi][nt][3])};
      *(u32x2*)(sXw + (nt * 16 + rit) * 272 + ((wv * 2 + mi) * 16 + g * 4) * 2) = p;
    }
  __syncthreads();

  f32x4 acc2 = z;
#pragma unroll
  for (int ks = 0; ks < 4; ++ks) {
    half8 bre = *(const half8*)(sXw + rit * 272 + ks * 64 + g * 16);
    half8 bim = *(const half8*)(sXw + (16 + rit) * 272 + ks * 64 + g * 16);
    half8 b1 = (nt2 == 0) ? bre : bim;
    half8 b2 = (nt2 == 0) ? bim : bre;
    acc2 = __builtin_amdgcn_mfma_f32_16x16x32_f16(a2c[ks], b1, acc2, 0, 0, 0);
    acc2 = __builtin_amdgcn_mfma_f32_16x16x32_f16(a2o[ks], b2, acc2, 0, 0, 0);
  }
  float* outp = ((nt2 == 0) ? XfRe : XfIm) + (size_t)bc * 512 + (mt2 * 16 + g * 4) * 16 + rit;
#pragma unroll
  for (int r = 0; r < 4; ++r) outp[r * 16] = acc2[r];
}

// ---------------- per-mode complex channel mixing (in-place) ----------------
__global__ __launch_bounds__(256) void mode_mix_kernel(
    float* __restrict__ XfRe, float* __restrict__ XfIm,
    const float* __restrict__ w1r, const float* __restrict__ w1i,
    const float* __restrict__ w2r, const float* __restrict__ w2i) {
  __shared__ float Wr[4096];
  __shared__ float Wi[4096];
  __shared__ float Ar[1024];
  __shared__ float Ai[1024];
  const int tid = threadIdx.x;
  const int bid = blockIdx.x;
  const int mode = ((bid & 7) << 6) | (bid >> 3);  // XCD-chunked bijective
  const int m = mode >> 4, kx = mode & 15;
  const float* wr = (m < 16) ? w1r : w2r;
  const float* wi = (m < 16) ? w1i : w2i;
  const int woff = (m & 15) * 16 + kx;
  for (int e = tid; e < 4096; e += 256) {
    Wr[e] = wr[(size_t)e * 256 + woff];
    Wi[e] = wi[(size_t)e * 256 + woff];
  }
  for (int e = tid; e < 1024; e += 256) {
    Ar[e] = XfRe[(size_t)e * 512 + mode];
    Ai[e] = XfIm[(size_t)e * 512 + mode];
  }
  __syncthreads();
  const int o = tid & 63;
  const int b0 = tid >> 6;
  float outR[4], outI[4];
#pragma unroll
  for (int bb = 0; bb < 4; ++bb) {
    const int b = b0 * 4 + bb;
    float re = 0.f, im = 0.f;
    for (int i = 0; i < 64; ++i) {
      float ar = Ar[b * 64 + i], ai = Ai[b * 64 + i];
      float br = Wr[i * 64 + o], bi = Wi[i * 64 + o];
      re += ar * br - ai * bi;
      im += ar * bi + ai * br;
    }
    outR[bb] = re;
    outI[bb] = im;
  }
#pragma unroll
  for (int bb = 0; bb < 4; ++bb) {
    const int b = b0 * 4 + bb;
    size_t off = (size_t)(b * 64 + o) * 512 + mode;
    XfRe[off] = outR[bb];
    XfIm[off] = outI[bb];
  }
}

// ---------------- inverse DFT along h, MFMA ----------------
__global__ __launch_bounds__(256) void inv_h_kernel(
    const float* __restrict__ GfRe, const float* __restrict__ GfIm,
    _Float16* __restrict__ Y1h, const half8* __restrict__ A3c,
    const half8* __restrict__ A3s, const half8* __restrict__ A3sn) {
  __shared__ __align__(16) char Ysh[128 * 80];  // fp16 [h][32], 80B rows
  const int tid = threadIdx.x;
  const int l = tid & 63, wv = tid >> 6;
  const int rit = l & 15, g = l >> 4;
  const int bo = blockIdx.x;
  const int bb = bo >> 6, o = bo & 63;
  float gr[8], gi[8];
#pragma unroll
  for (int j = 0; j < 8; ++j) {
    size_t off = (size_t)bo * 512 + (size_t)(g * 8 + j) * 16 + rit;
    gr[j] = GfRe[off];
    gi[j] = GfIm[off];
  }
  u32x4 ur, ui;
#pragma unroll
  for (int p = 0; p < 4; ++p) {
    ur[p] = pk2(gr[2 * p] * 9.765625e-4f, gr[2 * p + 1] * 9.765625e-4f);
    ui[p] = pk2(gi[2 * p] * 9.765625e-4f, gi[2 * p + 1] * 9.765625e-4f);
  }
  half8 grF = __builtin_bit_cast(half8, ur);
  half8 giF = __builtin_bit_cast(half8, ui);
  half8 a3c[2], a3s[2], a3sn[2];
#pragma unroll
  for (int mi = 0; mi < 2; ++mi) {
    a3c[mi] = A3c[(wv * 2 + mi) * 64 + l];
    a3s[mi] = A3s[(wv * 2 + mi) * 64 + l];
    a3sn[mi] = A3sn[(wv * 2 + mi) * 64 + l];
  }
  const f32x4 z = {0.f, 0.f, 0.f, 0.f};
#pragma unroll
  for (int mi = 0; mi < 2; ++mi) {
    f32x4 ar = z, ai = z;
    ar = __builtin_amdgcn_mfma_f32_16x16x32_f16(a3c[mi], grF, ar, 0, 0, 0);
    ar = __builtin_amdgcn_mfma_f32_16x16x32_f16(a3sn[mi], giF, ar, 0, 0, 0);
    ai = __builtin_amdgcn_mfma_f32_16x16x32_f16(a3s[mi], grF, ai, 0, 0, 0);
    ai = __builtin_amdgcn_mfma_f32_16x16x32_f16(a3c[mi], giF, ai, 0, 0, 0);
#pragma unroll
    for (int r = 0; r < 4; ++r) {
      int h = (wv * 2 + mi) * 16 + g * 4 + r;
      *(_Float16*)(Ysh + h * 80 + rit * 2) = (_Float16)ar[r];
      *(_Float16*)(Ysh + h * 80 + (16 + rit) * 2) = (_Float16)ai[r];
    }
  }
  __syncthreads();
#pragma unroll
  for (int i = 0; i < 2; ++i) {
    int idx = i * 256 + tid;
    int h = idx >> 2, q = idx & 3;
    u32x4 v = *(const u32x4*)(Ysh + h * 80 + q * 16);
    *(u32x4*)(Y1h + ((size_t)(bb * 128 + h) * 64 + o) * 32 + q * 8) = v;
  }
}

// ---------------- KAN feature math ----------------
__device__ __forceinline__ float fast_silu(float v) {
  return v * (1.f / (1.f + __expf(-v)));
}

__device__ __forceinline__ void spline_scatter(char* p16, float v) {
  const float Klo = __fsub_rn(__fmul_rn(-3.f, 0.4f), 1.0f);
  float u = (v - Klo) * 2.5f;
  float uc = fminf(fmaxf(u, 0.f), 10.5f);
  int i = (int)uc;
  float t = u - (float)i;
  float t2 = t * t, t3 = t2 * t;
  float omt = 1.f - t;
  float p0 = t3 * (1.f / 6.f);
  float p3 = omt * omt * (omt * (1.f / 6.f));
  float p1 = fmaf(t3, -0.5f, fmaf(t2, 0.5f, fmaf(t, 0.5f, 1.f / 6.f)));
  float p2 = fmaf(t3, 0.5f, fmaf(t2, -1.f, 2.f / 3.f));
  bool ok = (u >= 0.f) && (u < 11.f);
  unsigned a32 = ok ? pk2(p3, p2) : 0u;
  unsigned b32 = ok ? pk2(p1, p0) : 0u;
  u64 P = ((u64)b32 << 32) | a32;
  int sh = i << 4;
  u64 tA = P >> ((48 - sh) & 63);
  u64 tB = P << ((sh - 48) & 63);
  u64 tC = P >> ((112 - sh) & 63);
  u64 tD = P << ((sh - 112) & 63);
  u64 lo = (sh < 64) ? tA : ((sh < 112) ? tB : 0ull);
  u64 hi = (sh < 64) ? 0ull : ((sh < 128) ? tC : tD);
  u32x4 st = {(unsigned)lo, (unsigned)(lo >> 32), (unsigned)hi, (unsigned)(hi >> 32)};
  *(u32x4*)p16 = st;
}

// Exact-GELU via A&S 7.1.26 erf (|eps| <= 1.5e-7): ~17 VALU, no libm branches.
__device__ __forceinline__ float gelu_exact(float v) {
  float x = fabsf(v) * 0.70710678118654752f;
  float t = __builtin_amdgcn_rcpf(fmaf(0.3275911f, x, 1.0f));
  float p = fmaf(fmaf(fmaf(fmaf(1.061405429f, t, -1.453152027f), t,
                           1.421413741f), t, -0.284496736f), t, 0.254829592f) * t;
  float e = __expf(-x * x);
  float erfa = fmaf(-p, e, 1.0f);  // erf(|x|)
  return 0.5f * v * (1.0f + copysignf(erfa, v));
}

__device__ __forceinline__ void w2feat(char* S, int g, int nt, int rit, f32x4 a) {
  const int c = nt * 16 + rit;
#pragma unroll
  for (int r = 0; r < 4; ++r) {
    char* row = S + (g * 4 + r) * ROWB;
    float v = a[r];
    *(_Float16*)(row + c * 2) = (_Float16)fast_silu(v);
    spline_scatter(row + 128 + c * 16, v);
  }
}

// Load one layer's 18 B-fragments into registers (72 VGPR, kept resident).
__device__ __forceinline__ void load_bfrags(half8* B, const half8* Bq, int nt,
                                            int l) {
  const half8* bq = Bq + (size_t)nt * 18 * 64 + l;
#pragma unroll
  for (int ks = 0; ks < 18; ++ks) B[ks] = bq[ks * 64];
}

// One 16x16x576 GEMM slice with register-resident B: 18 ds_read + 18 MFMA.
__device__ __forceinline__ void gemm_slot_res(const char* S, const half8* B,
                                              int rit, int g, f32x4& acc) {
  const char* pa = S + rit * ROWB + g * 16;
#pragma unroll
  for (int ks = 0; ks < 18; ++ks) {
    half8 a = *(const half8*)(pa + ks * 64);
    acc = __builtin_amdgcn_mfma_f32_16x16x32_f16(a, B[ks], acc, 0, 0, 0);
  }
}

__device__ __forceinline__ void bounce_acc(float* bnc, int c, int px0, f32x4 a) {
  float* row = bnc + c * 65 + px0;
#pragma unroll
  for (int r = 0; r < 4; ++r) row[r] = gelu_exact(a[r]);
}

// ---------------- mega kernel: c2r + conv + bias + 2x KAN + GELU ------------
__global__ __launch_bounds__(256, 3) void kan_mega_kernel(
    const float* __restrict__ x, float* __restrict__ y,
    const _Float16* __restrict__ Y1h,
    const half8* __restrict__ Bq1, const half8* __restrict__ Bq2,
    const half8* __restrict__ Wfrag, const half8* __restrict__ Tfrag,
    const float* __restrict__ convb) {
  __shared__ __align__(16) char Abuf[2 * 16 * ROWB];
  char* A0 = Abuf;
  char* A1 = Abuf + 16 * ROWB;
  float* ybounce = (float*)A1;
  const int tid = threadIdx.x;
  const int l = tid & 63;
  const int nt = tid >> 6;
  const int rit = l & 15, g = l >> 4;
  const int n0 = blockIdx.x * 64;
  const int b = n0 >> 14;
  const int rem = n0 & 16383;
  const int hrow = rem >> 7, w0 = rem & 127;
  float* base = y + (size_t)b * 1048576 + (size_t)hrow * 128 + w0;
  const float* xbase = x + (size_t)b * 1048576 + (size_t)hrow * 128 + w0;

  half8 By = ((const half8*)Y1h)[((size_t)(b * 128 + hrow) * 64 + nt * 16 + rit) * 4 + g];
  half8 Wf0 = Wfrag[(nt * 2 + 0) * 64 + l];
  half8 Wf1 = Wfrag[(nt * 2 + 1) * 64 + l];
  half8 Tf0 = Tfrag[(w0 + 0 + rit) * 4 + g];
  half8 Tf1 = Tfrag[(w0 + 16 + rit) * 4 + g];
  half8 Tf2 = Tfrag[(w0 + 32 + rit) * 4 + g];
  half8 Tf3 = Tfrag[(w0 + 48 + rit) * 4 + g];
  const float cbv = convb[nt * 16 + rit];

  // layer-1 B fragments: loaded once, resident through P1..P4
  half8 B[18];
  load_bfrags(B, Bq1, nt, l);

  {
    const int c = tid >> 2, lq = tid & 3;
    const float* bx = xbase + (size_t)c * 16384;
#pragma unroll
    for (int s = 0; s < 4; ++s) {
      float4 v = *(const float4*)(bx + lq * 4 + s * 16);
      const float* vp = (const float*)&v;
#pragma unroll
      for (int j = 0; j < 4; ++j)
        *(_Float16*)(A0 + (lq * 4 + s * 16 + j) * ROWX + c * 2) = (_Float16)vp[j];
    }
  }
  __syncthreads();

  const f32x4 z = {0.f, 0.f, 0.f, 0.f};
  f32x4 a00 = z, a01 = z, a02 = z, a03 = z;
#define CONV_TILE(acc, mt, TF)                                                \
  {                                                                           \
    const char* pa = A0 + (mt * 16 + rit) * ROWX;                             \
    acc = __builtin_amdgcn_mfma_f32_16x16x32_f16(TF, By, z, 0, 0, 0);         \
    half8 xa0 = *(const half8*)(pa + g * 16);                                 \
    acc = __builtin_amdgcn_mfma_f32_16x16x32_f16(xa0, Wf0, acc, 0, 0, 0);     \
    half8 xa1 = *(const half8*)(pa + 64 + g * 16);                            \
    acc = __builtin_amdgcn_mfma_f32_16x16x32_f16(xa1, Wf1, acc, 0, 0, 0);     \
    acc[0] += cbv; acc[1] += cbv; acc[2] += cbv; acc[3] += cbv;               \
  }
  CONV_TILE(a00, 0, Tf0)
  CONV_TILE(a01, 1, Tf1)
  CONV_TILE(a02, 2, Tf2)
  CONV_TILE(a03, 3, Tf3)
#undef CONV_TILE
  w2feat(A1, g, nt, rit, a00);
  __syncthreads();

  f32x4 a10 = z, a11 = z, a12 = z, a13 = z;
  f32x4 a20 = z, a21 = z, a22 = z, a23 = z;
  // P1..P3: layer-1 GEMM(p) || features(p+1)
  gemm_slot_res(A1, B, rit, g, a10); w2feat(A0, g, nt, rit, a01);
  __syncthreads();
  gemm_slot_res(A0, B, rit, g, a11); w2feat(A1, g, nt, rit, a02);
  __syncthreads();
  gemm_slot_res(A1, B, rit, g, a12); w2feat(A0, g, nt, rit, a03);
  __syncthreads();
  // P4: last layer-1 GEMM; then reload B with layer-2 fragments (latency
  // hides under w2feat + barrier; same registers -> no extra VGPR pressure)
  gemm_slot_res(A0, B, rit, g, a13);
  load_bfrags(B, Bq2, nt, l);
  w2feat(A1, g, nt, rit, a10);
  __syncthreads();
  // P5..P7: layer-2 GEMM(p) || layer-2 features(p+1)
  gemm_slot_res(A1, B, rit, g, a20); w2feat(A0, g, nt, rit, a11);
  __syncthreads();
  gemm_slot_res(A0, B, rit, g, a21); w2feat(A1, g, nt, rit, a12);
  __syncthreads();
  gemm_slot_res(A1, B, rit, g, a22); w2feat(A0, g, nt, rit, a13);
  __syncthreads();
  // P8: last GEMM (reads A0) || GELU-bounce into A1 region
  const int cch = nt * 16 + rit;
  gemm_slot_res(A0, B, rit, g, a23);
  bounce_acc(ybounce, cch, 0 + g * 4, a20);
  bounce_acc(ybounce, cch, 16 + g * 4, a21);
  bounce_acc(ybounce, cch, 32 + g * 4, a22);
  bounce_acc(ybounce, cch, 48 + g * 4, a23);
  __syncthreads();
#pragma unroll
  for (int i = 0; i < 4; ++i) {
    int idx = i * 256 + tid;
    int c = idx >> 4, q = idx & 15;
    const float* r = ybounce + c * 65 + q * 4;
    float4 v;
    v.x = r[0]; v.y = r[1]; v.z = r[2]; v.w = r[3];
    *(float4*)(base + (size_t)c * 16384 + q * 4) = v;
  }
}

// ---------------------------------------------------------------------------
extern "C" void kernel_launch(void* const* d_in, const int* in_sizes, int n_in,
                              void* d_out, int out_size, void* d_ws, size_t ws_size,
                              hipStream_t stream) {
  const float* x    = (const float*)d_in[0];
  const float* w1r  = (const float*)d_in[1];
  const float* w1i  = (const float*)d_in[2];
  const float* w2r  = (const float*)d_in[3];
  const float* w2i  = (const float*)d_in[4];
  const float* cw   = (const float*)d_in[5];
  const float* cb   = (const float*)d_in[6];
  const float* k1b  = (const float*)d_in[7];
  const float* k1s  = (const float*)d_in[8];
  const float* k1sc = (const float*)d_in[9];
  const float* k2b  = (const float*)d_in[10];
  const float* k2s  = (const float*)d_in[11];
  const float* k2sc = (const float*)d_in[12];

  char* ws = (char*)d_ws;
  float*     XfRe  = (float*)(ws + 0);           // 2 MB
  float*     XfIm  = (float*)(ws + 2097152);     // 2 MB
  _Float16*  Y1h   = (_Float16*)(ws + 4194304);  // 8 MB
  half8*     Bf1   = (half8*)(ws + 12582912);    // 73728 B
  half8*     Bf2   = (half8*)(ws + 12656640);    // 73728 B
  half8*     Wfrag = (half8*)(ws + 12730368);    // 8192 B
  half8*     Tfrag = (half8*)(ws + 12738560);    // 8192 B
  half8*     T1f   = (half8*)(ws + 12746752);    // 8192 B
  half8*     A2c   = (half8*)(ws + 12754944);
  half8*     A2s   = (half8*)(ws + 12763136);
  half8*     A2sn  = (half8*)(ws + 12771328);
  half8*     A3c   = (half8*)(ws + 12779520);
  half8*     A3s   = (half8*)(ws + 12787712);
  half8*     A3sn  = (half8*)(ws + 12795904);
  float* y = (float*)d_out;

  prep_all_kernel<<<54, 256, 0, stream>>>(k1b, k1s, k1sc, k2b, k2s, k2sc, cw,
                                          Bf1, Bf2, Wfrag, Tfrag, T1f, A2c,
                                          A2s, A2sn, A3c, A3s, A3sn);
  fwd_dft_kernel<<<1024, 256, 0, stream>>>(x, XfRe, XfIm, T1f, A2c, A2s, A2sn);
  mode_mix_kernel<<<512, 256, 0, stream>>>(XfRe, XfIm, w1r, w1i, w2r, w2i);
  inv_h_kernel<<<1024, 256, 0, stream>>>(XfRe, XfIm, Y1h, A3c, A3s, A3sn);
  kan_mega_kernel<<<4096, 256, 0, stream>>>(x, y, Y1h, Bf1, Bf2, Wfrag, Tfrag, cb);
}

// Round 12
// 140.922 us; speedup vs baseline: 8.4075x; 1.0003x over previous
//
#include <hip/hip_runtime.h>

// ---------------------------------------------------------------------------
// KAN-FNO block, MI355X.
//   1. fwd_dft:   truncated separable rfft2 via MFMA (2 GEMM stages, fp16
//                 trig fragment tables) -> Xf fp32 [b,c][mode=32x16]
//   2. mode_mix:  per-mode 16x64x64 complex GEMM (in-place on Xf), XCD-swizzled
//   3. inv_h:     inverse DFT along h via MFMA -> Y1h fp16 [b][h][o][re|im]x2^-10
//   4. kan_mega:  c2r-along-w GEMM + 1x1-conv GEMM + bias (all MFMA) feeding
//                 BOTH KAN layers (MFMA f16) + exact GELU -> y. One kernel.
// R12: kan_mega is VALU-issue bound (74% VALUBusy + 20% MfmaUtil = 94% issue).
//     (a) spline poly now packed fp16: p2(t)=p1(1-t), p3(t)=p0(1-t), so pack
//         {t,1-t} once and 6 v_pk ops produce all 4 bases; payload words
//         assembled with 2 v_perm_b32. Replaces ~13 f32 ops + 2 pkrtz.
//     (b) Xh staging px-major: 2 ds_write_b128 + 8 pkrtz per thread instead
//         of 16 scalar ds_write_b16 + 16 cvt.
// ---------------------------------------------------------------------------

typedef _Float16 half8 __attribute__((ext_vector_type(8)));
typedef _Float16 half2 __attribute__((ext_vector_type(2)));
typedef float f32x4 __attribute__((ext_vector_type(4)));
typedef unsigned u32x2 __attribute__((ext_vector_type(2)));
typedef unsigned u32x4 __attribute__((ext_vector_type(4)));
typedef unsigned long long u64;

#define ROWB 1168  // KAN feature row: 576 fp16 = 1152 + 16 pad
#define ROWX 144   // conv A-tile row: 64 fp16 = 128 + 16 pad

__device__ __forceinline__ unsigned pk2(float a, float b) {
  auto h = __builtin_amdgcn_cvt_pkrtz(a, b);
  return __builtin_bit_cast(unsigned, h);
}
__device__ __forceinline__ half2 h2splat(float f) {
  _Float16 h = (_Float16)f;
  half2 r = {h, h};
  return r;
}

// ---------------- merged prep kernel ----------------
__device__ __forceinline__ void prep_dft_elem(int idx7, half8* T1f, half8* A2c,
                                              half8* A2s, half8* A2sn,
                                              half8* A3c, half8* A3s,
                                              half8* A3sn) {
  int tab = idx7 >> 9, e = idx7 & 511, l = e & 63, eg = e >> 6;
  int lg = l >> 4, li = l & 15;
  const double W0 = 6.283185307179586476925287 / 128.0;
  half8 hv;
#pragma unroll
  for (int j = 0; j < 8; ++j) {
    float val;
    if (tab == 0) {
      int ks = eg >> 1, nt = eg & 1;
      int w = ks * 32 + lg * 8 + j, kx = li;
      int t = (w * kx) & 127;
      float s, c;
      sincosf((float)((double)t * W0), &s, &c);
      val = nt ? -s : c;
    } else if (tab <= 3) {
      int mt = eg >> 2, ks = eg & 3;
      int mp = mt * 16 + li;
      int ky = mp < 16 ? mp : mp + 96;
      int h = ks * 32 + lg * 8 + j;
      int t = (ky * h) & 127;
      float s, c;
      sincosf((float)((double)t * W0), &s, &c);
      val = (tab == 1) ? c : (tab == 2) ? s : -s;
    } else {
      int h = eg * 16 + li;
      int m = lg * 8 + j;
      int ky = m < 16 ? m : m + 96;
      int t = (ky * h) & 127;
      float s, c;
      sincosf((float)((double)t * W0), &s, &c);
      val = (tab == 4) ? c : (tab == 5) ? s : -s;
    }
    hv[j] = (_Float16)val;
  }
  half8* dst = (tab == 0)   ? T1f
               : (tab == 1) ? A2c
               : (tab == 2) ? A2s
               : (tab == 3) ? A2sn
               : (tab == 4) ? A3c
               : (tab == 5) ? A3s
                            : A3sn;
  dst[e] = hv;
}

__device__ __forceinline__ void prep_bfrag_elem(int idx, const float* base_w,
                                                const float* spline_w,
                                                const float* scaler,
                                                half8* out) {
  int lane = idx & 63;
  int ks = (idx >> 6) % 18;
  int nt = idx / (64 * 18);
  int n = nt * 16 + (lane & 15);
  int k0 = ks * 32 + (lane >> 4) * 8;
  half8 hv;
#pragma unroll
  for (int j = 0; j < 8; ++j) {
    int k = k0 + j;
    float val;
    if (k < 64) {
      val = base_w[n * 64 + k];
    } else {
      int c = (k - 64) >> 3, jj = (k - 64) & 7;
      val = spline_w[(n * 64 + c) * 8 + jj] * scaler[n * 64 + c];
    }
    hv[j] = (_Float16)val;
  }
  out[idx] = hv;
}

__device__ __forceinline__ void prep_conv_elem(int idx, const float* convw,
                                               half8* Wfrag, half8* Tfrag) {
  if (idx < 512) {
    int l = idx & 63, ks = (idx >> 6) & 1, nt = idx >> 7;
    int cout = nt * 16 + (l & 15);
    int cin0 = ks * 32 + (l >> 4) * 8;
    half8 hv;
#pragma unroll
    for (int j = 0; j < 8; ++j) hv[j] = (_Float16)convw[cout * 64 + cin0 + j];
    Wfrag[idx] = hv;
  } else {
    int e = idx - 512;
    int w = e >> 2, g = e & 3;
    half8 hv;
#pragma unroll
    for (int j = 0; j < 8; ++j) {
      int k = g * 8 + j;
      float coeff;
      if (k < 16) {
        int t = (k * w) & 127;
        coeff = (k == 0) ? 1.f
                         : 2.f * cosf((float)((double)t * (6.283185307179586476925287 / 128.0)));
      } else {
        int kx = k - 16;
        int t = (kx * w) & 127;
        coeff = (kx == 0) ? 0.f
                          : -2.f * sinf((float)((double)t * (6.283185307179586476925287 / 128.0)));
      }
      hv[j] = (_Float16)(coeff * 0.0625f);
    }
    Tfrag[e] = hv;
  }
}

__global__ __launch_bounds__(256) void prep_all_kernel(
    const float* __restrict__ k1b, const float* __restrict__ k1s,
    const float* __restrict__ k1sc, const float* __restrict__ k2b,
    const float* __restrict__ k2s, const float* __restrict__ k2sc,
    const float* __restrict__ convw,
    half8* __restrict__ Bf1, half8* __restrict__ Bf2,
    half8* __restrict__ Wfrag, half8* __restrict__ Tfrag,
    half8* __restrict__ T1f, half8* __restrict__ A2c, half8* __restrict__ A2s,
    half8* __restrict__ A2sn, half8* __restrict__ A3c, half8* __restrict__ A3s,
    half8* __restrict__ A3sn) {
  int idx = blockIdx.x * 256 + threadIdx.x;
  if (idx < 3584) {
    prep_dft_elem(idx, T1f, A2c, A2s, A2sn, A3c, A3s, A3sn);
  } else if (idx < 8192) {
    prep_bfrag_elem(idx - 3584, k1b, k1s, k1sc, Bf1);
  } else if (idx < 12800) {
    prep_bfrag_elem(idx - 8192, k2b, k2s, k2sc, Bf2);
  } else if (idx < 13824) {
    prep_conv_elem(idx - 12800, convw, Wfrag, Tfrag);
  }
}

// ---------------- forward truncated rfft2, MFMA ----------------
__global__ __launch_bounds__(256) void fwd_dft_kernel(
    const float* __restrict__ x, float* __restrict__ XfRe, float* __restrict__ XfIm,
    const half8* __restrict__ T1f, const half8* __restrict__ A2c,
    const half8* __restrict__ A2s, const half8* __restrict__ A2sn) {
  __shared__ __align__(16) char sImg[128 * 272];  // fp16 [h][w], 272B rows
  __shared__ __align__(16) char sXw[32 * 272];    // fp16 [n][h] transposed
  const int tid = threadIdx.x;
  const int l = tid & 63, wv = tid >> 6;
  const int rit = l & 15, g = l >> 4;
  const int bc = blockIdx.x;
  const float4* src4 = (const float4*)(x + (size_t)bc * 16384);

  half8 t1f[8];
#pragma unroll
  for (int i = 0; i < 8; ++i) t1f[i] = T1f[i * 64 + l];
  const int mt2 = wv & 1, nt2 = wv >> 1;
  const half8* a2op = (nt2 == 0) ? A2s : A2sn;
  half8 a2c[4], a2o[4];
#pragma unroll
  for (int ks = 0; ks < 4; ++ks) {
    a2c[ks] = A2c[(mt2 * 4 + ks) * 64 + l];
    a2o[ks] = a2op[(mt2 * 4 + ks) * 64 + l];
  }

#pragma unroll
  for (int i = 0; i < 16; ++i) {
    int idx = i * 256 + tid;
    int r = idx >> 5, c4 = idx & 31;
    float4 v = src4[idx];
    u32x2 p = {pk2(v.x, v.y), pk2(v.z, v.w)};
    *(u32x2*)(sImg + r * 272 + c4 * 8) = p;
  }
  __syncthreads();

  const f32x4 z = {0.f, 0.f, 0.f, 0.f};
  f32x4 s1[2][2];
  s1[0][0] = z; s1[0][1] = z; s1[1][0] = z; s1[1][1] = z;
#pragma unroll
  for (int ks = 0; ks < 4; ++ks) {
#pragma unroll
    for (int mi = 0; mi < 2; ++mi) {
      const char* pa = sImg + ((wv * 2 + mi) * 16 + rit) * 272 + ks * 64 + g * 16;
      half8 a = *(const half8*)pa;
      s1[mi][0] = __builtin_amdgcn_mfma_f32_16x16x32_f16(a, t1f[ks * 2 + 0], s1[mi][0], 0, 0, 0);
      s1[mi][1] = __builtin_amdgcn_mfma_f32_16x16x32_f16(a, t1f[ks * 2 + 1], s1[mi][1], 0, 0, 0);
    }
  }
#pragma unroll
  for (int mi = 0; mi < 2; ++mi)
#pragma unroll
    for (int nt = 0; nt < 2; ++nt) {
      u32x2 p = {pk2(s1[mi][nt][0], s1[mi][nt][1]), pk2(s1[mi][nt][2], s1[mi][nt][3])};
      *(u32x2*)(sXw + (nt * 16 + rit) * 272 + ((wv * 2 + mi) * 16 + g * 4) * 2) = p;
    }
  __syncthreads();

  f32x4 acc2 = z;
#pragma unroll
  for (int ks = 0; ks < 4; ++ks) {
    half8 bre = *(const half8*)(sXw + rit * 272 + ks * 64 + g * 16);
    half8 bim = *(const half8*)(sXw + (16 + rit) * 272 + ks * 64 + g * 16);
    half8 b1 = (nt2 == 0) ? bre : bim;
    half8 b2 = (nt2 == 0) ? bim : bre;
    acc2 = __builtin_amdgcn_mfma_f32_16x16x32_f16(a2c[ks], b1, acc2, 0, 0, 0);
    acc2 = __builtin_amdgcn_mfma_f32_16x16x32_f16(a2o[ks], b2, acc2, 0, 0, 0);
  }
  float* outp = ((nt2 == 0) ? XfRe : XfIm) + (size_t)bc * 512 + (mt2 * 16 + g * 4) * 16 + rit;
#pragma unroll
  for (int r = 0; r < 4; ++r) outp[r * 16] = acc2[r];
}

// ---------------- per-mode complex channel mixing (in-place) ----------------
__global__ __launch_bounds__(256) void mode_mix_kernel(
    float* __restrict__ XfRe, float* __restrict__ XfIm,
    const float* __restrict__ w1r, const float* __restrict__ w1i,
    const float* __restrict__ w2r, const float* __restrict__ w2i) {
  __shared__ float Wr[4096];
  __shared__ float Wi[4096];
  __shared__ float Ar[1024];
  __shared__ float Ai[1024];
  const int tid = threadIdx.x;
  const int bid = blockIdx.x;
  const int mode = ((bid & 7) << 6) | (bid >> 3);  // XCD-chunked bijective
  const int m = mode >> 4, kx = mode & 15;
  const float* wr = (m < 16) ? w1r : w2r;
  const float* wi = (m < 16) ? w1i : w2i;
  const int woff = (m & 15) * 16 + kx;
  for (int e = tid; e < 4096; e += 256) {
    Wr[e] = wr[(size_t)e * 256 + woff];
    Wi[e] = wi[(size_t)e * 256 + woff];
  }
  for (int e = tid; e < 1024; e += 256) {
    Ar[e] = XfRe[(size_t)e * 512 + mode];
    Ai[e] = XfIm[(size_t)e * 512 + mode];
  }
  __syncthreads();
  const int o = tid & 63;
  const int b0 = tid >> 6;
  float outR[4], outI[4];
#pragma unroll
  for (int bb = 0; bb < 4; ++bb) {
    const int b = b0 * 4 + bb;
    float re = 0.f, im = 0.f;
    for (int i = 0; i < 64; ++i) {
      float ar = Ar[b * 64 + i], ai = Ai[b * 64 + i];
      float br = Wr[i * 64 + o], bi = Wi[i * 64 + o];
      re += ar * br - ai * bi;
      im += ar * bi + ai * br;
    }
    outR[bb] = re;
    outI[bb] = im;
  }
#pragma unroll
  for (int bb = 0; bb < 4; ++bb) {
    const int b = b0 * 4 + bb;
    size_t off = (size_t)(b * 64 + o) * 512 + mode;
    XfRe[off] = outR[bb];
    XfIm[off] = outI[bb];
  }
}

// ---------------- inverse DFT along h, MFMA ----------------
__global__ __launch_bounds__(256) void inv_h_kernel(
    const float* __restrict__ GfRe, const float* __restrict__ GfIm,
    _Float16* __restrict__ Y1h, const half8* __restrict__ A3c,
    const half8* __restrict__ A3s, const half8* __restrict__ A3sn) {
  __shared__ __align__(16) char Ysh[128 * 80];  // fp16 [h][32], 80B rows
  const int tid = threadIdx.x;
  const int l = tid & 63, wv = tid >> 6;
  const int rit = l & 15, g = l >> 4;
  const int bo = blockIdx.x;
  const int bb = bo >> 6, o = bo & 63;
  float gr[8], gi[8];
#pragma unroll
  for (int j = 0; j < 8; ++j) {
    size_t off = (size_t)bo * 512 + (size_t)(g * 8 + j) * 16 + rit;
    gr[j] = GfRe[off];
    gi[j] = GfIm[off];
  }
  u32x4 ur, ui;
#pragma unroll
  for (int p = 0; p < 4; ++p) {
    ur[p] = pk2(gr[2 * p] * 9.765625e-4f, gr[2 * p + 1] * 9.765625e-4f);
    ui[p] = pk2(gi[2 * p] * 9.765625e-4f, gi[2 * p + 1] * 9.765625e-4f);
  }
  half8 grF = __builtin_bit_cast(half8, ur);
  half8 giF = __builtin_bit_cast(half8, ui);
  half8 a3c[2], a3s[2], a3sn[2];
#pragma unroll
  for (int mi = 0; mi < 2; ++mi) {
    a3c[mi] = A3c[(wv * 2 + mi) * 64 + l];
    a3s[mi] = A3s[(wv * 2 + mi) * 64 + l];
    a3sn[mi] = A3sn[(wv * 2 + mi) * 64 + l];
  }
  const f32x4 z = {0.f, 0.f, 0.f, 0.f};
#pragma unroll
  for (int mi = 0; mi < 2; ++mi) {
    f32x4 ar = z, ai = z;
    ar = __builtin_amdgcn_mfma_f32_16x16x32_f16(a3c[mi], grF, ar, 0, 0, 0);
    ar = __builtin_amdgcn_mfma_f32_16x16x32_f16(a3sn[mi], giF, ar, 0, 0, 0);
    ai = __builtin_amdgcn_mfma_f32_16x16x32_f16(a3s[mi], grF, ai, 0, 0, 0);
    ai = __builtin_amdgcn_mfma_f32_16x16x32_f16(a3c[mi], giF, ai, 0, 0, 0);
#pragma unroll
    for (int r = 0; r < 4; ++r) {
      int h = (wv * 2 + mi) * 16 + g * 4 + r;
      *(_Float16*)(Ysh + h * 80 + rit * 2) = (_Float16)ar[r];
      *(_Float16*)(Ysh + h * 80 + (16 + rit) * 2) = (_Float16)ai[r];
    }
  }
  __syncthreads();
#pragma unroll
  for (int i = 0; i < 2; ++i) {
    int idx = i * 256 + tid;
    int h = idx >> 2, q = idx & 3;
    u32x4 v = *(const u32x4*)(Ysh + h * 80 + q * 16);
    *(u32x4*)(Y1h + ((size_t)(bb * 128 + h) * 64 + o) * 32 + q * 8) = v;
  }
}

// ---------------- KAN feature math ----------------
__device__ __forceinline__ float fast_silu(float v) {
  return v * (1.f / (1.f + __expf(-v)));
}

// Packed-fp16 cubic B-spline: p2(t)=p1(1-t), p3(t)=p0(1-t) -> pack {t,1-t},
// 6 v_pk ops yield {p0,p3} and {p1,p2}; 2 v_perm_b32 assemble the payload
// words; branchless 128-bit shift positions them; one b128 LDS write.
__device__ __forceinline__ void spline_scatter(char* p16, float v) {
  const float Klo = __fsub_rn(__fmul_rn(-3.f, 0.4f), 1.0f);
  float u = (v - Klo) * 2.5f;
  float uc = fminf(fmaxf(u, 0.f), 10.5f);
  int i = (int)uc;
  float t = u - (float)i;
  half2 tv = __builtin_bit_cast(half2, pk2(t, 1.f - t));  // {t, 1-t}
  half2 v2 = tv * tv;
  half2 A = (v2 * tv) * h2splat(1.f / 6.f);  // {p0, p3}
  half2 B = tv * h2splat(-0.5f) + h2splat(0.5f);
  B = B * tv + h2splat(0.5f);
  B = B * tv + h2splat(1.f / 6.f);           // {p1, p2}
  bool ok = (u >= 0.f) && (u < 11.f);
  unsigned ua = __builtin_bit_cast(unsigned, A);  // bytes p0lo p0hi p3lo p3hi
  unsigned ub = __builtin_bit_cast(unsigned, B);  // bytes p1lo p1hi p2lo p2hi
  unsigned w0 = __builtin_amdgcn_perm(ua, ub, 0x03020706u);  // [p3|p2]
  unsigned w1 = __builtin_amdgcn_perm(ua, ub, 0x05040100u);  // [p1|p0]
  unsigned a32 = ok ? w0 : 0u;
  unsigned b32 = ok ? w1 : 0u;
  u64 P = ((u64)b32 << 32) | a32;
  int sh = i << 4;
  u64 tA = P >> ((48 - sh) & 63);
  u64 tB = P << ((sh - 48) & 63);
  u64 tC = P >> ((112 - sh) & 63);
  u64 tD = P << ((sh - 112) & 63);
  u64 lo = (sh < 64) ? tA : ((sh < 112) ? tB : 0ull);
  u64 hi = (sh < 64) ? 0ull : ((sh < 128) ? tC : tD);
  u32x4 st = {(unsigned)lo, (unsigned)(lo >> 32), (unsigned)hi, (unsigned)(hi >> 32)};
  *(u32x4*)p16 = st;
}

// Exact-GELU via A&S 7.1.26 erf (|eps| <= 1.5e-7): ~17 VALU, no libm branches.
__device__ __forceinline__ float gelu_exact(float v) {
  float x = fabsf(v) * 0.70710678118654752f;
  float t = __builtin_amdgcn_rcpf(fmaf(0.3275911f, x, 1.0f));
  float p = fmaf(fmaf(fmaf(fmaf(1.061405429f, t, -1.453152027f), t,
                           1.421413741f), t, -0.284496736f), t, 0.254829592f) * t;
  float e = __expf(-x * x);
  float erfa = fmaf(-p, e, 1.0f);  // erf(|x|)
  return 0.5f * v * (1.0f + copysignf(erfa, v));
}

__device__ __forceinline__ void w2feat(char* S, int g, int nt, int rit, f32x4 a) {
  const int c = nt * 16 + rit;
#pragma unroll
  for (int r = 0; r < 4; ++r) {
    char* row = S + (g * 4 + r) * ROWB;
    float v = a[r];
    *(_Float16*)(row + c * 2) = (_Float16)fast_silu(v);
    spline_scatter(row + 128 + c * 16, v);
  }
}

// Load one layer's 18 B-fragments into registers (72 VGPR, kept resident).
__device__ __forceinline__ void load_bfrags(half8* B, const half8* Bq, int nt,
                                            int l) {
  const half8* bq = Bq + (size_t)nt * 18 * 64 + l;
#pragma unroll
  for (int ks = 0; ks < 18; ++ks) B[ks] = bq[ks * 64];
}

// One 16x16x576 GEMM slice with register-resident B: 18 ds_read + 18 MFMA.
__device__ __forceinline__ void gemm_slot_res(const char* S, const half8* B,
                                              int rit, int g, f32x4& acc) {
  const char* pa = S + rit * ROWB + g * 16;
#pragma unroll
  for (int ks = 0; ks < 18; ++ks) {
    half8 a = *(const half8*)(pa + ks * 64);
    acc = __builtin_amdgcn_mfma_f32_16x16x32_f16(a, B[ks], acc, 0, 0, 0);
  }
}

__device__ __forceinline__ void bounce_acc(float* bnc, int c, int px0, f32x4 a) {
  float* row = bnc + c * 65 + px0;
#pragma unroll
  for (int r = 0; r < 4; ++r) row[r] = gelu_exact(a[r]);
}

// ---------------- mega kernel: c2r + conv + bias + 2x KAN + GELU ------------
__global__ __launch_bounds__(256, 3) void kan_mega_kernel(
    const float* __restrict__ x, float* __restrict__ y,
    const _Float16* __restrict__ Y1h,
    const half8* __restrict__ Bq1, const half8* __restrict__ Bq2,
    const half8* __restrict__ Wfrag, const half8* __restrict__ Tfrag,
    const float* __restrict__ convb) {
  __shared__ __align__(16) char Abuf[2 * 16 * ROWB];
  char* A0 = Abuf;
  char* A1 = Abuf + 16 * ROWB;
  float* ybounce = (float*)A1;
  const int tid = threadIdx.x;
  const int l = tid & 63;
  const int nt = tid >> 6;
  const int rit = l & 15, g = l >> 4;
  const int n0 = blockIdx.x * 64;
  const int b = n0 >> 14;
  const int rem = n0 & 16383;
  const int hrow = rem >> 7, w0 = rem & 127;
  float* base = y + (size_t)b * 1048576 + (size_t)hrow * 128 + w0;
  const float* xbase = x + (size_t)b * 1048576 + (size_t)hrow * 128 + w0;

  half8 By = ((const half8*)Y1h)[((size_t)(b * 128 + hrow) * 64 + nt * 16 + rit) * 4 + g];
  half8 Wf0 = Wfrag[(nt * 2 + 0) * 64 + l];
  half8 Wf1 = Wfrag[(nt * 2 + 1) * 64 + l];
  half8 Tf0 = Tfrag[(w0 + 0 + rit) * 4 + g];
  half8 Tf1 = Tfrag[(w0 + 16 + rit) * 4 + g];
  half8 Tf2 = Tfrag[(w0 + 32 + rit) * 4 + g];
  half8 Tf3 = Tfrag[(w0 + 48 + rit) * 4 + g];
  const float cbv = convb[nt * 16 + rit];

  // layer-1 B fragments: loaded once, resident through P1..P4
  half8 B[18];
  load_bfrags(B, Bq1, nt, l);

  // ---- stage Xh[64 px][64 cin] fp16 into A0, px-major: 2x ds_write_b128 ----
  {
    const int px = tid & 63, cg = tid >> 6;
    const float* bx = xbase + px + (size_t)cg * (16 * 16384);
    float tmp[16];
#pragma unroll
    for (int j = 0; j < 16; ++j) tmp[j] = bx[(size_t)j * 16384];
    u32x4 wA, wB;
#pragma unroll
    for (int p = 0; p < 4; ++p) wA[p] = pk2(tmp[2 * p], tmp[2 * p + 1]);
#pragma unroll
    for (int p = 0; p < 4; ++p) wB[p] = pk2(tmp[8 + 2 * p], tmp[9 + 2 * p]);
    *(u32x4*)(A0 + px * ROWX + cg * 32) = wA;
    *(u32x4*)(A0 + px * ROWX + cg * 32 + 16) = wB;
  }
  __syncthreads();

  const f32x4 z = {0.f, 0.f, 0.f, 0.f};
  f32x4 a00 = z, a01 = z, a02 = z, a03 = z;
#define CONV_TILE(acc, mt, TF)                                                \
  {                                                                           \
    const char* pa = A0 + (mt * 16 + rit) * ROWX;                             \
    acc = __builtin_amdgcn_mfma_f32_16x16x32_f16(TF, By, z, 0, 0, 0);         \
    half8 xa0 = *(const half8*)(pa + g * 16);                                 \
    acc = __builtin_amdgcn_mfma_f32_16x16x32_f16(xa0, Wf0, acc, 0, 0, 0);     \
    half8 xa1 = *(const half8*)(pa + 64 + g * 16);                            \
    acc = __builtin_amdgcn_mfma_f32_16x16x32_f16(xa1, Wf1, acc, 0, 0, 0);     \
    acc[0] += cbv; acc[1] += cbv; acc[2] += cbv; acc[3] += cbv;               \
  }
  CONV_TILE(a00, 0, Tf0)
  CONV_TILE(a01, 1, Tf1)
  CONV_TILE(a02, 2, Tf2)
  CONV_TILE(a03, 3, Tf3)
#undef CONV_TILE
  w2feat(A1, g, nt, rit, a00);
  __syncthreads();

  f32x4 a10 = z, a11 = z, a12 = z, a13 = z;
  f32x4 a20 = z, a21 = z, a22 = z, a23 = z;
  // P1..P3: layer-1 GEMM(p) || features(p+1)
  gemm_slot_res(A1, B, rit, g, a10); w2feat(A0, g, nt, rit, a01);
  __syncthreads();
  gemm_slot_res(A0, B, rit, g, a11); w2feat(A1, g, nt, rit, a02);
  __syncthreads();
  gemm_slot_res(A1, B, rit, g, a12); w2feat(A0, g, nt, rit, a03);
  __syncthreads();
  // P4: last layer-1 GEMM; reload B with layer-2 fragments (hides under
  // w2feat + barrier; same registers -> no extra VGPR pressure)
  gemm_slot_res(A0, B, rit, g, a13);
  load_bfrags(B, Bq2, nt, l);
  w2feat(A1, g, nt, rit, a10);
  __syncthreads();
  // P5..P7: layer-2 GEMM(p) || layer-2 features(p+1)
  gemm_slot_res(A1, B, rit, g, a20); w2feat(A0, g, nt, rit, a11);
  __syncthreads();
  gemm_slot_res(A0, B, rit, g, a21); w2feat(A1, g, nt, rit, a12);
  __syncthreads();
  gemm_slot_res(A1, B, rit, g, a22); w2feat(A0, g, nt, rit, a13);
  __syncthreads();
  // P8: last GEMM (reads A0) || GELU-bounce into A1 region
  const int cch = nt * 16 + rit;
  gemm_slot_res(A0, B, rit, g, a23);
  bounce_acc(ybounce, cch, 0 + g * 4, a20);
  bounce_acc(ybounce, cch, 16 + g * 4, a21);
  bounce_acc(ybounce, cch, 32 + g * 4, a22);
  bounce_acc(ybounce, cch, 48 + g * 4, a23);
  __syncthreads();
#pragma unroll
  for (int i = 0; i < 4; ++i) {
    int idx = i * 256 + tid;
    int c = idx >> 4, q = idx & 15;
    const float* r = ybounce + c * 65 + q * 4;
    float4 v;
    v.x = r[0]; v.y = r[1]; v.z = r[2]; v.w = r[3];
    *(float4*)(base + (size_t)c * 16384 + q * 4) = v;
  }
}

// ---------------------------------------------------------------------------
extern "C" void kernel_launch(void* const* d_in, const int* in_sizes, int n_in,
                              void* d_out, int out_size, void* d_ws, size_t ws_size,
                              hipStream_t stream) {
  const float* x    = (const float*)d_in[0];
  const float* w1r  = (const float*)d_in[1];
  const float* w1i  = (const float*)d_in[2];
  const float* w2r  = (const float*)d_in[3];
  const float* w2i  = (const float*)d_in[4];
  const float* cw   = (const float*)d_in[5];
  const float* cb   = (const float*)d_in[6];
  const float* k1b  = (const float*)d_in[7];
  const float* k1s  = (const float*)d_in[8];
  const float* k1sc = (const float*)d_in[9];
  const float* k2b  = (const float*)d_in[10];
  const float* k2s  = (const float*)d_in[11];
  const float* k2sc = (const float*)d_in[12];

  char* ws = (char*)d_ws;
  float*     XfRe  = (float*)(ws + 0);           // 2 MB
  float*     XfIm  = (float*)(ws + 2097152);     // 2 MB
  _Float16*  Y1h   = (_Float16*)(ws + 4194304);  // 8 MB
  half8*     Bf1   = (half8*)(ws + 12582912);    // 73728 B
  half8*     Bf2   = (half8*)(ws + 12656640);    // 73728 B
  half8*     Wfrag = (half8*)(ws + 12730368);    // 8192 B
  half8*     Tfrag = (half8*)(ws + 12738560);    // 8192 B
  half8*     T1f   = (half8*)(ws + 12746752);    // 8192 B
  half8*     A2c   = (half8*)(ws + 12754944);
  half8*     A2s   = (half8*)(ws + 12763136);
  half8*     A2sn  = (half8*)(ws + 12771328);
  half8*     A3c   = (half8*)(ws + 12779520);
  half8*     A3s   = (half8*)(ws + 12787712);
  half8*     A3sn  = (half8*)(ws + 12795904);
  float* y = (float*)d_out;

  prep_all_kernel<<<54, 256, 0, stream>>>(k1b, k1s, k1sc, k2b, k2s, k2sc, cw,
                                          Bf1, Bf2, Wfrag, Tfrag, T1f, A2c,
                                          A2s, A2sn, A3c, A3s, A3sn);
  fwd_dft_kernel<<<1024, 256, 0, stream>>>(x, XfRe, XfIm, T1f, A2c, A2s, A2sn);
  mode_mix_kernel<<<512, 256, 0, stream>>>(XfRe, XfIm, w1r, w1i, w2r, w2i);
  inv_h_kernel<<<1024, 256, 0, stream>>>(XfRe, XfIm, Y1h, A3c, A3s, A3sn);
  kan_mega_kernel<<<4096, 256, 0, stream>>>(x, y, Y1h, Bf1, Bf2, Wfrag, Tfrag, cb);
}